// Round 9
// baseline (890.307 us; speedup 1.0000x reference)
//
#include <hip/hip_runtime.h>
#include <math.h>

#define FD 64
#define NRBF 20
#define CUT 5.0f
#define EPSV 1e-8f
#define PI_F 3.14159265358979f

__device__ __forceinline__ float wredsum(float v){
#pragma unroll
  for (int m = 32; m >= 1; m >>= 1) v += __shfl_xor(v, m, 64);
  return v;
}
__device__ __forceinline__ float wredmax(float v){
#pragma unroll
  for (int m = 32; m >= 1; m >>= 1) v = fmaxf(v, __shfl_xor(v, m, 64));
  return v;
}
__device__ __forceinline__ float silu_f(float x){ return x * (1.0f / (1.0f + __expf(-x))); }
__device__ __forceinline__ unsigned pack_bf16(float a, float b){
  unsigned ua = __float_as_uint(a), ub = __float_as_uint(b);
  ua = (ua + 0x7fffu + ((ua >> 16) & 1u)) >> 16;
  ub = (ub + 0x7fffu + ((ub >> 16) & 1u)) >> 16;
  return ua | (ub << 16);
}
#define BF_LO(u) __uint_as_float((u) << 16)
#define BF_HI(u) __uint_as_float((u) & 0xffff0000u)

// ---- CSR build: histogram, scan, scatter ----
__global__ __launch_bounds__(256) void k_count(const int* __restrict__ idx_i,
                                               int* __restrict__ cnt, int P)
{
  int p = blockIdx.x * blockDim.x + threadIdx.x;
  if (p < P) atomicAdd(&cnt[idx_i[p]], 1);
}

__global__ __launch_bounds__(1024) void k_scan(const int* __restrict__ cnt,
                                               int* __restrict__ start,
                                               int* __restrict__ cursor, int N)
{
  __shared__ int part[1024];
  int t = threadIdx.x;
  int chunk = (N + 1023) / 1024;
  int lo = t * chunk, hi = lo + chunk; if (hi > N) hi = N;
  int s = 0;
  for (int i = lo; i < hi; ++i) s += cnt[i];
  part[t] = s;
  __syncthreads();
  for (int off = 1; off < 1024; off <<= 1){
    int v = 0;
    if (t >= off) v = part[t - off];
    __syncthreads();
    if (t >= off) part[t] += v;
    __syncthreads();
  }
  int run = (t == 0) ? 0 : part[t-1];
  for (int i = lo; i < hi; ++i){ start[i] = run; cursor[i] = run; run += cnt[i]; }
  if (t == 1023) start[N] = run;
}

__global__ __launch_bounds__(256) void k_scatter(const int* __restrict__ idx_i,
                                                 int* __restrict__ cursor,
                                                 int* __restrict__ elist, int P)
{
  int p = blockIdx.x * blockDim.x + threadIdx.x;
  if (p < P){
    int pos = atomicAdd(&cursor[idx_i[p]], 1);
    elist[pos] = p;
  }
}

// ---- edge records in CSR order: eP[e][24] = dir(3),fcut,phi*fcut(20); eJ[e]=idx_j ----
__global__ __launch_bounds__(256) void k_edgeprep(const float* __restrict__ Rij,
                                                  const int* __restrict__ elist,
                                                  const int* __restrict__ idx_j,
                                                  float* __restrict__ eP,
                                                  int* __restrict__ eJ, int P)
{
  int e = blockIdx.x * blockDim.x + threadIdx.x;
  if (e >= P) return;
  int p = elist[e];
  eJ[e] = idx_j[p];
  float rx = Rij[3*p+0], ry = Rij[3*p+1], rz = Rij[3*p+2];
  float d = sqrtf(rx*rx + ry*ry + rz*rz);
  float inv = 1.0f / d;
  float fc = (d < CUT) ? 0.5f * (__cosf(PI_F * d / CUT) + 1.0f) : 0.0f;
  float* pr = eP + (size_t)e * 24;
  pr[0] = rx*inv; pr[1] = ry*inv; pr[2] = rz*inv; pr[3] = fc;
  const float width = CUT / (float)(NRBF - 1);
#pragma unroll
  for (int r = 0; r < NRBF; ++r){
    float t = (d - width * (float)r) / width;
    pr[4+r] = __expf(-0.5f * t * t) * fc;
  }
}

// ---- transpose rec_W2 -> swizzled bf16 rW2S; rb2 -> rb2T[l][c][f] (f32) ----
__global__ __launch_bounds__(256) void k_transpose_w(const float* __restrict__ rW2,
                                                     const float* __restrict__ rb2,
                                                     unsigned short* __restrict__ rW2S,
                                                     float* __restrict__ rb2T)
{
  int t = blockIdx.x * blockDim.x + threadIdx.x;
  if (t < 2*64*64*32){
    int km   = t & 7;
    int slot = (t >> 3) & 3;
    int f    = (t >> 5) & 63;
    int c    = (t >> 11) & 63;
    int l    = t >> 17;
    int k    = ((slot ^ ((f >> 1) & 3)) << 3) | km;
    float v = rW2[((size_t)(l*32 + k))*4096 + f*64 + c];
    unsigned int u = __float_as_uint(v);
    unsigned int r = (u + 0x7fffu + ((u >> 16) & 1u)) >> 16;
    rW2S[t] = (unsigned short)r;
  }
  if (t < 2*64*64){
    int f = t & 63, c = (t >> 6) & 63, l = t >> 12;
    rb2T[t] = rb2[(size_t)l*4096 + f*64 + c];
  }
}

// ---- K_init: q = embed[Z] ----
__global__ __launch_bounds__(256) void k_init_q(const int* __restrict__ Z,
                                                const float* __restrict__ embed,
                                                float* __restrict__ q, int Ntot)
{
  int t = blockIdx.x * blockDim.x + threadIdx.x;
  if (t >= Ntot * FD) return;
  int n = t >> 6, f = t & 63;
  q[t] = embed[Z[n]*FD + f];
}

// ---- K1: per-atom pre. 16 atoms/block, weights LDS-staged.
// Writes XCVh (packed bf16: k0=(X0,X1), k1=(X2,CV0), k2=(CV1,CV2)) and CVf (f32). ----
__global__ __launch_bounds__(256) void k_atom_pre(
    const float* __restrict__ q, const float* __restrict__ mu,
    const float* __restrict__ cW1, const float* __restrict__ cb1,
    const float* __restrict__ cW2, const float* __restrict__ cb2,
    const float* __restrict__ pW1, const float* __restrict__ pb1,
    const float* __restrict__ pW2, const float* __restrict__ pb2,
    unsigned* __restrict__ XCVh, float* __restrict__ CVf, int Ntot)
{
  __shared__ float wbuf[12288];     // 48 KB
  __shared__ float qs[16][64];      // 4 KB
  __shared__ float sbuf[16][128];   // 8 KB
  __shared__ float h1s[16][64];     // 4 KB
  __shared__ float hcs[16][32];     // 2 KB
  int t = threadIdx.x;
  int w = t >> 6, f = t & 63;
  int base = blockIdx.x * 16;
  const int aw = w * 4;
  float4* wt4 = (float4*)wbuf;

  float m0a[4], m1a[4], m2a[4], m0b[4], m1b[4], m2b[4];
#pragma unroll
  for (int s = 0; s < 4; ++s){
    int a = aw + s;
    int n = base + a; if (n >= Ntot) n = Ntot - 1;
    qs[a][f] = q[(size_t)n*64 + f];
    const float* mun = mu + (size_t)n * 384;
    m0a[s] = mun[0*128 + f];      m1a[s] = mun[1*128 + f];      m2a[s] = mun[2*128 + f];
    m0b[s] = mun[0*128 + 64 + f]; m1b[s] = mun[1*128 + 64 + f]; m2b[s] = mun[2*128 + 64 + f];
    sbuf[a][f]      = sqrtf(m0a[s]*m0a[s] + m1a[s]*m1a[s] + m2a[s]*m2a[s] + EPSV);
    sbuf[a][64 + f] = sqrtf(m0b[s]*m0b[s] + m1b[s]*m1b[s] + m2b[s]*m2b[s] + EPSV);
  }
#pragma unroll
  for (int i = 0; i < 4; ++i) wt4[t + i*256] = ((const float4*)cW1)[t + i*256];
  __syncthreads();

  float hacc[4];
#pragma unroll
  for (int s = 0; s < 4; ++s) hacc[s] = cb1[f];
  for (int k = 0; k < 64; ++k){
    float wv = wbuf[k*64 + f];
#pragma unroll
    for (int s = 0; s < 4; ++s) hacc[s] = fmaf(qs[aw + s][k], wv, hacc[s]);
  }
#pragma unroll
  for (int s = 0; s < 4; ++s) h1s[aw + s][f] = silu_f(hacc[s]);

  __syncthreads();
#pragma unroll
  for (int i = 0; i < 12; ++i) wt4[t + i*256] = ((const float4*)cW2)[t + i*256];
  __syncthreads();

  float x0[4], x1[4], x2[4];
#pragma unroll
  for (int s = 0; s < 4; ++s){ x0[s] = cb2[f]; x1[s] = cb2[64+f]; x2[s] = cb2[128+f]; }
  for (int k = 0; k < 64; ++k){
    float u0 = wbuf[k*192 + f];
    float u1 = wbuf[k*192 + 64 + f];
    float u2 = wbuf[k*192 + 128 + f];
#pragma unroll
    for (int s = 0; s < 4; ++s){
      float h = h1s[aw + s][k];
      x0[s] = fmaf(h, u0, x0[s]); x1[s] = fmaf(h, u1, x1[s]); x2[s] = fmaf(h, u2, x2[s]);
    }
  }
#pragma unroll
  for (int s = 0; s < 4; ++s){
    int n = base + aw + s;
    if (n < Ntot) XCVh[(size_t)n*192 + f] = pack_bf16(x0[s], x1[s]);
  }

  __syncthreads();
#pragma unroll
  for (int i = 0; i < 4; ++i) wt4[t + i*256] = ((const float4*)pW1)[t + i*256];
#pragma unroll
  for (int i = 0; i < 2; ++i) wt4[1024 + t + i*256] = ((const float4*)pW2)[t + i*256];
  __syncthreads();

  int ki = f & 31;
#pragma unroll
  for (int p = 0; p < 2; ++p){
    int a_h = aw + p*2 + (f >> 5);
    float ah = pb1[ki];
#pragma unroll 4
    for (int c = 0; c < 128; ++c) ah = fmaf(sbuf[a_h][c], wbuf[c*32 + ki], ah);
    hcs[a_h][ki] = fmaxf(ah, 0.0f);
  }

  float logit[4];
#pragma unroll
  for (int s = 0; s < 4; ++s) logit[s] = pb2[f];
  for (int k = 0; k < 32; ++k){
    float wv = wbuf[4096 + k*64 + f];
#pragma unroll
    for (int s = 0; s < 4; ++s) logit[s] = fmaf(hcs[aw + s][k], wv, logit[s]);
  }
#pragma unroll
  for (int s = 0; s < 4; ++s){
    float mx = wredmax(logit[s]);
    float e  = __expf(logit[s] - mx);
    float se = wredsum(e);
    float wt = e / se;
    float v0 = wredsum(m0a[s] + m0b[s]);
    float v1 = wredsum(m1a[s] + m1b[s]);
    float v2 = wredsum(m2a[s] + m2b[s]);
    int n = base + aw + s;
    if (n < Ntot){
      float cv0 = v0 * wt, cv1 = v1 * wt, cv2 = v2 * wt;
      XCVh[(size_t)n*192 + 64 + f]  = pack_bf16(x2[s], cv0);
      XCVh[(size_t)n*192 + 128 + f] = pack_bf16(cv1, cv2);
      float* cvn = CVf + (size_t)n*192;
      cvn[f] = cv0; cvn[64+f] = cv1; cvn[128+f] = cv2;
    }
  }
}

// ---- K2 v4: gather, sequential edge records, j-preload + readlane, bf16 XCV. ----
__global__ __launch_bounds__(256) void k_gather(
    const float* __restrict__ eP, const int* __restrict__ eJ,
    const int* __restrict__ start,
    const float* __restrict__ fW, const float* __restrict__ fb,
    const unsigned* __restrict__ XCVh,
    float* __restrict__ dq, float* __restrict__ dmu, int l, int Ntot)
{
  int w = threadIdx.x >> 6;
  int f = threadIdx.x & 63;
  int i = blockIdx.x * 4 + w;
  if (i >= Ntot) return;
  const int col = l * 192;

  float fw0[NRBF], fw1[NRBF], fw2[NRBF];
#pragma unroll
  for (int r = 0; r < NRBF; ++r){
    const float* fr = fW + r*384 + col;
    fw0[r] = fr[f]; fw1[r] = fr[64 + f]; fw2[r] = fr[128 + f];
  }
  float fb0 = fb[col + f], fb1 = fb[col + 64 + f], fb2 = fb[col + 128 + f];

  float dqa = 0.f, dm0 = 0.f, dm1 = 0.f, dm2 = 0.f;
  int e0 = start[i], e1 = start[i+1];
  for (int cb = e0; cb < e1; cb += 64){
    int cnt = e1 - cb; if (cnt > 64) cnt = 64;
    int jv = (f < cnt) ? eJ[cb + f] : 0;
    int e = 0;
    for (; e + 2 <= cnt; e += 2){
      int jA = __builtin_amdgcn_readlane(jv, e);
      int jB = __builtin_amdgcn_readlane(jv, e + 1);
      const float4* pr = (const float4*)(eP + (size_t)(cb + e) * 24);
      float4 A0=pr[0],A1=pr[1],A2=pr[2],A3=pr[3],A4=pr[4],A5=pr[5];
      float4 B0=pr[6],B1=pr[7],B2=pr[8],B3=pr[9],B4=pr[10],B5=pr[11];
      const unsigned* xA = XCVh + (size_t)jA * 192;
      const unsigned* xB = XCVh + (size_t)jB * 192;
      unsigned uA0=xA[f], uA1=xA[64+f], uA2=xA[128+f];
      unsigned uB0=xB[f], uB1=xB[64+f], uB2=xB[128+f];
      float phA[NRBF] = {A1.x,A1.y,A1.z,A1.w, A2.x,A2.y,A2.z,A2.w,
                         A3.x,A3.y,A3.z,A3.w, A4.x,A4.y,A4.z,A4.w,
                         A5.x,A5.y,A5.z,A5.w};
      float phB[NRBF] = {B1.x,B1.y,B1.z,B1.w, B2.x,B2.y,B2.z,B2.w,
                         B3.x,B3.y,B3.z,B3.w, B4.x,B4.y,B4.z,B4.w,
                         B5.x,B5.y,B5.z,B5.w};
      float wA0=fb0*A0.w, wA1=fb1*A0.w, wA2=fb2*A0.w;
      float wB0=fb0*B0.w, wB1=fb1*B0.w, wB2=fb2*B0.w;
#pragma unroll
      for (int r = 0; r < NRBF; ++r){
        wA0 = fmaf(phA[r], fw0[r], wA0);
        wA1 = fmaf(phA[r], fw1[r], wA1);
        wA2 = fmaf(phA[r], fw2[r], wA2);
        wB0 = fmaf(phB[r], fw0[r], wB0);
        wB1 = fmaf(phB[r], fw1[r], wB1);
        wB2 = fmaf(phB[r], fw2[r], wB2);
      }
      dqa = fmaf(BF_LO(uA0), wA0, dqa);
      float dmRA = BF_HI(uA0) * wA1, dmmA = BF_LO(uA1) * wA2;
      dm0 = fmaf(dmRA, A0.x, fmaf(dmmA, BF_HI(uA1), dm0));
      dm1 = fmaf(dmRA, A0.y, fmaf(dmmA, BF_LO(uA2), dm1));
      dm2 = fmaf(dmRA, A0.z, fmaf(dmmA, BF_HI(uA2), dm2));
      dqa = fmaf(BF_LO(uB0), wB0, dqa);
      float dmRB = BF_HI(uB0) * wB1, dmmB = BF_LO(uB1) * wB2;
      dm0 = fmaf(dmRB, B0.x, fmaf(dmmB, BF_HI(uB1), dm0));
      dm1 = fmaf(dmRB, B0.y, fmaf(dmmB, BF_LO(uB2), dm1));
      dm2 = fmaf(dmRB, B0.z, fmaf(dmmB, BF_HI(uB2), dm2));
    }
    if (e < cnt){
      int j = __builtin_amdgcn_readlane(jv, e);
      const float4* pr = (const float4*)(eP + (size_t)(cb + e) * 24);
      float4 A0=pr[0],A1=pr[1],A2=pr[2],A3=pr[3],A4=pr[4],A5=pr[5];
      const unsigned* xj = XCVh + (size_t)j * 192;
      unsigned u0=xj[f], u1=xj[64+f], u2=xj[128+f];
      float ph[NRBF] = {A1.x,A1.y,A1.z,A1.w, A2.x,A2.y,A2.z,A2.w,
                        A3.x,A3.y,A3.z,A3.w, A4.x,A4.y,A4.z,A4.w,
                        A5.x,A5.y,A5.z,A5.w};
      float w0=fb0*A0.w, w1=fb1*A0.w, w2=fb2*A0.w;
#pragma unroll
      for (int r = 0; r < NRBF; ++r){
        w0 = fmaf(ph[r], fw0[r], w0);
        w1 = fmaf(ph[r], fw1[r], w1);
        w2 = fmaf(ph[r], fw2[r], w2);
      }
      dqa = fmaf(BF_LO(u0), w0, dqa);
      float dmR = BF_HI(u0) * w1, dmm = BF_LO(u1) * w2;
      dm0 = fmaf(dmR, A0.x, fmaf(dmm, BF_HI(u1), dm0));
      dm1 = fmaf(dmR, A0.y, fmaf(dmm, BF_LO(u2), dm1));
      dm2 = fmaf(dmR, A0.z, fmaf(dmm, BF_HI(u2), dm2));
    }
  }
  dq[(size_t)i*64 + f] = dqa;
  float* dmn = dmu + (size_t)i*192;
  dmn[f] = dm0; dmn[64 + f] = dm1; dmn[128 + f] = dm2;
}

// ---- K3a v5: tv with bf16 tiles + h in SGPRs (readlane). 512 thr, 16 atoms/block. ----
__global__ __launch_bounds__(512) void k_tv(
    const float* __restrict__ dmuA, const float* __restrict__ CVf,
    const float* __restrict__ rW1, const float* __restrict__ rb1,
    const unsigned short* __restrict__ rW2S, const float* __restrict__ rb2Tl,
    float* __restrict__ MUI, float* __restrict__ TV, int Ntot)
{
  __shared__ float mus[16][3][64];  // 12 KB
  __shared__ float svs[16][64];     // 4 KB
  __shared__ float4 wt4[2048];      // 32 KB
  __shared__ float rbt[8][64];      // 2 KB
  int t = threadIdx.x;
  int w = t >> 6, f = t & 63;
  int base = blockIdx.x * 16;

#pragma unroll
  for (int s = 0; s < 2; ++s){
    int a = w*2 + s;
    int n = base + a; bool ok = (n < Ntot); if (!ok) n = Ntot - 1;
    const float* dmn = dmuA + (size_t)n*192;
    const float* cvn = CVf  + (size_t)n*192;
    float m0 = dmn[f]       + cvn[f];
    float m1 = dmn[64 + f]  + cvn[64 + f];
    float m2 = dmn[128 + f] + cvn[128 + f];
    mus[a][0][f] = m0; mus[a][1][f] = m1; mus[a][2][f] = m2;
    svs[a][f] = sqrtf(m0*m0 + m1*m1 + m2*m2 + EPSV);
    if (ok){
      float* mo = MUI + (size_t)n*192;
      mo[f] = m0; mo[64+f] = m1; mo[128+f] = m2;
    }
  }
  __syncthreads();

  int ki = f & 31;
  int a_h = w*2 + (f >> 5);
  float ah = rb1[ki];
#pragma unroll
  for (int c = 0; c < 64; ++c) ah = fmaf(svs[a_h][c], rW1[c*32 + ki], ah);
  ah = fmaxf(ah, 0.0f);
  // h is wave-uniform per atom -> SGPRs via readlane
  float hs0[32], hs1[32];
#pragma unroll
  for (int k = 0; k < 32; ++k){
    hs0[k] = __uint_as_float(__builtin_amdgcn_readlane(__float_as_uint(ah), k));
    hs1[k] = __uint_as_float(__builtin_amdgcn_readlane(__float_as_uint(ah), 32 + k));
  }

  const int a0 = w*2, a1 = a0 + 1;
  float mf00 = mus[a0][0][f], mf01 = mus[a0][1][f], mf02 = mus[a0][2][f];
  float mf10 = mus[a1][0][f], mf11 = mus[a1][1][f], mf12 = mus[a1][2][f];
  float tv00=0,tv01=0,tv02=0, tv10=0,tv11=0,tv12=0;
  const int sw2 = (f >> 1) & 3;

  for (int ct = 0; ct < 8; ++ct){
    __syncthreads();
    const float4* src = (const float4*)rW2S + (size_t)ct*2048;
#pragma unroll
    for (int i = 0; i < 4; ++i) wt4[t + i*512] = src[t + i*512];
    if (t < 128) ((float4*)rbt)[t] = ((const float4*)(rb2Tl + ct*512))[t];
    __syncthreads();

#pragma unroll
    for (int cc = 0; cc < 8; ++cc){
      int c = ct*8 + cc;
      float u00 = mus[a0][0][c], u01 = mus[a0][1][c], u02 = mus[a0][2][c];
      float u10 = mus[a1][0][c], u11 = mus[a1][1][c], u12 = mus[a1][2][c];
      float g0 = u00*mf00 + u01*mf01 + u02*mf02;
      float g1 = u10*mf10 + u11*mf11 + u12*mf12;
      float acc0 = rbt[cc][f];
      float acc1 = acc0;
      const uint4* wrow = reinterpret_cast<const uint4*>(&wt4[(cc*64 + f)*4]);
#pragma unroll
      for (int kq = 0; kq < 4; ++kq){
        uint4 u = wrow[kq ^ sw2];
        int k0 = kq*8;
        float w0 = BF_LO(u.x), w1 = BF_HI(u.x);
        float w2 = BF_LO(u.y), w3 = BF_HI(u.y);
        float w4 = BF_LO(u.z), w5 = BF_HI(u.z);
        float w6 = BF_LO(u.w), w7 = BF_HI(u.w);
        acc0 = fmaf(hs0[k0+0], w0, acc0);
        acc0 = fmaf(hs0[k0+1], w1, acc0);
        acc0 = fmaf(hs0[k0+2], w2, acc0);
        acc0 = fmaf(hs0[k0+3], w3, acc0);
        acc0 = fmaf(hs0[k0+4], w4, acc0);
        acc0 = fmaf(hs0[k0+5], w5, acc0);
        acc0 = fmaf(hs0[k0+6], w6, acc0);
        acc0 = fmaf(hs0[k0+7], w7, acc0);
        acc1 = fmaf(hs1[k0+0], w0, acc1);
        acc1 = fmaf(hs1[k0+1], w1, acc1);
        acc1 = fmaf(hs1[k0+2], w2, acc1);
        acc1 = fmaf(hs1[k0+3], w3, acc1);
        acc1 = fmaf(hs1[k0+4], w4, acc1);
        acc1 = fmaf(hs1[k0+5], w5, acc1);
        acc1 = fmaf(hs1[k0+6], w6, acc1);
        acc1 = fmaf(hs1[k0+7], w7, acc1);
      }
      float mm0 = acc0 * g0, mm1 = acc1 * g1;
      tv00 = fmaf(u00, mm0, tv00); tv01 = fmaf(u01, mm0, tv01); tv02 = fmaf(u02, mm0, tv02);
      tv10 = fmaf(u10, mm1, tv10); tv11 = fmaf(u11, mm1, tv11); tv12 = fmaf(u12, mm1, tv12);
    }
  }

  int n0 = base + a0, n1 = base + a1;
  if (n0 < Ntot){
    float* tvp = TV + (size_t)n0*192;
    tvp[f] = tv00; tvp[64+f] = tv01; tvp[128+f] = tv02;
  }
  if (n1 < Ntot){
    float* tvp = TV + (size_t)n1*192;
    tvp[f] = tv10; tvp[64+f] = tv11; tvp[128+f] = tv12;
  }
}

// ---- K3b: mixing tail. 16 atoms/block (4 per wave), weights LDS-staged. ----
__global__ __launch_bounds__(256) void k_mix2(
    float* __restrict__ q, float* __restrict__ mu,
    const float* __restrict__ dq, const float* __restrict__ MUI, const float* __restrict__ TV,
    const float* __restrict__ mW1, const float* __restrict__ mb1,
    const float* __restrict__ mW2, const float* __restrict__ mb2,
    const float* __restrict__ Wm, int Ntot)
{
  __shared__ float wbuf[12288];     // 48 KB
  __shared__ float mua[16][3][64];  // 12 KB
  __shared__ float ava[16][128];    // 8 KB
  __shared__ float h2a[16][64];     // 4 KB
  int t = threadIdx.x;
  int w = t >> 6, f = t & 63;
  int base = blockIdx.x * 16;
  const int aw = w * 4;
  float4* wt4 = (float4*)wbuf;

  float qv[4], m0[4], m1[4], m2[4];
#pragma unroll
  for (int s = 0; s < 4; ++s){
    int a = aw + s;
    int n = base + a; if (n >= Ntot) n = Ntot - 1;
    qv[s] = q[(size_t)n*64 + f] + dq[(size_t)n*64 + f];
    const float* mi = MUI + (size_t)n*192;
    m0[s] = mi[f]; m1[s] = mi[64 + f]; m2[s] = mi[128 + f];
    mua[a][0][f] = m0[s]; mua[a][1][f] = m1[s]; mua[a][2][f] = m2[s];
  }

#pragma unroll
  for (int i = 0; i < 8; ++i) wt4[t + i*256] = ((const float4*)Wm)[t + i*256];
  __syncthreads();

  float V0[4]={0,0,0,0}, V1[4]={0,0,0,0}, V2[4]={0,0,0,0};
  float W0[4]={0,0,0,0}, W1[4]={0,0,0,0}, W2[4]={0,0,0,0};
  for (int k = 0; k < 64; ++k){
    float wv = wbuf[k*128 + f];
    float ww = wbuf[k*128 + 64 + f];
#pragma unroll
    for (int s = 0; s < 4; ++s){
      int a = aw + s;
      float b0 = mua[a][0][k], b1 = mua[a][1][k], b2 = mua[a][2][k];
      V0[s] = fmaf(b0, wv, V0[s]); V1[s] = fmaf(b1, wv, V1[s]); V2[s] = fmaf(b2, wv, V2[s]);
      W0[s] = fmaf(b0, ww, W0[s]); W1[s] = fmaf(b1, ww, W1[s]); W2[s] = fmaf(b2, ww, W2[s]);
    }
  }
  float dot[4];
#pragma unroll
  for (int s = 0; s < 4; ++s){
    int a = aw + s;
    ava[a][f] = qv[s];
    ava[a][64 + f] = sqrtf(V0[s]*V0[s] + V1[s]*V1[s] + V2[s]*V2[s] + EPSV);
    dot[s] = V0[s]*W0[s] + V1[s]*W1[s] + V2[s]*W2[s];
  }

  __syncthreads();
#pragma unroll
  for (int i = 0; i < 8; ++i) wt4[t + i*256] = ((const float4*)mW1)[t + i*256];
  __syncthreads();

  float acc[4];
#pragma unroll
  for (int s = 0; s < 4; ++s) acc[s] = mb1[f];
  for (int k = 0; k < 128; ++k){
    float wv = wbuf[k*64 + f];
#pragma unroll
    for (int s = 0; s < 4; ++s) acc[s] = fmaf(ava[aw + s][k], wv, acc[s]);
  }
#pragma unroll
  for (int s = 0; s < 4; ++s) h2a[aw + s][f] = silu_f(acc[s]);

  __syncthreads();
#pragma unroll
  for (int i = 0; i < 12; ++i) wt4[t + i*256] = ((const float4*)mW2)[t + i*256];
  __syncthreads();

  float y0[4], y1[4], y2[4];
#pragma unroll
  for (int s = 0; s < 4; ++s){ y0[s] = mb2[f]; y1[s] = mb2[64+f]; y2[s] = mb2[128+f]; }
  for (int k = 0; k < 64; ++k){
    float u0 = wbuf[k*192 + f];
    float u1 = wbuf[k*192 + 64 + f];
    float u2 = wbuf[k*192 + 128 + f];
#pragma unroll
    for (int s = 0; s < 4; ++s){
      float h = h2a[aw + s][k];
      y0[s] = fmaf(h, u0, y0[s]); y1[s] = fmaf(h, u1, y1[s]); y2[s] = fmaf(h, u2, y2[s]);
    }
  }

#pragma unroll
  for (int s = 0; s < 4; ++s){
    int n = base + aw + s;
    if (n < Ntot){
      q[(size_t)n*64 + f] = qv[s] + y0[s] + y2[s]*dot[s];
      const float* tvp = TV + (size_t)n*192;
      float* mun = mu + (size_t)n*384;
      mun[0*128 + f] = fmaf(y1[s], W0[s], m0[s]); mun[0*128 + 64 + f] = tvp[f];
      mun[1*128 + f] = fmaf(y1[s], W1[s], m1[s]); mun[1*128 + 64 + f] = tvp[64+f];
      mun[2*128 + f] = fmaf(y1[s], W2[s], m2[s]); mun[2*128 + 64 + f] = tvp[128+f];
    }
  }
}

extern "C" void kernel_launch(void* const* d_in, const int* in_sizes, int n_in,
                              void* d_out, int out_size, void* d_ws, size_t ws_size,
                              hipStream_t stream)
{
  const int*   Z      = (const int*)  d_in[0];
  const float* Rij    = (const float*)d_in[1];
  const int*   idx_i  = (const int*)  d_in[2];
  const int*   idx_j  = (const int*)  d_in[3];
  const float* embed  = (const float*)d_in[5];
  const float* fW     = (const float*)d_in[6];
  const float* fb     = (const float*)d_in[7];
  const float* ctxW1  = (const float*)d_in[8];
  const float* ctxb1  = (const float*)d_in[9];
  const float* ctxW2  = (const float*)d_in[10];
  const float* ctxb2  = (const float*)d_in[11];
  const float* compW1 = (const float*)d_in[12];
  const float* compb1 = (const float*)d_in[13];
  const float* compW2 = (const float*)d_in[14];
  const float* compb2 = (const float*)d_in[15];
  const float* recW1  = (const float*)d_in[16];
  const float* recb1  = (const float*)d_in[17];
  const float* recW2  = (const float*)d_in[18];
  const float* recb2  = (const float*)d_in[19];
  const float* mixW1  = (const float*)d_in[20];
  const float* mixb1  = (const float*)d_in[21];
  const float* mixW2  = (const float*)d_in[22];
  const float* mixb2  = (const float*)d_in[23];
  const float* muMixW = (const float*)d_in[24];

  const int N = in_sizes[0];
  const int P = in_sizes[1] / 3;

  float* ws    = (float*)d_ws;
  float* eP    = ws;                         // P*24
  float* q     = eP    + (size_t)P*24;       // N*64
  float* mu    = q     + (size_t)N*64;       // N*384
  float* XCVhf = mu    + (size_t)N*384;      // N*192 (uints; MUI overlays later)
  float* CVf   = XCVhf + (size_t)N*192;      // N*192
  float* dq    = CVf   + (size_t)N*192;      // N*64
  float* dmu   = dq    + (size_t)N*64;       // N*192
  float* rW2Sf = dmu   + (size_t)N*192;      // bf16 512KB = 131072 floats
  float* rb2T  = rW2Sf + (size_t)131072;     // 8192
  float* TV    = rb2T  + (size_t)8192;       // N*192
  int*   cnt    = (int*)(TV + (size_t)N*192);  // N
  int*   startA = cnt    + N;                  // N+1
  int*   cursor = startA + (N + 1);            // N
  int*   elist  = cursor + N;                  // P
  int*   eJ     = elist  + P;                  // P
  unsigned*       XCVh = (unsigned*)XCVhf;
  float*          MUI  = XCVhf;               // overlay: XCVh dead after k_gather
  unsigned short* rW2S = (unsigned short*)rW2Sf;

  hipMemsetAsync(mu, 0, (size_t)N*384*sizeof(float), stream);
  hipMemsetAsync(cnt, 0, (size_t)N*sizeof(int), stream);
  k_init_q<<<(N*FD + 255)/256, 256, 0, stream>>>(Z, embed, q, N);
  k_transpose_w<<<(2*64*64*32 + 255)/256, 256, 0, stream>>>(recW2, recb2, rW2S, rb2T);

  // CSR build + CSR-ordered edge records (idx fixed across layers)
  k_count<<<(P + 255)/256, 256, 0, stream>>>(idx_i, cnt, P);
  k_scan<<<1, 1024, 0, stream>>>(cnt, startA, cursor, N);
  k_scatter<<<(P + 255)/256, 256, 0, stream>>>(idx_i, cursor, elist, P);
  k_edgeprep<<<(P + 255)/256, 256, 0, stream>>>(Rij, elist, idx_j, eP, eJ, P);

  const int ablk4  = (N + 3) / 4;
  const int ablk16 = (N + 15) / 16;
  for (int l = 0; l < 2; ++l){
    k_atom_pre<<<ablk16, 256, 0, stream>>>(q, mu,
        ctxW1 + (size_t)l*64*64,  ctxb1 + (size_t)l*64,
        ctxW2 + (size_t)l*64*192, ctxb2 + (size_t)l*192,
        compW1 + (size_t)l*128*32, compb1 + (size_t)l*32,
        compW2 + (size_t)l*32*64,  compb2 + (size_t)l*64,
        XCVh, CVf, N);
    k_gather<<<ablk4, 256, 0, stream>>>(eP, eJ, startA, fW, fb, XCVh,
        dq, dmu, l, N);
    k_tv<<<ablk16, 512, 0, stream>>>(dmu, CVf,
        recW1 + (size_t)l*64*32, recb1 + (size_t)l*32,
        rW2S + (size_t)l*131072, rb2T + (size_t)l*4096,
        MUI, TV, N);
    k_mix2<<<ablk16, 256, 0, stream>>>(q, mu, dq, MUI, TV,
        mixW1 + (size_t)l*128*64, mixb1 + (size_t)l*64,
        mixW2 + (size_t)l*64*192, mixb2 + (size_t)l*192,
        muMixW + (size_t)l*64*128, N);
  }

  hipMemcpyAsync(d_out, q, (size_t)N*64*sizeof(float), hipMemcpyDeviceToDevice, stream);
  hipMemcpyAsync((float*)d_out + (size_t)N*64, mu, (size_t)N*384*sizeof(float),
                 hipMemcpyDeviceToDevice, stream);
}

// Round 10
// 661.269 us; speedup vs baseline: 1.3464x; 1.3464x over previous
//
#include <hip/hip_runtime.h>
#include <math.h>

#define FD 64
#define NRBF 20
#define CUT 5.0f
#define EPSV 1e-8f
#define PI_F 3.14159265358979f

__device__ __forceinline__ float wredsum(float v){
#pragma unroll
  for (int m = 32; m >= 1; m >>= 1) v += __shfl_xor(v, m, 64);
  return v;
}
__device__ __forceinline__ float wredmax(float v){
#pragma unroll
  for (int m = 32; m >= 1; m >>= 1) v = fmaxf(v, __shfl_xor(v, m, 64));
  return v;
}
__device__ __forceinline__ float silu_f(float x){ return x * (1.0f / (1.0f + __expf(-x))); }
#define BF_LO(u) __uint_as_float((u) << 16)
#define BF_HI(u) __uint_as_float((u) & 0xffff0000u)

// ---- CSR build: histogram, scan, scatter ----
__global__ __launch_bounds__(256) void k_count(const int* __restrict__ idx_i,
                                               int* __restrict__ cnt, int P)
{
  int p = blockIdx.x * blockDim.x + threadIdx.x;
  if (p < P) atomicAdd(&cnt[idx_i[p]], 1);
}

__global__ __launch_bounds__(1024) void k_scan(const int* __restrict__ cnt,
                                               int* __restrict__ start,
                                               int* __restrict__ cursor, int N)
{
  __shared__ int part[1024];
  int t = threadIdx.x;
  int chunk = (N + 1023) / 1024;
  int lo = t * chunk, hi = lo + chunk; if (hi > N) hi = N;
  int s = 0;
  for (int i = lo; i < hi; ++i) s += cnt[i];
  part[t] = s;
  __syncthreads();
  for (int off = 1; off < 1024; off <<= 1){
    int v = 0;
    if (t >= off) v = part[t - off];
    __syncthreads();
    if (t >= off) part[t] += v;
    __syncthreads();
  }
  int run = (t == 0) ? 0 : part[t-1];
  for (int i = lo; i < hi; ++i){ start[i] = run; cursor[i] = run; run += cnt[i]; }
  if (t == 1023) start[N] = run;
}

__global__ __launch_bounds__(256) void k_scatter(const int* __restrict__ idx_i,
                                                 int* __restrict__ cursor,
                                                 int* __restrict__ elist, int P)
{
  int p = blockIdx.x * blockDim.x + threadIdx.x;
  if (p < P){
    int pos = atomicAdd(&cursor[idx_i[p]], 1);
    elist[pos] = p;
  }
}

// ---- edge records in CSR order: eP[e][24] = dir(3),fcut,phi*fcut(20); eJ[e]=idx_j ----
__global__ __launch_bounds__(256) void k_edgeprep(const float* __restrict__ Rij,
                                                  const int* __restrict__ elist,
                                                  const int* __restrict__ idx_j,
                                                  float* __restrict__ eP,
                                                  int* __restrict__ eJ, int P)
{
  int e = blockIdx.x * blockDim.x + threadIdx.x;
  if (e >= P) return;
  int p = elist[e];
  eJ[e] = idx_j[p];
  float rx = Rij[3*p+0], ry = Rij[3*p+1], rz = Rij[3*p+2];
  float d = sqrtf(rx*rx + ry*ry + rz*rz);
  float inv = 1.0f / d;
  float fc = (d < CUT) ? 0.5f * (__cosf(PI_F * d / CUT) + 1.0f) : 0.0f;
  float* pr = eP + (size_t)e * 24;
  pr[0] = rx*inv; pr[1] = ry*inv; pr[2] = rz*inv; pr[3] = fc;
  const float width = CUT / (float)(NRBF - 1);
#pragma unroll
  for (int r = 0; r < NRBF; ++r){
    float t = (d - width * (float)r) / width;
    pr[4+r] = __expf(-0.5f * t * t) * fc;
  }
}

// ---- transpose rec_W2 -> swizzled bf16 rW2S; rb2 -> rb2T[l][c][f] (f32) ----
__global__ __launch_bounds__(256) void k_transpose_w(const float* __restrict__ rW2,
                                                     const float* __restrict__ rb2,
                                                     unsigned short* __restrict__ rW2S,
                                                     float* __restrict__ rb2T)
{
  int t = blockIdx.x * blockDim.x + threadIdx.x;
  if (t < 2*64*64*32){
    int km   = t & 7;
    int slot = (t >> 3) & 3;
    int f    = (t >> 5) & 63;
    int c    = (t >> 11) & 63;
    int l    = t >> 17;
    int k    = ((slot ^ ((f >> 1) & 3)) << 3) | km;
    float v = rW2[((size_t)(l*32 + k))*4096 + f*64 + c];
    unsigned int u = __float_as_uint(v);
    unsigned int r = (u + 0x7fffu + ((u >> 16) & 1u)) >> 16;   // RNE to bf16
    rW2S[t] = (unsigned short)r;
  }
  if (t < 2*64*64){
    int f = t & 63, c = (t >> 6) & 63, l = t >> 12;
    rb2T[t] = rb2[(size_t)l*4096 + f*64 + c];
  }
}

// ---- K_init: q = embed[Z] ----
__global__ __launch_bounds__(256) void k_init_q(const int* __restrict__ Z,
                                                const float* __restrict__ embed,
                                                float* __restrict__ q, int Ntot)
{
  int t = blockIdx.x * blockDim.x + threadIdx.x;
  if (t >= Ntot * FD) return;
  int n = t >> 6, f = t & 63;
  q[t] = embed[Z[n]*FD + f];
}

// ---- K1: per-atom pre. 16 atoms/block (4 per wave), weights LDS-staged. ----
__global__ __launch_bounds__(256) void k_atom_pre(
    const float* __restrict__ q, const float* __restrict__ mu,
    const float* __restrict__ cW1, const float* __restrict__ cb1,
    const float* __restrict__ cW2, const float* __restrict__ cb2,
    const float* __restrict__ pW1, const float* __restrict__ pb1,
    const float* __restrict__ pW2, const float* __restrict__ pb2,
    float* __restrict__ XCV, int Ntot)
{
  __shared__ float wbuf[12288];     // 48 KB
  __shared__ float qs[16][64];      // 4 KB
  __shared__ float sbuf[16][128];   // 8 KB
  __shared__ float h1s[16][64];     // 4 KB
  __shared__ float hcs[16][32];     // 2 KB
  int t = threadIdx.x;
  int w = t >> 6, f = t & 63;
  int base = blockIdx.x * 16;
  const int aw = w * 4;
  float4* wt4 = (float4*)wbuf;

  float m0a[4], m1a[4], m2a[4], m0b[4], m1b[4], m2b[4];
#pragma unroll
  for (int s = 0; s < 4; ++s){
    int a = aw + s;
    int n = base + a; if (n >= Ntot) n = Ntot - 1;
    qs[a][f] = q[(size_t)n*64 + f];
    const float* mun = mu + (size_t)n * 384;
    m0a[s] = mun[0*128 + f];      m1a[s] = mun[1*128 + f];      m2a[s] = mun[2*128 + f];
    m0b[s] = mun[0*128 + 64 + f]; m1b[s] = mun[1*128 + 64 + f]; m2b[s] = mun[2*128 + 64 + f];
    sbuf[a][f]      = sqrtf(m0a[s]*m0a[s] + m1a[s]*m1a[s] + m2a[s]*m2a[s] + EPSV);
    sbuf[a][64 + f] = sqrtf(m0b[s]*m0b[s] + m1b[s]*m1b[s] + m2b[s]*m2b[s] + EPSV);
  }
#pragma unroll
  for (int i = 0; i < 4; ++i) wt4[t + i*256] = ((const float4*)cW1)[t + i*256];
  __syncthreads();

  float hacc[4];
#pragma unroll
  for (int s = 0; s < 4; ++s) hacc[s] = cb1[f];
  for (int k = 0; k < 64; ++k){
    float wv = wbuf[k*64 + f];
#pragma unroll
    for (int s = 0; s < 4; ++s) hacc[s] = fmaf(qs[aw + s][k], wv, hacc[s]);
  }
#pragma unroll
  for (int s = 0; s < 4; ++s) h1s[aw + s][f] = silu_f(hacc[s]);

  __syncthreads();
#pragma unroll
  for (int i = 0; i < 12; ++i) wt4[t + i*256] = ((const float4*)cW2)[t + i*256];
  __syncthreads();

  float x0[4], x1[4], x2[4];
#pragma unroll
  for (int s = 0; s < 4; ++s){ x0[s] = cb2[f]; x1[s] = cb2[64+f]; x2[s] = cb2[128+f]; }
  for (int k = 0; k < 64; ++k){
    float u0 = wbuf[k*192 + f];
    float u1 = wbuf[k*192 + 64 + f];
    float u2 = wbuf[k*192 + 128 + f];
#pragma unroll
    for (int s = 0; s < 4; ++s){
      float h = h1s[aw + s][k];
      x0[s] = fmaf(h, u0, x0[s]); x1[s] = fmaf(h, u1, x1[s]); x2[s] = fmaf(h, u2, x2[s]);
    }
  }
#pragma unroll
  for (int s = 0; s < 4; ++s){
    int n = base + aw + s;
    if (n < Ntot){
      float* Xn = XCV + (size_t)n*384;
      Xn[f] = x0[s]; Xn[64+f] = x1[s]; Xn[128+f] = x2[s];
    }
  }

  __syncthreads();
#pragma unroll
  for (int i = 0; i < 4; ++i) wt4[t + i*256] = ((const float4*)pW1)[t + i*256];
#pragma unroll
  for (int i = 0; i < 2; ++i) wt4[1024 + t + i*256] = ((const float4*)pW2)[t + i*256];
  __syncthreads();

  int ki = f & 31;
#pragma unroll
  for (int p = 0; p < 2; ++p){
    int a_h = aw + p*2 + (f >> 5);
    float ah = pb1[ki];
#pragma unroll 4
    for (int c = 0; c < 128; ++c) ah = fmaf(sbuf[a_h][c], wbuf[c*32 + ki], ah);
    hcs[a_h][ki] = fmaxf(ah, 0.0f);
  }

  float logit[4];
#pragma unroll
  for (int s = 0; s < 4; ++s) logit[s] = pb2[f];
  for (int k = 0; k < 32; ++k){
    float wv = wbuf[4096 + k*64 + f];
#pragma unroll
    for (int s = 0; s < 4; ++s) logit[s] = fmaf(hcs[aw + s][k], wv, logit[s]);
  }
#pragma unroll
  for (int s = 0; s < 4; ++s){
    float mx = wredmax(logit[s]);
    float e  = __expf(logit[s] - mx);
    float se = wredsum(e);
    float wt = e / se;
    float v0 = wredsum(m0a[s] + m0b[s]);
    float v1 = wredsum(m1a[s] + m1b[s]);
    float v2 = wredsum(m2a[s] + m2b[s]);
    int n = base + aw + s;
    if (n < Ntot){
      float* cvn = XCV + (size_t)n*384 + 192;
      cvn[f] = v0 * wt; cvn[64+f] = v1 * wt; cvn[128+f] = v2 * wt;
    }
  }
}

// ---- K2 v5: gather, round-8 loop structure, CSR-ordered eP/eJ (1-deep chain). ----
__global__ __launch_bounds__(256) void k_gather(
    const float* __restrict__ eP, const int* __restrict__ eJ,
    const int* __restrict__ start,
    const float* __restrict__ fW, const float* __restrict__ fb,
    const float* __restrict__ XCV,
    float* __restrict__ dq, float* __restrict__ dmu, int l, int Ntot)
{
  int w = threadIdx.x >> 6;
  int f = threadIdx.x & 63;
  int i = blockIdx.x * 4 + w;
  if (i >= Ntot) return;
  const int col = l * 192;

  float fw0[NRBF], fw1[NRBF], fw2[NRBF];
#pragma unroll
  for (int r = 0; r < NRBF; ++r){
    const float* fr = fW + r*384 + col;
    fw0[r] = fr[f]; fw1[r] = fr[64 + f]; fw2[r] = fr[128 + f];
  }
  float fb0 = fb[col + f], fb1 = fb[col + 64 + f], fb2 = fb[col + 128 + f];

  float dqa = 0.f, dm0 = 0.f, dm1 = 0.f, dm2 = 0.f;
  int e0 = start[i], e1 = start[i+1];
  int e = e0;
  for (; e + 2 <= e1; e += 2){
    int jA = eJ[e], jB = eJ[e+1];
    const float4* pr = (const float4*)(eP + (size_t)e * 24);
    float4 A0=pr[0],A1=pr[1],A2=pr[2],A3=pr[3],A4=pr[4],A5=pr[5];
    float4 B0=pr[6],B1=pr[7],B2=pr[8],B3=pr[9],B4=pr[10],B5=pr[11];
    const float* xA = XCV + (size_t)jA * 384;
    const float* xB = XCV + (size_t)jB * 384;
    float xA0=xA[f], xA1=xA[64+f], xA2=xA[128+f], cA0=xA[192+f], cA1=xA[256+f], cA2=xA[320+f];
    float xB0=xB[f], xB1=xB[64+f], xB2=xB[128+f], cB0=xB[192+f], cB1=xB[256+f], cB2=xB[320+f];
    float phA[NRBF] = {A1.x,A1.y,A1.z,A1.w, A2.x,A2.y,A2.z,A2.w,
                       A3.x,A3.y,A3.z,A3.w, A4.x,A4.y,A4.z,A4.w,
                       A5.x,A5.y,A5.z,A5.w};
    float phB[NRBF] = {B1.x,B1.y,B1.z,B1.w, B2.x,B2.y,B2.z,B2.w,
                       B3.x,B3.y,B3.z,B3.w, B4.x,B4.y,B4.z,B4.w,
                       B5.x,B5.y,B5.z,B5.w};
    float wA0=fb0*A0.w, wA1=fb1*A0.w, wA2=fb2*A0.w;
    float wB0=fb0*B0.w, wB1=fb1*B0.w, wB2=fb2*B0.w;
#pragma unroll
    for (int r = 0; r < NRBF; ++r){
      wA0 = fmaf(phA[r], fw0[r], wA0);
      wA1 = fmaf(phA[r], fw1[r], wA1);
      wA2 = fmaf(phA[r], fw2[r], wA2);
      wB0 = fmaf(phB[r], fw0[r], wB0);
      wB1 = fmaf(phB[r], fw1[r], wB1);
      wB2 = fmaf(phB[r], fw2[r], wB2);
    }
    dqa = fmaf(xA0, wA0, dqa);
    float dmRA = xA1 * wA1, dmmA = xA2 * wA2;
    dm0 = fmaf(dmRA, A0.x, fmaf(dmmA, cA0, dm0));
    dm1 = fmaf(dmRA, A0.y, fmaf(dmmA, cA1, dm1));
    dm2 = fmaf(dmRA, A0.z, fmaf(dmmA, cA2, dm2));
    dqa = fmaf(xB0, wB0, dqa);
    float dmRB = xB1 * wB1, dmmB = xB2 * wB2;
    dm0 = fmaf(dmRB, B0.x, fmaf(dmmB, cB0, dm0));
    dm1 = fmaf(dmRB, B0.y, fmaf(dmmB, cB1, dm1));
    dm2 = fmaf(dmRB, B0.z, fmaf(dmmB, cB2, dm2));
  }
  if (e < e1){
    int j = eJ[e];
    const float4* pr = (const float4*)(eP + (size_t)e * 24);
    float4 v0 = pr[0], v1 = pr[1], v2 = pr[2], v3 = pr[3], v4 = pr[4], v5 = pr[5];
    const float* xj = XCV + (size_t)j * 384;
    float ph[NRBF] = {v1.x,v1.y,v1.z,v1.w, v2.x,v2.y,v2.z,v2.w,
                      v3.x,v3.y,v3.z,v3.w, v4.x,v4.y,v4.z,v4.w,
                      v5.x,v5.y,v5.z,v5.w};
    float w0 = fb0 * v0.w, w1 = fb1 * v0.w, w2 = fb2 * v0.w;
#pragma unroll
    for (int r = 0; r < NRBF; ++r){
      w0 = fmaf(ph[r], fw0[r], w0);
      w1 = fmaf(ph[r], fw1[r], w1);
      w2 = fmaf(ph[r], fw2[r], w2);
    }
    dqa = fmaf(xj[f], w0, dqa);
    float dmR = xj[64 + f]  * w1;
    float dmm = xj[128 + f] * w2;
    dm0 = fmaf(dmR, v0.x, fmaf(dmm, xj[192 + f], dm0));
    dm1 = fmaf(dmR, v0.y, fmaf(dmm, xj[256 + f], dm1));
    dm2 = fmaf(dmR, v0.z, fmaf(dmm, xj[320 + f], dm2));
  }
  dq[(size_t)i*64 + f] = dqa;
  float* dmn = dmu + (size_t)i*192;
  dmn[f] = dm0; dmn[64 + f] = dm1; dmn[128 + f] = dm2;
}

// ---- K3a: tv with bf16 weight tiles (round-8 v4). 512 thr, 16 atoms/block. ----
__global__ __launch_bounds__(512) void k_tv(
    const float* __restrict__ dmuA, const float* __restrict__ XCV,
    const float* __restrict__ rW1, const float* __restrict__ rb1,
    const unsigned short* __restrict__ rW2S, const float* __restrict__ rb2Tl,
    float* __restrict__ MUI, float* __restrict__ TV, int Ntot)
{
  __shared__ float mus[16][3][64];  // 12 KB
  __shared__ float svs[16][64];     // 4 KB
  __shared__ float4 wt4[2048];      // 32 KB
  __shared__ float rbt[8][64];      // 2 KB
  int t = threadIdx.x;
  int w = t >> 6, f = t & 63;
  int base = blockIdx.x * 16;

#pragma unroll
  for (int s = 0; s < 2; ++s){
    int a = w*2 + s;
    int n = base + a; bool ok = (n < Ntot); if (!ok) n = Ntot - 1;
    const float* dmn = dmuA + (size_t)n*192;
    const float* cvn = XCV  + (size_t)n*384 + 192;
    float m0 = dmn[f]       + cvn[f];
    float m1 = dmn[64 + f]  + cvn[64 + f];
    float m2 = dmn[128 + f] + cvn[128 + f];
    mus[a][0][f] = m0; mus[a][1][f] = m1; mus[a][2][f] = m2;
    svs[a][f] = sqrtf(m0*m0 + m1*m1 + m2*m2 + EPSV);
    if (ok){
      float* mo = MUI + (size_t)n*192;
      mo[f] = m0; mo[64+f] = m1; mo[128+f] = m2;
    }
  }
  __syncthreads();

  int ki = f & 31;
  int a_h = w*2 + (f >> 5);
  float ah = rb1[ki];
#pragma unroll
  for (int c = 0; c < 64; ++c) ah = fmaf(svs[a_h][c], rW1[c*32 + ki], ah);
  ah = fmaxf(ah, 0.0f);
  float hreg[2][32];
#pragma unroll
  for (int k = 0; k < 32; ++k){
    hreg[0][k] = __shfl(ah, k, 64);
    hreg[1][k] = __shfl(ah, 32 + k, 64);
  }

  const int a0 = w*2, a1 = a0 + 1;
  float mf00 = mus[a0][0][f], mf01 = mus[a0][1][f], mf02 = mus[a0][2][f];
  float mf10 = mus[a1][0][f], mf11 = mus[a1][1][f], mf12 = mus[a1][2][f];
  float tv00=0,tv01=0,tv02=0, tv10=0,tv11=0,tv12=0;
  const int sw2 = (f >> 1) & 3;

  for (int ct = 0; ct < 8; ++ct){
    __syncthreads();
    const float4* src = (const float4*)rW2S + (size_t)ct*2048;
#pragma unroll
    for (int i = 0; i < 4; ++i) wt4[t + i*512] = src[t + i*512];
    if (t < 128) ((float4*)rbt)[t] = ((const float4*)(rb2Tl + ct*512))[t];
    __syncthreads();

#pragma unroll
    for (int cc = 0; cc < 8; ++cc){
      int c = ct*8 + cc;
      float u00 = mus[a0][0][c], u01 = mus[a0][1][c], u02 = mus[a0][2][c];
      float u10 = mus[a1][0][c], u11 = mus[a1][1][c], u12 = mus[a1][2][c];
      float g0 = u00*mf00 + u01*mf01 + u02*mf02;
      float g1 = u10*mf10 + u11*mf11 + u12*mf12;
      float acc0 = rbt[cc][f];
      float acc1 = acc0;
      const uint4* wrow = reinterpret_cast<const uint4*>(&wt4[(cc*64 + f)*4]);
#pragma unroll
      for (int kq = 0; kq < 4; ++kq){
        uint4 u = wrow[kq ^ sw2];
        int k0 = kq*8;
        float w0 = BF_LO(u.x), w1 = BF_HI(u.x);
        float w2 = BF_LO(u.y), w3 = BF_HI(u.y);
        float w4 = BF_LO(u.z), w5 = BF_HI(u.z);
        float w6 = BF_LO(u.w), w7 = BF_HI(u.w);
        acc0 = fmaf(hreg[0][k0+0], w0, acc0);
        acc0 = fmaf(hreg[0][k0+1], w1, acc0);
        acc0 = fmaf(hreg[0][k0+2], w2, acc0);
        acc0 = fmaf(hreg[0][k0+3], w3, acc0);
        acc0 = fmaf(hreg[0][k0+4], w4, acc0);
        acc0 = fmaf(hreg[0][k0+5], w5, acc0);
        acc0 = fmaf(hreg[0][k0+6], w6, acc0);
        acc0 = fmaf(hreg[0][k0+7], w7, acc0);
        acc1 = fmaf(hreg[1][k0+0], w0, acc1);
        acc1 = fmaf(hreg[1][k0+1], w1, acc1);
        acc1 = fmaf(hreg[1][k0+2], w2, acc1);
        acc1 = fmaf(hreg[1][k0+3], w3, acc1);
        acc1 = fmaf(hreg[1][k0+4], w4, acc1);
        acc1 = fmaf(hreg[1][k0+5], w5, acc1);
        acc1 = fmaf(hreg[1][k0+6], w6, acc1);
        acc1 = fmaf(hreg[1][k0+7], w7, acc1);
      }
      float mm0 = acc0 * g0, mm1 = acc1 * g1;
      tv00 = fmaf(u00, mm0, tv00); tv01 = fmaf(u01, mm0, tv01); tv02 = fmaf(u02, mm0, tv02);
      tv10 = fmaf(u10, mm1, tv10); tv11 = fmaf(u11, mm1, tv11); tv12 = fmaf(u12, mm1, tv12);
    }
  }

  int n0 = base + a0, n1 = base + a1;
  if (n0 < Ntot){
    float* tvp = TV + (size_t)n0*192;
    tvp[f] = tv00; tvp[64+f] = tv01; tvp[128+f] = tv02;
  }
  if (n1 < Ntot){
    float* tvp = TV + (size_t)n1*192;
    tvp[f] = tv10; tvp[64+f] = tv11; tvp[128+f] = tv12;
  }
}

// ---- K3b: mixing tail. 16 atoms/block (4 per wave), weights LDS-staged. ----
__global__ __launch_bounds__(256) void k_mix2(
    float* __restrict__ q, float* __restrict__ mu,
    const float* __restrict__ dq, const float* __restrict__ MUI, const float* __restrict__ TV,
    const float* __restrict__ mW1, const float* __restrict__ mb1,
    const float* __restrict__ mW2, const float* __restrict__ mb2,
    const float* __restrict__ Wm, int Ntot)
{
  __shared__ float wbuf[12288];     // 48 KB
  __shared__ float mua[16][3][64];  // 12 KB
  __shared__ float ava[16][128];    // 8 KB
  __shared__ float h2a[16][64];     // 4 KB
  int t = threadIdx.x;
  int w = t >> 6, f = t & 63;
  int base = blockIdx.x * 16;
  const int aw = w * 4;
  float4* wt4 = (float4*)wbuf;

  float qv[4], m0[4], m1[4], m2[4];
#pragma unroll
  for (int s = 0; s < 4; ++s){
    int a = aw + s;
    int n = base + a; if (n >= Ntot) n = Ntot - 1;
    qv[s] = q[(size_t)n*64 + f] + dq[(size_t)n*64 + f];
    const float* mi = MUI + (size_t)n*192;
    m0[s] = mi[f]; m1[s] = mi[64 + f]; m2[s] = mi[128 + f];
    mua[a][0][f] = m0[s]; mua[a][1][f] = m1[s]; mua[a][2][f] = m2[s];
  }

#pragma unroll
  for (int i = 0; i < 8; ++i) wt4[t + i*256] = ((const float4*)Wm)[t + i*256];
  __syncthreads();

  float V0[4]={0,0,0,0}, V1[4]={0,0,0,0}, V2[4]={0,0,0,0};
  float W0[4]={0,0,0,0}, W1[4]={0,0,0,0}, W2[4]={0,0,0,0};
  for (int k = 0; k < 64; ++k){
    float wv = wbuf[k*128 + f];
    float ww = wbuf[k*128 + 64 + f];
#pragma unroll
    for (int s = 0; s < 4; ++s){
      int a = aw + s;
      float b0 = mua[a][0][k], b1 = mua[a][1][k], b2 = mua[a][2][k];
      V0[s] = fmaf(b0, wv, V0[s]); V1[s] = fmaf(b1, wv, V1[s]); V2[s] = fmaf(b2, wv, V2[s]);
      W0[s] = fmaf(b0, ww, W0[s]); W1[s] = fmaf(b1, ww, W1[s]); W2[s] = fmaf(b2, ww, W2[s]);
    }
  }
  float dot[4];
#pragma unroll
  for (int s = 0; s < 4; ++s){
    int a = aw + s;
    ava[a][f] = qv[s];
    ava[a][64 + f] = sqrtf(V0[s]*V0[s] + V1[s]*V1[s] + V2[s]*V2[s] + EPSV);
    dot[s] = V0[s]*W0[s] + V1[s]*W1[s] + V2[s]*W2[s];
  }

  __syncthreads();
#pragma unroll
  for (int i = 0; i < 8; ++i) wt4[t + i*256] = ((const float4*)mW1)[t + i*256];
  __syncthreads();

  float acc[4];
#pragma unroll
  for (int s = 0; s < 4; ++s) acc[s] = mb1[f];
  for (int k = 0; k < 128; ++k){
    float wv = wbuf[k*64 + f];
#pragma unroll
    for (int s = 0; s < 4; ++s) acc[s] = fmaf(ava[aw + s][k], wv, acc[s]);
  }
#pragma unroll
  for (int s = 0; s < 4; ++s) h2a[aw + s][f] = silu_f(acc[s]);

  __syncthreads();
#pragma unroll
  for (int i = 0; i < 12; ++i) wt4[t + i*256] = ((const float4*)mW2)[t + i*256];
  __syncthreads();

  float y0[4], y1[4], y2[4];
#pragma unroll
  for (int s = 0; s < 4; ++s){ y0[s] = mb2[f]; y1[s] = mb2[64+f]; y2[s] = mb2[128+f]; }
  for (int k = 0; k < 64; ++k){
    float u0 = wbuf[k*192 + f];
    float u1 = wbuf[k*192 + 64 + f];
    float u2 = wbuf[k*192 + 128 + f];
#pragma unroll
    for (int s = 0; s < 4; ++s){
      float h = h2a[aw + s][k];
      y0[s] = fmaf(h, u0, y0[s]); y1[s] = fmaf(h, u1, y1[s]); y2[s] = fmaf(h, u2, y2[s]);
    }
  }

#pragma unroll
  for (int s = 0; s < 4; ++s){
    int n = base + aw + s;
    if (n < Ntot){
      q[(size_t)n*64 + f] = qv[s] + y0[s] + y2[s]*dot[s];
      const float* tvp = TV + (size_t)n*192;
      float* mun = mu + (size_t)n*384;
      mun[0*128 + f] = fmaf(y1[s], W0[s], m0[s]); mun[0*128 + 64 + f] = tvp[f];
      mun[1*128 + f] = fmaf(y1[s], W1[s], m1[s]); mun[1*128 + 64 + f] = tvp[64+f];
      mun[2*128 + f] = fmaf(y1[s], W2[s], m2[s]); mun[2*128 + 64 + f] = tvp[128+f];
    }
  }
}

extern "C" void kernel_launch(void* const* d_in, const int* in_sizes, int n_in,
                              void* d_out, int out_size, void* d_ws, size_t ws_size,
                              hipStream_t stream)
{
  const int*   Z      = (const int*)  d_in[0];
  const float* Rij    = (const float*)d_in[1];
  const int*   idx_i  = (const int*)  d_in[2];
  const int*   idx_j  = (const int*)  d_in[3];
  const float* embed  = (const float*)d_in[5];
  const float* fW     = (const float*)d_in[6];
  const float* fb     = (const float*)d_in[7];
  const float* ctxW1  = (const float*)d_in[8];
  const float* ctxb1  = (const float*)d_in[9];
  const float* ctxW2  = (const float*)d_in[10];
  const float* ctxb2  = (const float*)d_in[11];
  const float* compW1 = (const float*)d_in[12];
  const float* compb1 = (const float*)d_in[13];
  const float* compW2 = (const float*)d_in[14];
  const float* compb2 = (const float*)d_in[15];
  const float* recW1  = (const float*)d_in[16];
  const float* recb1  = (const float*)d_in[17];
  const float* recW2  = (const float*)d_in[18];
  const float* recb2  = (const float*)d_in[19];
  const float* mixW1  = (const float*)d_in[20];
  const float* mixb1  = (const float*)d_in[21];
  const float* mixW2  = (const float*)d_in[22];
  const float* mixb2  = (const float*)d_in[23];
  const float* muMixW = (const float*)d_in[24];

  const int N = in_sizes[0];
  const int P = in_sizes[1] / 3;

  float* ws    = (float*)d_ws;
  float* eP    = ws;                         // P*24
  float* q     = eP    + (size_t)P*24;       // N*64
  float* mu    = q     + (size_t)N*64;       // N*384
  float* XCV   = mu    + (size_t)N*384;      // N*384
  float* dq    = XCV   + (size_t)N*384;      // N*64
  float* dmu   = dq    + (size_t)N*64;       // N*192
  float* rW2Sf = dmu   + (size_t)N*192;      // bf16 512KB = 131072 floats
  float* rb2T  = rW2Sf + (size_t)131072;     // 8192
  float* TV    = rb2T  + (size_t)8192;       // N*192
  float* MUI   = TV    + (size_t)N*192;      // N*192
  int*   cnt    = (int*)(MUI + (size_t)N*192); // N
  int*   startA = cnt    + N;                  // N+1
  int*   cursor = startA + (N + 1);            // N
  int*   elist  = cursor + N;                  // P
  int*   eJ     = elist  + P;                  // P
  unsigned short* rW2S = (unsigned short*)rW2Sf;

  hipMemsetAsync(mu, 0, (size_t)N*384*sizeof(float), stream);
  hipMemsetAsync(cnt, 0, (size_t)N*sizeof(int), stream);
  k_init_q<<<(N*FD + 255)/256, 256, 0, stream>>>(Z, embed, q, N);
  k_transpose_w<<<(2*64*64*32 + 255)/256, 256, 0, stream>>>(recW2, recb2, rW2S, rb2T);

  // CSR build + CSR-ordered edge records (idx fixed across layers)
  k_count<<<(P + 255)/256, 256, 0, stream>>>(idx_i, cnt, P);
  k_scan<<<1, 1024, 0, stream>>>(cnt, startA, cursor, N);
  k_scatter<<<(P + 255)/256, 256, 0, stream>>>(idx_i, cursor, elist, P);
  k_edgeprep<<<(P + 255)/256, 256, 0, stream>>>(Rij, elist, idx_j, eP, eJ, P);

  const int ablk4  = (N + 3) / 4;
  const int ablk16 = (N + 15) / 16;
  for (int l = 0; l < 2; ++l){
    k_atom_pre<<<ablk16, 256, 0, stream>>>(q, mu,
        ctxW1 + (size_t)l*64*64,  ctxb1 + (size_t)l*64,
        ctxW2 + (size_t)l*64*192, ctxb2 + (size_t)l*192,
        compW1 + (size_t)l*128*32, compb1 + (size_t)l*32,
        compW2 + (size_t)l*32*64,  compb2 + (size_t)l*64,
        XCV, N);
    k_gather<<<ablk4, 256, 0, stream>>>(eP, eJ, startA, fW, fb, XCV,
        dq, dmu, l, N);
    k_tv<<<ablk16, 512, 0, stream>>>(dmu, XCV,
        recW1 + (size_t)l*64*32, recb1 + (size_t)l*32,
        rW2S + (size_t)l*131072, rb2T + (size_t)l*4096,
        MUI, TV, N);
    k_mix2<<<ablk16, 256, 0, stream>>>(q, mu, dq, MUI, TV,
        mixW1 + (size_t)l*128*64, mixb1 + (size_t)l*64,
        mixW2 + (size_t)l*64*192, mixb2 + (size_t)l*192,
        muMixW + (size_t)l*64*128, N);
  }

  hipMemcpyAsync(d_out, q, (size_t)N*64*sizeof(float), hipMemcpyDeviceToDevice, stream);
  hipMemcpyAsync((float*)d_out + (size_t)N*64, mu, (size_t)N*384*sizeof(float),
                 hipMemcpyDeviceToDevice, stream);
}

// Round 11
// 592.210 us; speedup vs baseline: 1.5034x; 1.1166x over previous
//
#include <hip/hip_runtime.h>
#include <math.h>

#define FD 64
#define NRBF 20
#define CUT 5.0f
#define EPSV 1e-8f
#define PI_F 3.14159265358979f

typedef _Float16 h2v __attribute__((ext_vector_type(2)));

__device__ __forceinline__ float wredsum(float v){
#pragma unroll
  for (int m = 32; m >= 1; m >>= 1) v += __shfl_xor(v, m, 64);
  return v;
}
__device__ __forceinline__ float wredmax(float v){
#pragma unroll
  for (int m = 32; m >= 1; m >>= 1) v = fmaxf(v, __shfl_xor(v, m, 64));
  return v;
}
__device__ __forceinline__ float silu_f(float x){ return x * (1.0f / (1.0f + __expf(-x))); }
__device__ __forceinline__ h2v as_h2(unsigned u){
  union { unsigned u; h2v h; } x; x.u = u; return x.h;
}

// ---- CSR build: histogram, scan, scatter ----
__global__ __launch_bounds__(256) void k_count(const int* __restrict__ idx_i,
                                               int* __restrict__ cnt, int P)
{
  int p = blockIdx.x * blockDim.x + threadIdx.x;
  if (p < P) atomicAdd(&cnt[idx_i[p]], 1);
}

__global__ __launch_bounds__(1024) void k_scan(const int* __restrict__ cnt,
                                               int* __restrict__ start,
                                               int* __restrict__ cursor, int N)
{
  __shared__ int part[1024];
  int t = threadIdx.x;
  int chunk = (N + 1023) / 1024;
  int lo = t * chunk, hi = lo + chunk; if (hi > N) hi = N;
  int s = 0;
  for (int i = lo; i < hi; ++i) s += cnt[i];
  part[t] = s;
  __syncthreads();
  for (int off = 1; off < 1024; off <<= 1){
    int v = 0;
    if (t >= off) v = part[t - off];
    __syncthreads();
    if (t >= off) part[t] += v;
    __syncthreads();
  }
  int run = (t == 0) ? 0 : part[t-1];
  for (int i = lo; i < hi; ++i){ start[i] = run; cursor[i] = run; run += cnt[i]; }
  if (t == 1023) start[N] = run;
}

__global__ __launch_bounds__(256) void k_scatter(const int* __restrict__ idx_i,
                                                 int* __restrict__ cursor,
                                                 int* __restrict__ elist, int P)
{
  int p = blockIdx.x * blockDim.x + threadIdx.x;
  if (p < P){
    int pos = atomicAdd(&cursor[idx_i[p]], 1);
    elist[pos] = p;
  }
}

// ---- edge records in CSR order: eP[e][24] = dir(3),fcut,phi*fcut(20); eJ[e]=idx_j ----
__global__ __launch_bounds__(256) void k_edgeprep(const float* __restrict__ Rij,
                                                  const int* __restrict__ elist,
                                                  const int* __restrict__ idx_j,
                                                  float* __restrict__ eP,
                                                  int* __restrict__ eJ, int P)
{
  int e = blockIdx.x * blockDim.x + threadIdx.x;
  if (e >= P) return;
  int p = elist[e];
  eJ[e] = idx_j[p];
  float rx = Rij[3*p+0], ry = Rij[3*p+1], rz = Rij[3*p+2];
  float d = sqrtf(rx*rx + ry*ry + rz*rz);
  float inv = 1.0f / d;
  float fc = (d < CUT) ? 0.5f * (__cosf(PI_F * d / CUT) + 1.0f) : 0.0f;
  float* pr = eP + (size_t)e * 24;
  pr[0] = rx*inv; pr[1] = ry*inv; pr[2] = rz*inv; pr[3] = fc;
  const float width = CUT / (float)(NRBF - 1);
#pragma unroll
  for (int r = 0; r < NRBF; ++r){
    float t = (d - width * (float)r) / width;
    pr[4+r] = __expf(-0.5f * t * t) * fc;
  }
}

// ---- transpose rec_W2 -> swizzled f16 rW2S; rb2 -> rb2T[l][c][f] (f32) ----
// ushort index t: km=t&7, slot=(t>>3)&3, f=(t>>5)&63, c=(t>>11)&63, l=t>>17
// stored k = ((slot ^ ((f>>1)&3))<<3) | km
__global__ __launch_bounds__(256) void k_transpose_w(const float* __restrict__ rW2,
                                                     const float* __restrict__ rb2,
                                                     unsigned short* __restrict__ rW2S,
                                                     float* __restrict__ rb2T)
{
  int t = blockIdx.x * blockDim.x + threadIdx.x;
  if (t < 2*64*64*32){
    int km   = t & 7;
    int slot = (t >> 3) & 3;
    int f    = (t >> 5) & 63;
    int c    = (t >> 11) & 63;
    int l    = t >> 17;
    int k    = ((slot ^ ((f >> 1) & 3)) << 3) | km;
    float v = rW2[((size_t)(l*32 + k))*4096 + f*64 + c];
    _Float16 hv = (_Float16)v;            // RNE f32->f16
    unsigned short us;
    __builtin_memcpy(&us, &hv, 2);
    rW2S[t] = us;
  }
  if (t < 2*64*64){
    int f = t & 63, c = (t >> 6) & 63, l = t >> 12;
    rb2T[t] = rb2[(size_t)l*4096 + f*64 + c];
  }
}

// ---- K_init: q = embed[Z] ----
__global__ __launch_bounds__(256) void k_init_q(const int* __restrict__ Z,
                                                const float* __restrict__ embed,
                                                float* __restrict__ q, int Ntot)
{
  int t = blockIdx.x * blockDim.x + threadIdx.x;
  if (t >= Ntot * FD) return;
  int n = t >> 6, f = t & 63;
  q[t] = embed[Z[n]*FD + f];
}

// ---- K1: per-atom pre. 16 atoms/block (4 per wave), weights LDS-staged. ----
__global__ __launch_bounds__(256) void k_atom_pre(
    const float* __restrict__ q, const float* __restrict__ mu,
    const float* __restrict__ cW1, const float* __restrict__ cb1,
    const float* __restrict__ cW2, const float* __restrict__ cb2,
    const float* __restrict__ pW1, const float* __restrict__ pb1,
    const float* __restrict__ pW2, const float* __restrict__ pb2,
    float* __restrict__ XCV, int Ntot)
{
  __shared__ float wbuf[12288];     // 48 KB
  __shared__ float qs[16][64];      // 4 KB
  __shared__ float sbuf[16][128];   // 8 KB
  __shared__ float h1s[16][64];     // 4 KB
  __shared__ float hcs[16][32];     // 2 KB
  int t = threadIdx.x;
  int w = t >> 6, f = t & 63;
  int base = blockIdx.x * 16;
  const int aw = w * 4;
  float4* wt4 = (float4*)wbuf;

  float m0a[4], m1a[4], m2a[4], m0b[4], m1b[4], m2b[4];
#pragma unroll
  for (int s = 0; s < 4; ++s){
    int a = aw + s;
    int n = base + a; if (n >= Ntot) n = Ntot - 1;
    qs[a][f] = q[(size_t)n*64 + f];
    const float* mun = mu + (size_t)n * 384;
    m0a[s] = mun[0*128 + f];      m1a[s] = mun[1*128 + f];      m2a[s] = mun[2*128 + f];
    m0b[s] = mun[0*128 + 64 + f]; m1b[s] = mun[1*128 + 64 + f]; m2b[s] = mun[2*128 + 64 + f];
    sbuf[a][f]      = sqrtf(m0a[s]*m0a[s] + m1a[s]*m1a[s] + m2a[s]*m2a[s] + EPSV);
    sbuf[a][64 + f] = sqrtf(m0b[s]*m0b[s] + m1b[s]*m1b[s] + m2b[s]*m2b[s] + EPSV);
  }
#pragma unroll
  for (int i = 0; i < 4; ++i) wt4[t + i*256] = ((const float4*)cW1)[t + i*256];
  __syncthreads();

  float hacc[4];
#pragma unroll
  for (int s = 0; s < 4; ++s) hacc[s] = cb1[f];
  for (int k = 0; k < 64; ++k){
    float wv = wbuf[k*64 + f];
#pragma unroll
    for (int s = 0; s < 4; ++s) hacc[s] = fmaf(qs[aw + s][k], wv, hacc[s]);
  }
#pragma unroll
  for (int s = 0; s < 4; ++s) h1s[aw + s][f] = silu_f(hacc[s]);

  __syncthreads();
#pragma unroll
  for (int i = 0; i < 12; ++i) wt4[t + i*256] = ((const float4*)cW2)[t + i*256];
  __syncthreads();

  float x0[4], x1[4], x2[4];
#pragma unroll
  for (int s = 0; s < 4; ++s){ x0[s] = cb2[f]; x1[s] = cb2[64+f]; x2[s] = cb2[128+f]; }
  for (int k = 0; k < 64; ++k){
    float u0 = wbuf[k*192 + f];
    float u1 = wbuf[k*192 + 64 + f];
    float u2 = wbuf[k*192 + 128 + f];
#pragma unroll
    for (int s = 0; s < 4; ++s){
      float h = h1s[aw + s][k];
      x0[s] = fmaf(h, u0, x0[s]); x1[s] = fmaf(h, u1, x1[s]); x2[s] = fmaf(h, u2, x2[s]);
    }
  }
#pragma unroll
  for (int s = 0; s < 4; ++s){
    int n = base + aw + s;
    if (n < Ntot){
      float* Xn = XCV + (size_t)n*384;
      Xn[f] = x0[s]; Xn[64+f] = x1[s]; Xn[128+f] = x2[s];
    }
  }

  __syncthreads();
#pragma unroll
  for (int i = 0; i < 4; ++i) wt4[t + i*256] = ((const float4*)pW1)[t + i*256];
#pragma unroll
  for (int i = 0; i < 2; ++i) wt4[1024 + t + i*256] = ((const float4*)pW2)[t + i*256];
  __syncthreads();

  int ki = f & 31;
#pragma unroll
  for (int p = 0; p < 2; ++p){
    int a_h = aw + p*2 + (f >> 5);
    float ah = pb1[ki];
#pragma unroll 4
    for (int c = 0; c < 128; ++c) ah = fmaf(sbuf[a_h][c], wbuf[c*32 + ki], ah);
    hcs[a_h][ki] = fmaxf(ah, 0.0f);
  }

  float logit[4];
#pragma unroll
  for (int s = 0; s < 4; ++s) logit[s] = pb2[f];
  for (int k = 0; k < 32; ++k){
    float wv = wbuf[4096 + k*64 + f];
#pragma unroll
    for (int s = 0; s < 4; ++s) logit[s] = fmaf(hcs[aw + s][k], wv, logit[s]);
  }
#pragma unroll
  for (int s = 0; s < 4; ++s){
    float mx = wredmax(logit[s]);
    float e  = __expf(logit[s] - mx);
    float se = wredsum(e);
    float wt = e / se;
    float v0 = wredsum(m0a[s] + m0b[s]);
    float v1 = wredsum(m1a[s] + m1b[s]);
    float v2 = wredsum(m2a[s] + m2b[s]);
    int n = base + aw + s;
    if (n < Ntot){
      float* cvn = XCV + (size_t)n*384 + 192;
      cvn[f] = v0 * wt; cvn[64+f] = v1 * wt; cvn[128+f] = v2 * wt;
    }
  }
}

// ---- K2: gather, CSR-ordered eP/eJ (1-deep chain), unroll-2. ----
__global__ __launch_bounds__(256) void k_gather(
    const float* __restrict__ eP, const int* __restrict__ eJ,
    const int* __restrict__ start,
    const float* __restrict__ fW, const float* __restrict__ fb,
    const float* __restrict__ XCV,
    float* __restrict__ dq, float* __restrict__ dmu, int l, int Ntot)
{
  int w = threadIdx.x >> 6;
  int f = threadIdx.x & 63;
  int i = blockIdx.x * 4 + w;
  if (i >= Ntot) return;
  const int col = l * 192;

  float fw0[NRBF], fw1[NRBF], fw2[NRBF];
#pragma unroll
  for (int r = 0; r < NRBF; ++r){
    const float* fr = fW + r*384 + col;
    fw0[r] = fr[f]; fw1[r] = fr[64 + f]; fw2[r] = fr[128 + f];
  }
  float fb0 = fb[col + f], fb1 = fb[col + 64 + f], fb2 = fb[col + 128 + f];

  float dqa = 0.f, dm0 = 0.f, dm1 = 0.f, dm2 = 0.f;
  int e0 = start[i], e1 = start[i+1];
  int e = e0;
  for (; e + 2 <= e1; e += 2){
    int jA = eJ[e], jB = eJ[e+1];
    const float4* pr = (const float4*)(eP + (size_t)e * 24);
    float4 A0=pr[0],A1=pr[1],A2=pr[2],A3=pr[3],A4=pr[4],A5=pr[5];
    float4 B0=pr[6],B1=pr[7],B2=pr[8],B3=pr[9],B4=pr[10],B5=pr[11];
    const float* xA = XCV + (size_t)jA * 384;
    const float* xB = XCV + (size_t)jB * 384;
    float xA0=xA[f], xA1=xA[64+f], xA2=xA[128+f], cA0=xA[192+f], cA1=xA[256+f], cA2=xA[320+f];
    float xB0=xB[f], xB1=xB[64+f], xB2=xB[128+f], cB0=xB[192+f], cB1=xB[256+f], cB2=xB[320+f];
    float phA[NRBF] = {A1.x,A1.y,A1.z,A1.w, A2.x,A2.y,A2.z,A2.w,
                       A3.x,A3.y,A3.z,A3.w, A4.x,A4.y,A4.z,A4.w,
                       A5.x,A5.y,A5.z,A5.w};
    float phB[NRBF] = {B1.x,B1.y,B1.z,B1.w, B2.x,B2.y,B2.z,B2.w,
                       B3.x,B3.y,B3.z,B3.w, B4.x,B4.y,B4.z,B4.w,
                       B5.x,B5.y,B5.z,B5.w};
    float wA0=fb0*A0.w, wA1=fb1*A0.w, wA2=fb2*A0.w;
    float wB0=fb0*B0.w, wB1=fb1*B0.w, wB2=fb2*B0.w;
#pragma unroll
    for (int r = 0; r < NRBF; ++r){
      wA0 = fmaf(phA[r], fw0[r], wA0);
      wA1 = fmaf(phA[r], fw1[r], wA1);
      wA2 = fmaf(phA[r], fw2[r], wA2);
      wB0 = fmaf(phB[r], fw0[r], wB0);
      wB1 = fmaf(phB[r], fw1[r], wB1);
      wB2 = fmaf(phB[r], fw2[r], wB2);
    }
    dqa = fmaf(xA0, wA0, dqa);
    float dmRA = xA1 * wA1, dmmA = xA2 * wA2;
    dm0 = fmaf(dmRA, A0.x, fmaf(dmmA, cA0, dm0));
    dm1 = fmaf(dmRA, A0.y, fmaf(dmmA, cA1, dm1));
    dm2 = fmaf(dmRA, A0.z, fmaf(dmmA, cA2, dm2));
    dqa = fmaf(xB0, wB0, dqa);
    float dmRB = xB1 * wB1, dmmB = xB2 * wB2;
    dm0 = fmaf(dmRB, B0.x, fmaf(dmmB, cB0, dm0));
    dm1 = fmaf(dmRB, B0.y, fmaf(dmmB, cB1, dm1));
    dm2 = fmaf(dmRB, B0.z, fmaf(dmmB, cB2, dm2));
  }
  if (e < e1){
    int j = eJ[e];
    const float4* pr = (const float4*)(eP + (size_t)e * 24);
    float4 v0 = pr[0], v1 = pr[1], v2 = pr[2], v3 = pr[3], v4 = pr[4], v5 = pr[5];
    const float* xj = XCV + (size_t)j * 384;
    float ph[NRBF] = {v1.x,v1.y,v1.z,v1.w, v2.x,v2.y,v2.z,v2.w,
                      v3.x,v3.y,v3.z,v3.w, v4.x,v4.y,v4.z,v4.w,
                      v5.x,v5.y,v5.z,v5.w};
    float w0 = fb0 * v0.w, w1 = fb1 * v0.w, w2 = fb2 * v0.w;
#pragma unroll
    for (int r = 0; r < NRBF; ++r){
      w0 = fmaf(ph[r], fw0[r], w0);
      w1 = fmaf(ph[r], fw1[r], w1);
      w2 = fmaf(ph[r], fw2[r], w2);
    }
    dqa = fmaf(xj[f], w0, dqa);
    float dmR = xj[64 + f]  * w1;
    float dmm = xj[128 + f] * w2;
    dm0 = fmaf(dmR, v0.x, fmaf(dmm, xj[192 + f], dm0));
    dm1 = fmaf(dmR, v0.y, fmaf(dmm, xj[256 + f], dm1));
    dm2 = fmaf(dmR, v0.z, fmaf(dmm, xj[320 + f], dm2));
  }
  dq[(size_t)i*64 + f] = dqa;
  float* dmn = dmu + (size_t)i*192;
  dmn[f] = dm0; dmn[64 + f] = dm1; dmn[128 + f] = dm2;
}

// ---- K3a v6: tv with f16 weight tiles + v_dot2_f32_f16. 512 thr, 16 atoms/block. ----
__global__ __launch_bounds__(512) void k_tv(
    const float* __restrict__ dmuA, const float* __restrict__ XCV,
    const float* __restrict__ rW1, const float* __restrict__ rb1,
    const unsigned short* __restrict__ rW2S, const float* __restrict__ rb2Tl,
    float* __restrict__ MUI, float* __restrict__ TV, int Ntot)
{
  __shared__ float mus[16][3][64];  // 12 KB
  __shared__ float svs[16][64];     // 4 KB
  __shared__ float4 wt4[2048];      // 32 KB
  __shared__ float rbt[8][64];      // 2 KB
  int t = threadIdx.x;
  int w = t >> 6, f = t & 63;
  int base = blockIdx.x * 16;

#pragma unroll
  for (int s = 0; s < 2; ++s){
    int a = w*2 + s;
    int n = base + a; bool ok = (n < Ntot); if (!ok) n = Ntot - 1;
    const float* dmn = dmuA + (size_t)n*192;
    const float* cvn = XCV  + (size_t)n*384 + 192;
    float m0 = dmn[f]       + cvn[f];
    float m1 = dmn[64 + f]  + cvn[64 + f];
    float m2 = dmn[128 + f] + cvn[128 + f];
    mus[a][0][f] = m0; mus[a][1][f] = m1; mus[a][2][f] = m2;
    svs[a][f] = sqrtf(m0*m0 + m1*m1 + m2*m2 + EPSV);
    if (ok){
      float* mo = MUI + (size_t)n*192;
      mo[f] = m0; mo[64+f] = m1; mo[128+f] = m2;
    }
  }
  __syncthreads();

  int ki = f & 31;
  int a_h = w*2 + (f >> 5);
  float ah = rb1[ki];
#pragma unroll
  for (int c = 0; c < 64; ++c) ah = fmaf(svs[a_h][c], rW1[c*32 + ki], ah);
  ah = fmaxf(ah, 0.0f);
  // pack h pairs (f16) for both atoms: hpk[a][j] = (h[2j], h[2j+1])
  unsigned hpk0[16], hpk1[16];
#pragma unroll
  for (int k = 0; k < 16; ++k){
    float a0 = __shfl(ah, 2*k, 64),      b0 = __shfl(ah, 2*k + 1, 64);
    float a1 = __shfl(ah, 32 + 2*k, 64), b1 = __shfl(ah, 32 + 2*k + 1, 64);
    hpk0[k] = __builtin_bit_cast(unsigned, __builtin_amdgcn_cvt_pkrtz(a0, b0));
    hpk1[k] = __builtin_bit_cast(unsigned, __builtin_amdgcn_cvt_pkrtz(a1, b1));
  }

  const int a0i = w*2, a1i = a0i + 1;
  float mf00 = mus[a0i][0][f], mf01 = mus[a0i][1][f], mf02 = mus[a0i][2][f];
  float mf10 = mus[a1i][0][f], mf11 = mus[a1i][1][f], mf12 = mus[a1i][2][f];
  float tv00=0,tv01=0,tv02=0, tv10=0,tv11=0,tv12=0;
  const int sw2 = (f >> 1) & 3;

  for (int ct = 0; ct < 8; ++ct){
    __syncthreads();
    const float4* src = (const float4*)rW2S + (size_t)ct*2048;
#pragma unroll
    for (int i = 0; i < 4; ++i) wt4[t + i*512] = src[t + i*512];
    if (t < 128) ((float4*)rbt)[t] = ((const float4*)(rb2Tl + ct*512))[t];
    __syncthreads();

#pragma unroll
    for (int cc = 0; cc < 8; ++cc){
      int c = ct*8 + cc;
      float u00 = mus[a0i][0][c], u01 = mus[a0i][1][c], u02 = mus[a0i][2][c];
      float u10 = mus[a1i][0][c], u11 = mus[a1i][1][c], u12 = mus[a1i][2][c];
      float g0 = u00*mf00 + u01*mf01 + u02*mf02;
      float g1 = u10*mf10 + u11*mf11 + u12*mf12;
      float acc0 = rbt[cc][f];
      float acc1 = acc0;
      const uint4* wrow = reinterpret_cast<const uint4*>(&wt4[(cc*64 + f)*4]);
#pragma unroll
      for (int kq = 0; kq < 4; ++kq){
        uint4 u = wrow[kq ^ sw2];
        int k0 = kq*4;
        acc0 = __builtin_amdgcn_fdot2(as_h2(u.x), as_h2(hpk0[k0+0]), acc0, false);
        acc0 = __builtin_amdgcn_fdot2(as_h2(u.y), as_h2(hpk0[k0+1]), acc0, false);
        acc0 = __builtin_amdgcn_fdot2(as_h2(u.z), as_h2(hpk0[k0+2]), acc0, false);
        acc0 = __builtin_amdgcn_fdot2(as_h2(u.w), as_h2(hpk0[k0+3]), acc0, false);
        acc1 = __builtin_amdgcn_fdot2(as_h2(u.x), as_h2(hpk1[k0+0]), acc1, false);
        acc1 = __builtin_amdgcn_fdot2(as_h2(u.y), as_h2(hpk1[k0+1]), acc1, false);
        acc1 = __builtin_amdgcn_fdot2(as_h2(u.z), as_h2(hpk1[k0+2]), acc1, false);
        acc1 = __builtin_amdgcn_fdot2(as_h2(u.w), as_h2(hpk1[k0+3]), acc1, false);
      }
      float mm0 = acc0 * g0, mm1 = acc1 * g1;
      tv00 = fmaf(u00, mm0, tv00); tv01 = fmaf(u01, mm0, tv01); tv02 = fmaf(u02, mm0, tv02);
      tv10 = fmaf(u10, mm1, tv10); tv11 = fmaf(u11, mm1, tv11); tv12 = fmaf(u12, mm1, tv12);
    }
  }

  int n0 = base + a0i, n1 = base + a1i;
  if (n0 < Ntot){
    float* tvp = TV + (size_t)n0*192;
    tvp[f] = tv00; tvp[64+f] = tv01; tvp[128+f] = tv02;
  }
  if (n1 < Ntot){
    float* tvp = TV + (size_t)n1*192;
    tvp[f] = tv10; tvp[64+f] = tv11; tvp[128+f] = tv12;
  }
}

// ---- K3b: mixing tail. 16 atoms/block (4 per wave), weights LDS-staged. ----
__global__ __launch_bounds__(256) void k_mix2(
    float* __restrict__ q, float* __restrict__ mu,
    const float* __restrict__ dq, const float* __restrict__ MUI, const float* __restrict__ TV,
    const float* __restrict__ mW1, const float* __restrict__ mb1,
    const float* __restrict__ mW2, const float* __restrict__ mb2,
    const float* __restrict__ Wm, int Ntot)
{
  __shared__ float wbuf[12288];     // 48 KB
  __shared__ float mua[16][3][64];  // 12 KB
  __shared__ float ava[16][128];    // 8 KB
  __shared__ float h2a[16][64];     // 4 KB
  int t = threadIdx.x;
  int w = t >> 6, f = t & 63;
  int base = blockIdx.x * 16;
  const int aw = w * 4;
  float4* wt4 = (float4*)wbuf;

  float qv[4], m0[4], m1[4], m2[4];
#pragma unroll
  for (int s = 0; s < 4; ++s){
    int a = aw + s;
    int n = base + a; if (n >= Ntot) n = Ntot - 1;
    qv[s] = q[(size_t)n*64 + f] + dq[(size_t)n*64 + f];
    const float* mi = MUI + (size_t)n*192;
    m0[s] = mi[f]; m1[s] = mi[64 + f]; m2[s] = mi[128 + f];
    mua[a][0][f] = m0[s]; mua[a][1][f] = m1[s]; mua[a][2][f] = m2[s];
  }

#pragma unroll
  for (int i = 0; i < 8; ++i) wt4[t + i*256] = ((const float4*)Wm)[t + i*256];
  __syncthreads();

  float V0[4]={0,0,0,0}, V1[4]={0,0,0,0}, V2[4]={0,0,0,0};
  float W0[4]={0,0,0,0}, W1[4]={0,0,0,0}, W2[4]={0,0,0,0};
  for (int k = 0; k < 64; ++k){
    float wv = wbuf[k*128 + f];
    float ww = wbuf[k*128 + 64 + f];
#pragma unroll
    for (int s = 0; s < 4; ++s){
      int a = aw + s;
      float b0 = mua[a][0][k], b1 = mua[a][1][k], b2 = mua[a][2][k];
      V0[s] = fmaf(b0, wv, V0[s]); V1[s] = fmaf(b1, wv, V1[s]); V2[s] = fmaf(b2, wv, V2[s]);
      W0[s] = fmaf(b0, ww, W0[s]); W1[s] = fmaf(b1, ww, W1[s]); W2[s] = fmaf(b2, ww, W2[s]);
    }
  }
  float dot[4];
#pragma unroll
  for (int s = 0; s < 4; ++s){
    int a = aw + s;
    ava[a][f] = qv[s];
    ava[a][64 + f] = sqrtf(V0[s]*V0[s] + V1[s]*V1[s] + V2[s]*V2[s] + EPSV);
    dot[s] = V0[s]*W0[s] + V1[s]*W1[s] + V2[s]*W2[s];
  }

  __syncthreads();
#pragma unroll
  for (int i = 0; i < 8; ++i) wt4[t + i*256] = ((const float4*)mW1)[t + i*256];
  __syncthreads();

  float acc[4];
#pragma unroll
  for (int s = 0; s < 4; ++s) acc[s] = mb1[f];
  for (int k = 0; k < 128; ++k){
    float wv = wbuf[k*64 + f];
#pragma unroll
    for (int s = 0; s < 4; ++s) acc[s] = fmaf(ava[aw + s][k], wv, acc[s]);
  }
#pragma unroll
  for (int s = 0; s < 4; ++s) h2a[aw + s][f] = silu_f(acc[s]);

  __syncthreads();
#pragma unroll
  for (int i = 0; i < 12; ++i) wt4[t + i*256] = ((const float4*)mW2)[t + i*256];
  __syncthreads();

  float y0[4], y1[4], y2[4];
#pragma unroll
  for (int s = 0; s < 4; ++s){ y0[s] = mb2[f]; y1[s] = mb2[64+f]; y2[s] = mb2[128+f]; }
  for (int k = 0; k < 64; ++k){
    float u0 = wbuf[k*192 + f];
    float u1 = wbuf[k*192 + 64 + f];
    float u2 = wbuf[k*192 + 128 + f];
#pragma unroll
    for (int s = 0; s < 4; ++s){
      float h = h2a[aw + s][k];
      y0[s] = fmaf(h, u0, y0[s]); y1[s] = fmaf(h, u1, y1[s]); y2[s] = fmaf(h, u2, y2[s]);
    }
  }

#pragma unroll
  for (int s = 0; s < 4; ++s){
    int n = base + aw + s;
    if (n < Ntot){
      q[(size_t)n*64 + f] = qv[s] + y0[s] + y2[s]*dot[s];
      const float* tvp = TV + (size_t)n*192;
      float* mun = mu + (size_t)n*384;
      mun[0*128 + f] = fmaf(y1[s], W0[s], m0[s]); mun[0*128 + 64 + f] = tvp[f];
      mun[1*128 + f] = fmaf(y1[s], W1[s], m1[s]); mun[1*128 + 64 + f] = tvp[64+f];
      mun[2*128 + f] = fmaf(y1[s], W2[s], m2[s]); mun[2*128 + 64 + f] = tvp[128+f];
    }
  }
}

extern "C" void kernel_launch(void* const* d_in, const int* in_sizes, int n_in,
                              void* d_out, int out_size, void* d_ws, size_t ws_size,
                              hipStream_t stream)
{
  const int*   Z      = (const int*)  d_in[0];
  const float* Rij    = (const float*)d_in[1];
  const int*   idx_i  = (const int*)  d_in[2];
  const int*   idx_j  = (const int*)  d_in[3];
  const float* embed  = (const float*)d_in[5];
  const float* fW     = (const float*)d_in[6];
  const float* fb     = (const float*)d_in[7];
  const float* ctxW1  = (const float*)d_in[8];
  const float* ctxb1  = (const float*)d_in[9];
  const float* ctxW2  = (const float*)d_in[10];
  const float* ctxb2  = (const float*)d_in[11];
  const float* compW1 = (const float*)d_in[12];
  const float* compb1 = (const float*)d_in[13];
  const float* compW2 = (const float*)d_in[14];
  const float* compb2 = (const float*)d_in[15];
  const float* recW1  = (const float*)d_in[16];
  const float* recb1  = (const float*)d_in[17];
  const float* recW2  = (const float*)d_in[18];
  const float* recb2  = (const float*)d_in[19];
  const float* mixW1  = (const float*)d_in[20];
  const float* mixb1  = (const float*)d_in[21];
  const float* mixW2  = (const float*)d_in[22];
  const float* mixb2  = (const float*)d_in[23];
  const float* muMixW = (const float*)d_in[24];

  const int N = in_sizes[0];
  const int P = in_sizes[1] / 3;

  float* ws    = (float*)d_ws;
  float* eP    = ws;                         // P*24
  float* q     = eP    + (size_t)P*24;       // N*64
  float* mu    = q     + (size_t)N*64;       // N*384
  float* XCV   = mu    + (size_t)N*384;      // N*384
  float* dq    = XCV   + (size_t)N*384;      // N*64
  float* dmu   = dq    + (size_t)N*64;       // N*192
  float* rW2Sf = dmu   + (size_t)N*192;      // f16 512KB = 131072 floats
  float* rb2T  = rW2Sf + (size_t)131072;     // 8192
  float* TV    = rb2T  + (size_t)8192;       // N*192
  float* MUI   = TV    + (size_t)N*192;      // N*192
  int*   cnt    = (int*)(MUI + (size_t)N*192); // N
  int*   startA = cnt    + N;                  // N+1
  int*   cursor = startA + (N + 1);            // N
  int*   elist  = cursor + N;                  // P
  int*   eJ     = elist  + P;                  // P
  unsigned short* rW2S = (unsigned short*)rW2Sf;

  hipMemsetAsync(mu, 0, (size_t)N*384*sizeof(float), stream);
  hipMemsetAsync(cnt, 0, (size_t)N*sizeof(int), stream);
  k_init_q<<<(N*FD + 255)/256, 256, 0, stream>>>(Z, embed, q, N);
  k_transpose_w<<<(2*64*64*32 + 255)/256, 256, 0, stream>>>(recW2, recb2, rW2S, rb2T);

  // CSR build + CSR-ordered edge records (idx fixed across layers)
  k_count<<<(P + 255)/256, 256, 0, stream>>>(idx_i, cnt, P);
  k_scan<<<1, 1024, 0, stream>>>(cnt, startA, cursor, N);
  k_scatter<<<(P + 255)/256, 256, 0, stream>>>(idx_i, cursor, elist, P);
  k_edgeprep<<<(P + 255)/256, 256, 0, stream>>>(Rij, elist, idx_j, eP, eJ, P);

  const int ablk4  = (N + 3) / 4;
  const int ablk16 = (N + 15) / 16;
  for (int l = 0; l < 2; ++l){
    k_atom_pre<<<ablk16, 256, 0, stream>>>(q, mu,
        ctxW1 + (size_t)l*64*64,  ctxb1 + (size_t)l*64,
        ctxW2 + (size_t)l*64*192, ctxb2 + (size_t)l*192,
        compW1 + (size_t)l*128*32, compb1 + (size_t)l*32,
        compW2 + (size_t)l*32*64,  compb2 + (size_t)l*64,
        XCV, N);
    k_gather<<<ablk4, 256, 0, stream>>>(eP, eJ, startA, fW, fb, XCV,
        dq, dmu, l, N);
    k_tv<<<ablk16, 512, 0, stream>>>(dmu, XCV,
        recW1 + (size_t)l*64*32, recb1 + (size_t)l*32,
        rW2S + (size_t)l*131072, rb2T + (size_t)l*4096,
        MUI, TV, N);
    k_mix2<<<ablk16, 256, 0, stream>>>(q, mu, dq, MUI, TV,
        mixW1 + (size_t)l*128*64, mixb1 + (size_t)l*64,
        mixW2 + (size_t)l*64*192, mixb2 + (size_t)l*192,
        muMixW + (size_t)l*64*128, N);
  }

  hipMemcpyAsync(d_out, q, (size_t)N*64*sizeof(float), hipMemcpyDeviceToDevice, stream);
  hipMemcpyAsync((float*)d_out + (size_t)N*64, mu, (size_t)N*384*sizeof(float),
                 hipMemcpyDeviceToDevice, stream);
}

// Round 12
// 554.911 us; speedup vs baseline: 1.6044x; 1.0672x over previous
//
#include <hip/hip_runtime.h>
#include <math.h>

#define FD 64
#define NRBF 20
#define CUT 5.0f
#define EPSV 1e-8f
#define PI_F 3.14159265358979f

typedef _Float16 h2v __attribute__((ext_vector_type(2)));

__device__ __forceinline__ float wredsum(float v){
#pragma unroll
  for (int m = 32; m >= 1; m >>= 1) v += __shfl_xor(v, m, 64);
  return v;
}
__device__ __forceinline__ float wredmax(float v){
#pragma unroll
  for (int m = 32; m >= 1; m >>= 1) v = fmaxf(v, __shfl_xor(v, m, 64));
  return v;
}
__device__ __forceinline__ float silu_f(float x){ return x * (1.0f / (1.0f + __expf(-x))); }
__device__ __forceinline__ h2v as_h2(unsigned u){
  union { unsigned u; h2v h; } x; x.u = u; return x.h;
}

// ---- CSR build: histogram, scan, scatter ----
__global__ __launch_bounds__(256) void k_count(const int* __restrict__ idx_i,
                                               int* __restrict__ cnt, int P)
{
  int p = blockIdx.x * blockDim.x + threadIdx.x;
  if (p < P) atomicAdd(&cnt[idx_i[p]], 1);
}

__global__ __launch_bounds__(1024) void k_scan(const int* __restrict__ cnt,
                                               int* __restrict__ start,
                                               int* __restrict__ cursor, int N)
{
  __shared__ int part[1024];
  int t = threadIdx.x;
  int chunk = (N + 1023) / 1024;
  int lo = t * chunk, hi = lo + chunk; if (hi > N) hi = N;
  int s = 0;
  for (int i = lo; i < hi; ++i) s += cnt[i];
  part[t] = s;
  __syncthreads();
  for (int off = 1; off < 1024; off <<= 1){
    int v = 0;
    if (t >= off) v = part[t - off];
    __syncthreads();
    if (t >= off) part[t] += v;
    __syncthreads();
  }
  int run = (t == 0) ? 0 : part[t-1];
  for (int i = lo; i < hi; ++i){ start[i] = run; cursor[i] = run; run += cnt[i]; }
  if (t == 1023) start[N] = run;
}

__global__ __launch_bounds__(256) void k_scatter(const int* __restrict__ idx_i,
                                                 int* __restrict__ cursor,
                                                 int* __restrict__ elist, int P)
{
  int p = blockIdx.x * blockDim.x + threadIdx.x;
  if (p < P){
    int pos = atomicAdd(&cursor[idx_i[p]], 1);
    elist[pos] = p;
  }
}

// ---- edge records in CSR order: eP[e][24] = dir(3),fcut,phi*fcut(20); eJ[e]=idx_j ----
__global__ __launch_bounds__(256) void k_edgeprep(const float* __restrict__ Rij,
                                                  const int* __restrict__ elist,
                                                  const int* __restrict__ idx_j,
                                                  float* __restrict__ eP,
                                                  int* __restrict__ eJ, int P)
{
  int e = blockIdx.x * blockDim.x + threadIdx.x;
  if (e >= P) return;
  int p = elist[e];
  eJ[e] = idx_j[p];
  float rx = Rij[3*p+0], ry = Rij[3*p+1], rz = Rij[3*p+2];
  float d = sqrtf(rx*rx + ry*ry + rz*rz);
  float inv = 1.0f / d;
  float fc = (d < CUT) ? 0.5f * (__cosf(PI_F * d / CUT) + 1.0f) : 0.0f;
  float* pr = eP + (size_t)e * 24;
  pr[0] = rx*inv; pr[1] = ry*inv; pr[2] = rz*inv; pr[3] = fc;
  const float width = CUT / (float)(NRBF - 1);
#pragma unroll
  for (int r = 0; r < NRBF; ++r){
    float t = (d - width * (float)r) / width;
    pr[4+r] = __expf(-0.5f * t * t) * fc;
  }
}

// ---- transpose rec_W2 -> f16 rW2S in [l][c][kq][f][8] layout (conflict-free b128);
//      rb2 -> rb2T[l][c][f] (f32) ----
// ushort index t: km=t&7, f=(t>>3)&63, kq=(t>>9)&3, c=(t>>11)&63, l=t>>17; k=kq*8+km
__global__ __launch_bounds__(256) void k_transpose_w(const float* __restrict__ rW2,
                                                     const float* __restrict__ rb2,
                                                     unsigned short* __restrict__ rW2S,
                                                     float* __restrict__ rb2T)
{
  int t = blockIdx.x * blockDim.x + threadIdx.x;
  if (t < 2*64*64*32){
    int km = t & 7;
    int f  = (t >> 3) & 63;
    int kq = (t >> 9) & 3;
    int c  = (t >> 11) & 63;
    int l  = t >> 17;
    int k  = kq*8 + km;
    float v = rW2[((size_t)(l*32 + k))*4096 + f*64 + c];
    _Float16 hv = (_Float16)v;            // RNE f32->f16
    unsigned short us;
    __builtin_memcpy(&us, &hv, 2);
    rW2S[t] = us;
  }
  if (t < 2*64*64){
    int f = t & 63, c = (t >> 6) & 63, l = t >> 12;
    rb2T[t] = rb2[(size_t)l*4096 + f*64 + c];
  }
}

// ---- K_init: q = embed[Z] ----
__global__ __launch_bounds__(256) void k_init_q(const int* __restrict__ Z,
                                                const float* __restrict__ embed,
                                                float* __restrict__ q, int Ntot)
{
  int t = blockIdx.x * blockDim.x + threadIdx.x;
  if (t >= Ntot * FD) return;
  int n = t >> 6, f = t & 63;
  q[t] = embed[Z[n]*FD + f];
}

// ---- K1: per-atom pre. 16 atoms/block (4 per wave), weights LDS-staged. ----
__global__ __launch_bounds__(256) void k_atom_pre(
    const float* __restrict__ q, const float* __restrict__ mu,
    const float* __restrict__ cW1, const float* __restrict__ cb1,
    const float* __restrict__ cW2, const float* __restrict__ cb2,
    const float* __restrict__ pW1, const float* __restrict__ pb1,
    const float* __restrict__ pW2, const float* __restrict__ pb2,
    float* __restrict__ XCV, int Ntot)
{
  __shared__ float wbuf[12288];     // 48 KB
  __shared__ float qs[16][64];      // 4 KB
  __shared__ float sbuf[16][128];   // 8 KB
  __shared__ float h1s[16][64];     // 4 KB
  __shared__ float hcs[16][32];     // 2 KB
  int t = threadIdx.x;
  int w = t >> 6, f = t & 63;
  int base = blockIdx.x * 16;
  const int aw = w * 4;
  float4* wt4 = (float4*)wbuf;

  float m0a[4], m1a[4], m2a[4], m0b[4], m1b[4], m2b[4];
#pragma unroll
  for (int s = 0; s < 4; ++s){
    int a = aw + s;
    int n = base + a; if (n >= Ntot) n = Ntot - 1;
    qs[a][f] = q[(size_t)n*64 + f];
    const float* mun = mu + (size_t)n * 384;
    m0a[s] = mun[0*128 + f];      m1a[s] = mun[1*128 + f];      m2a[s] = mun[2*128 + f];
    m0b[s] = mun[0*128 + 64 + f]; m1b[s] = mun[1*128 + 64 + f]; m2b[s] = mun[2*128 + 64 + f];
    sbuf[a][f]      = sqrtf(m0a[s]*m0a[s] + m1a[s]*m1a[s] + m2a[s]*m2a[s] + EPSV);
    sbuf[a][64 + f] = sqrtf(m0b[s]*m0b[s] + m1b[s]*m1b[s] + m2b[s]*m2b[s] + EPSV);
  }
#pragma unroll
  for (int i = 0; i < 4; ++i) wt4[t + i*256] = ((const float4*)cW1)[t + i*256];
  __syncthreads();

  float hacc[4];
#pragma unroll
  for (int s = 0; s < 4; ++s) hacc[s] = cb1[f];
  for (int k = 0; k < 64; ++k){
    float wv = wbuf[k*64 + f];
#pragma unroll
    for (int s = 0; s < 4; ++s) hacc[s] = fmaf(qs[aw + s][k], wv, hacc[s]);
  }
#pragma unroll
  for (int s = 0; s < 4; ++s) h1s[aw + s][f] = silu_f(hacc[s]);

  __syncthreads();
#pragma unroll
  for (int i = 0; i < 12; ++i) wt4[t + i*256] = ((const float4*)cW2)[t + i*256];
  __syncthreads();

  float x0[4], x1[4], x2[4];
#pragma unroll
  for (int s = 0; s < 4; ++s){ x0[s] = cb2[f]; x1[s] = cb2[64+f]; x2[s] = cb2[128+f]; }
  for (int k = 0; k < 64; ++k){
    float u0 = wbuf[k*192 + f];
    float u1 = wbuf[k*192 + 64 + f];
    float u2 = wbuf[k*192 + 128 + f];
#pragma unroll
    for (int s = 0; s < 4; ++s){
      float h = h1s[aw + s][k];
      x0[s] = fmaf(h, u0, x0[s]); x1[s] = fmaf(h, u1, x1[s]); x2[s] = fmaf(h, u2, x2[s]);
    }
  }
#pragma unroll
  for (int s = 0; s < 4; ++s){
    int n = base + aw + s;
    if (n < Ntot){
      float* Xn = XCV + (size_t)n*384;
      Xn[f] = x0[s]; Xn[64+f] = x1[s]; Xn[128+f] = x2[s];
    }
  }

  __syncthreads();
#pragma unroll
  for (int i = 0; i < 4; ++i) wt4[t + i*256] = ((const float4*)pW1)[t + i*256];
#pragma unroll
  for (int i = 0; i < 2; ++i) wt4[1024 + t + i*256] = ((const float4*)pW2)[t + i*256];
  __syncthreads();

  int ki = f & 31;
#pragma unroll
  for (int p = 0; p < 2; ++p){
    int a_h = aw + p*2 + (f >> 5);
    float ah = pb1[ki];
#pragma unroll 4
    for (int c = 0; c < 128; ++c) ah = fmaf(sbuf[a_h][c], wbuf[c*32 + ki], ah);
    hcs[a_h][ki] = fmaxf(ah, 0.0f);
  }

  float logit[4];
#pragma unroll
  for (int s = 0; s < 4; ++s) logit[s] = pb2[f];
  for (int k = 0; k < 32; ++k){
    float wv = wbuf[4096 + k*64 + f];
#pragma unroll
    for (int s = 0; s < 4; ++s) logit[s] = fmaf(hcs[aw + s][k], wv, logit[s]);
  }
#pragma unroll
  for (int s = 0; s < 4; ++s){
    float mx = wredmax(logit[s]);
    float e  = __expf(logit[s] - mx);
    float se = wredsum(e);
    float wt = e / se;
    float v0 = wredsum(m0a[s] + m0b[s]);
    float v1 = wredsum(m1a[s] + m1b[s]);
    float v2 = wredsum(m2a[s] + m2b[s]);
    int n = base + aw + s;
    if (n < Ntot){
      float* cvn = XCV + (size_t)n*384 + 192;
      cvn[f] = v0 * wt; cvn[64+f] = v1 * wt; cvn[128+f] = v2 * wt;
    }
  }
}

// ---- K2: gather, CSR-ordered eP/eJ (1-deep chain), unroll-2. ----
__global__ __launch_bounds__(256) void k_gather(
    const float* __restrict__ eP, const int* __restrict__ eJ,
    const int* __restrict__ start,
    const float* __restrict__ fW, const float* __restrict__ fb,
    const float* __restrict__ XCV,
    float* __restrict__ dq, float* __restrict__ dmu, int l, int Ntot)
{
  int w = threadIdx.x >> 6;
  int f = threadIdx.x & 63;
  int i = blockIdx.x * 4 + w;
  if (i >= Ntot) return;
  const int col = l * 192;

  float fw0[NRBF], fw1[NRBF], fw2[NRBF];
#pragma unroll
  for (int r = 0; r < NRBF; ++r){
    const float* fr = fW + r*384 + col;
    fw0[r] = fr[f]; fw1[r] = fr[64 + f]; fw2[r] = fr[128 + f];
  }
  float fb0 = fb[col + f], fb1 = fb[col + 64 + f], fb2 = fb[col + 128 + f];

  float dqa = 0.f, dm0 = 0.f, dm1 = 0.f, dm2 = 0.f;
  int e0 = start[i], e1 = start[i+1];
  int e = e0;
  for (; e + 2 <= e1; e += 2){
    int jA = eJ[e], jB = eJ[e+1];
    const float4* pr = (const float4*)(eP + (size_t)e * 24);
    float4 A0=pr[0],A1=pr[1],A2=pr[2],A3=pr[3],A4=pr[4],A5=pr[5];
    float4 B0=pr[6],B1=pr[7],B2=pr[8],B3=pr[9],B4=pr[10],B5=pr[11];
    const float* xA = XCV + (size_t)jA * 384;
    const float* xB = XCV + (size_t)jB * 384;
    float xA0=xA[f], xA1=xA[64+f], xA2=xA[128+f], cA0=xA[192+f], cA1=xA[256+f], cA2=xA[320+f];
    float xB0=xB[f], xB1=xB[64+f], xB2=xB[128+f], cB0=xB[192+f], cB1=xB[256+f], cB2=xB[320+f];
    float phA[NRBF] = {A1.x,A1.y,A1.z,A1.w, A2.x,A2.y,A2.z,A2.w,
                       A3.x,A3.y,A3.z,A3.w, A4.x,A4.y,A4.z,A4.w,
                       A5.x,A5.y,A5.z,A5.w};
    float phB[NRBF] = {B1.x,B1.y,B1.z,B1.w, B2.x,B2.y,B2.z,B2.w,
                       B3.x,B3.y,B3.z,B3.w, B4.x,B4.y,B4.z,B4.w,
                       B5.x,B5.y,B5.z,B5.w};
    float wA0=fb0*A0.w, wA1=fb1*A0.w, wA2=fb2*A0.w;
    float wB0=fb0*B0.w, wB1=fb1*B0.w, wB2=fb2*B0.w;
#pragma unroll
    for (int r = 0; r < NRBF; ++r){
      wA0 = fmaf(phA[r], fw0[r], wA0);
      wA1 = fmaf(phA[r], fw1[r], wA1);
      wA2 = fmaf(phA[r], fw2[r], wA2);
      wB0 = fmaf(phB[r], fw0[r], wB0);
      wB1 = fmaf(phB[r], fw1[r], wB1);
      wB2 = fmaf(phB[r], fw2[r], wB2);
    }
    dqa = fmaf(xA0, wA0, dqa);
    float dmRA = xA1 * wA1, dmmA = xA2 * wA2;
    dm0 = fmaf(dmRA, A0.x, fmaf(dmmA, cA0, dm0));
    dm1 = fmaf(dmRA, A0.y, fmaf(dmmA, cA1, dm1));
    dm2 = fmaf(dmRA, A0.z, fmaf(dmmA, cA2, dm2));
    dqa = fmaf(xB0, wB0, dqa);
    float dmRB = xB1 * wB1, dmmB = xB2 * wB2;
    dm0 = fmaf(dmRB, B0.x, fmaf(dmmB, cB0, dm0));
    dm1 = fmaf(dmRB, B0.y, fmaf(dmmB, cB1, dm1));
    dm2 = fmaf(dmRB, B0.z, fmaf(dmmB, cB2, dm2));
  }
  if (e < e1){
    int j = eJ[e];
    const float4* pr = (const float4*)(eP + (size_t)e * 24);
    float4 v0 = pr[0], v1 = pr[1], v2 = pr[2], v3 = pr[3], v4 = pr[4], v5 = pr[5];
    const float* xj = XCV + (size_t)j * 384;
    float ph[NRBF] = {v1.x,v1.y,v1.z,v1.w, v2.x,v2.y,v2.z,v2.w,
                      v3.x,v3.y,v3.z,v3.w, v4.x,v4.y,v4.z,v4.w,
                      v5.x,v5.y,v5.z,v5.w};
    float w0 = fb0 * v0.w, w1 = fb1 * v0.w, w2 = fb2 * v0.w;
#pragma unroll
    for (int r = 0; r < NRBF; ++r){
      w0 = fmaf(ph[r], fw0[r], w0);
      w1 = fmaf(ph[r], fw1[r], w1);
      w2 = fmaf(ph[r], fw2[r], w2);
    }
    dqa = fmaf(xj[f], w0, dqa);
    float dmR = xj[64 + f]  * w1;
    float dmm = xj[128 + f] * w2;
    dm0 = fmaf(dmR, v0.x, fmaf(dmm, xj[192 + f], dm0));
    dm1 = fmaf(dmR, v0.y, fmaf(dmm, xj[256 + f], dm1));
    dm2 = fmaf(dmR, v0.z, fmaf(dmm, xj[320 + f], dm2));
  }
  dq[(size_t)i*64 + f] = dqa;
  float* dmn = dmu + (size_t)i*192;
  dmn[f] = dm0; dmn[64 + f] = dm1; dmn[128 + f] = dm2;
}

// ---- K3a v7: tv with f16 [c][kq][f][8] tiles (conflict-free) + fdot2. ----
__global__ __launch_bounds__(512) void k_tv(
    const float* __restrict__ dmuA, const float* __restrict__ XCV,
    const float* __restrict__ rW1, const float* __restrict__ rb1,
    const unsigned short* __restrict__ rW2S, const float* __restrict__ rb2Tl,
    float* __restrict__ MUI, float* __restrict__ TV, int Ntot)
{
  __shared__ float mus[16][3][64];  // 12 KB
  __shared__ float svs[16][64];     // 4 KB
  __shared__ float4 wt4[2048];      // 32 KB: 8 c x 4 kq x 64 f x 16B
  __shared__ float rbt[8][64];      // 2 KB
  int t = threadIdx.x;
  int w = t >> 6, f = t & 63;
  int base = blockIdx.x * 16;

#pragma unroll
  for (int s = 0; s < 2; ++s){
    int a = w*2 + s;
    int n = base + a; bool ok = (n < Ntot); if (!ok) n = Ntot - 1;
    const float* dmn = dmuA + (size_t)n*192;
    const float* cvn = XCV  + (size_t)n*384 + 192;
    float m0 = dmn[f]       + cvn[f];
    float m1 = dmn[64 + f]  + cvn[64 + f];
    float m2 = dmn[128 + f] + cvn[128 + f];
    mus[a][0][f] = m0; mus[a][1][f] = m1; mus[a][2][f] = m2;
    svs[a][f] = sqrtf(m0*m0 + m1*m1 + m2*m2 + EPSV);
    if (ok){
      float* mo = MUI + (size_t)n*192;
      mo[f] = m0; mo[64+f] = m1; mo[128+f] = m2;
    }
  }
  __syncthreads();

  int ki = f & 31;
  int a_h = w*2 + (f >> 5);
  float ah = rb1[ki];
#pragma unroll
  for (int c = 0; c < 64; ++c) ah = fmaf(svs[a_h][c], rW1[c*32 + ki], ah);
  ah = fmaxf(ah, 0.0f);
  // pack h pairs (f16) for both atoms: hpk[a][j] = (h[2j], h[2j+1])
  unsigned hpk0[16], hpk1[16];
#pragma unroll
  for (int k = 0; k < 16; ++k){
    float a0 = __shfl(ah, 2*k, 64),      b0 = __shfl(ah, 2*k + 1, 64);
    float a1 = __shfl(ah, 32 + 2*k, 64), b1 = __shfl(ah, 32 + 2*k + 1, 64);
    hpk0[k] = __builtin_bit_cast(unsigned, __builtin_amdgcn_cvt_pkrtz(a0, b0));
    hpk1[k] = __builtin_bit_cast(unsigned, __builtin_amdgcn_cvt_pkrtz(a1, b1));
  }

  const int a0i = w*2, a1i = a0i + 1;
  float mf00 = mus[a0i][0][f], mf01 = mus[a0i][1][f], mf02 = mus[a0i][2][f];
  float mf10 = mus[a1i][0][f], mf11 = mus[a1i][1][f], mf12 = mus[a1i][2][f];
  float tv00=0,tv01=0,tv02=0, tv10=0,tv11=0,tv12=0;
  const uint4* wtu = reinterpret_cast<const uint4*>(wt4);

  for (int ct = 0; ct < 8; ++ct){
    __syncthreads();
    const float4* src = (const float4*)rW2S + (size_t)ct*2048;
#pragma unroll
    for (int i = 0; i < 4; ++i) wt4[t + i*512] = src[t + i*512];
    if (t < 128) ((float4*)rbt)[t] = ((const float4*)(rb2Tl + ct*512))[t];
    __syncthreads();

#pragma unroll
    for (int cc = 0; cc < 8; ++cc){
      int c = ct*8 + cc;
      float u00 = mus[a0i][0][c], u01 = mus[a0i][1][c], u02 = mus[a0i][2][c];
      float u10 = mus[a1i][0][c], u11 = mus[a1i][1][c], u12 = mus[a1i][2][c];
      float g0 = u00*mf00 + u01*mf01 + u02*mf02;
      float g1 = u10*mf10 + u11*mf11 + u12*mf12;
      float acc0 = rbt[cc][f];
      float acc1 = acc0;
#pragma unroll
      for (int kq = 0; kq < 4; ++kq){
        uint4 u = wtu[(cc*4 + kq)*64 + f];   // lane-contiguous 16B: conflict-free
        int k0 = kq*4;
        acc0 = __builtin_amdgcn_fdot2(as_h2(u.x), as_h2(hpk0[k0+0]), acc0, false);
        acc0 = __builtin_amdgcn_fdot2(as_h2(u.y), as_h2(hpk0[k0+1]), acc0, false);
        acc0 = __builtin_amdgcn_fdot2(as_h2(u.z), as_h2(hpk0[k0+2]), acc0, false);
        acc0 = __builtin_amdgcn_fdot2(as_h2(u.w), as_h2(hpk0[k0+3]), acc0, false);
        acc1 = __builtin_amdgcn_fdot2(as_h2(u.x), as_h2(hpk1[k0+0]), acc1, false);
        acc1 = __builtin_amdgcn_fdot2(as_h2(u.y), as_h2(hpk1[k0+1]), acc1, false);
        acc1 = __builtin_amdgcn_fdot2(as_h2(u.z), as_h2(hpk1[k0+2]), acc1, false);
        acc1 = __builtin_amdgcn_fdot2(as_h2(u.w), as_h2(hpk1[k0+3]), acc1, false);
      }
      float mm0 = acc0 * g0, mm1 = acc1 * g1;
      tv00 = fmaf(u00, mm0, tv00); tv01 = fmaf(u01, mm0, tv01); tv02 = fmaf(u02, mm0, tv02);
      tv10 = fmaf(u10, mm1, tv10); tv11 = fmaf(u11, mm1, tv11); tv12 = fmaf(u12, mm1, tv12);
    }
  }

  int n0 = base + a0i, n1 = base + a1i;
  if (n0 < Ntot){
    float* tvp = TV + (size_t)n0*192;
    tvp[f] = tv00; tvp[64+f] = tv01; tvp[128+f] = tv02;
  }
  if (n1 < Ntot){
    float* tvp = TV + (size_t)n1*192;
    tvp[f] = tv10; tvp[64+f] = tv11; tvp[128+f] = tv12;
  }
}

// ---- K3b: mixing tail. 16 atoms/block (4 per wave), weights LDS-staged. ----
__global__ __launch_bounds__(256) void k_mix2(
    float* __restrict__ q, float* __restrict__ mu,
    const float* __restrict__ dq, const float* __restrict__ MUI, const float* __restrict__ TV,
    const float* __restrict__ mW1, const float* __restrict__ mb1,
    const float* __restrict__ mW2, const float* __restrict__ mb2,
    const float* __restrict__ Wm, int Ntot)
{
  __shared__ float wbuf[12288];     // 48 KB
  __shared__ float mua[16][3][64];  // 12 KB
  __shared__ float ava[16][128];    // 8 KB
  __shared__ float h2a[16][64];     // 4 KB
  int t = threadIdx.x;
  int w = t >> 6, f = t & 63;
  int base = blockIdx.x * 16;
  const int aw = w * 4;
  float4* wt4 = (float4*)wbuf;

  float qv[4], m0[4], m1[4], m2[4];
#pragma unroll
  for (int s = 0; s < 4; ++s){
    int a = aw + s;
    int n = base + a; if (n >= Ntot) n = Ntot - 1;
    qv[s] = q[(size_t)n*64 + f] + dq[(size_t)n*64 + f];
    const float* mi = MUI + (size_t)n*192;
    m0[s] = mi[f]; m1[s] = mi[64 + f]; m2[s] = mi[128 + f];
    mua[a][0][f] = m0[s]; mua[a][1][f] = m1[s]; mua[a][2][f] = m2[s];
  }

#pragma unroll
  for (int i = 0; i < 8; ++i) wt4[t + i*256] = ((const float4*)Wm)[t + i*256];
  __syncthreads();

  float V0[4]={0,0,0,0}, V1[4]={0,0,0,0}, V2[4]={0,0,0,0};
  float W0[4]={0,0,0,0}, W1[4]={0,0,0,0}, W2[4]={0,0,0,0};
  for (int k = 0; k < 64; ++k){
    float wv = wbuf[k*128 + f];
    float ww = wbuf[k*128 + 64 + f];
#pragma unroll
    for (int s = 0; s < 4; ++s){
      int a = aw + s;
      float b0 = mua[a][0][k], b1 = mua[a][1][k], b2 = mua[a][2][k];
      V0[s] = fmaf(b0, wv, V0[s]); V1[s] = fmaf(b1, wv, V1[s]); V2[s] = fmaf(b2, wv, V2[s]);
      W0[s] = fmaf(b0, ww, W0[s]); W1[s] = fmaf(b1, ww, W1[s]); W2[s] = fmaf(b2, ww, W2[s]);
    }
  }
  float dot[4];
#pragma unroll
  for (int s = 0; s < 4; ++s){
    int a = aw + s;
    ava[a][f] = qv[s];
    ava[a][64 + f] = sqrtf(V0[s]*V0[s] + V1[s]*V1[s] + V2[s]*V2[s] + EPSV);
    dot[s] = V0[s]*W0[s] + V1[s]*W1[s] + V2[s]*W2[s];
  }

  __syncthreads();
#pragma unroll
  for (int i = 0; i < 8; ++i) wt4[t + i*256] = ((const float4*)mW1)[t + i*256];
  __syncthreads();

  float acc[4];
#pragma unroll
  for (int s = 0; s < 4; ++s) acc[s] = mb1[f];
  for (int k = 0; k < 128; ++k){
    float wv = wbuf[k*64 + f];
#pragma unroll
    for (int s = 0; s < 4; ++s) acc[s] = fmaf(ava[aw + s][k], wv, acc[s]);
  }
#pragma unroll
  for (int s = 0; s < 4; ++s) h2a[aw + s][f] = silu_f(acc[s]);

  __syncthreads();
#pragma unroll
  for (int i = 0; i < 12; ++i) wt4[t + i*256] = ((const float4*)mW2)[t + i*256];
  __syncthreads();

  float y0[4], y1[4], y2[4];
#pragma unroll
  for (int s = 0; s < 4; ++s){ y0[s] = mb2[f]; y1[s] = mb2[64+f]; y2[s] = mb2[128+f]; }
  for (int k = 0; k < 64; ++k){
    float u0 = wbuf[k*192 + f];
    float u1 = wbuf[k*192 + 64 + f];
    float u2 = wbuf[k*192 + 128 + f];
#pragma unroll
    for (int s = 0; s < 4; ++s){
      float h = h2a[aw + s][k];
      y0[s] = fmaf(h, u0, y0[s]); y1[s] = fmaf(h, u1, y1[s]); y2[s] = fmaf(h, u2, y2[s]);
    }
  }

#pragma unroll
  for (int s = 0; s < 4; ++s){
    int n = base + aw + s;
    if (n < Ntot){
      q[(size_t)n*64 + f] = qv[s] + y0[s] + y2[s]*dot[s];
      const float* tvp = TV + (size_t)n*192;
      float* mun = mu + (size_t)n*384;
      mun[0*128 + f] = fmaf(y1[s], W0[s], m0[s]); mun[0*128 + 64 + f] = tvp[f];
      mun[1*128 + f] = fmaf(y1[s], W1[s], m1[s]); mun[1*128 + 64 + f] = tvp[64+f];
      mun[2*128 + f] = fmaf(y1[s], W2[s], m2[s]); mun[2*128 + 64 + f] = tvp[128+f];
    }
  }
}

extern "C" void kernel_launch(void* const* d_in, const int* in_sizes, int n_in,
                              void* d_out, int out_size, void* d_ws, size_t ws_size,
                              hipStream_t stream)
{
  const int*   Z      = (const int*)  d_in[0];
  const float* Rij    = (const float*)d_in[1];
  const int*   idx_i  = (const int*)  d_in[2];
  const int*   idx_j  = (const int*)  d_in[3];
  const float* embed  = (const float*)d_in[5];
  const float* fW     = (const float*)d_in[6];
  const float* fb     = (const float*)d_in[7];
  const float* ctxW1  = (const float*)d_in[8];
  const float* ctxb1  = (const float*)d_in[9];
  const float* ctxW2  = (const float*)d_in[10];
  const float* ctxb2  = (const float*)d_in[11];
  const float* compW1 = (const float*)d_in[12];
  const float* compb1 = (const float*)d_in[13];
  const float* compW2 = (const float*)d_in[14];
  const float* compb2 = (const float*)d_in[15];
  const float* recW1  = (const float*)d_in[16];
  const float* recb1  = (const float*)d_in[17];
  const float* recW2  = (const float*)d_in[18];
  const float* recb2  = (const float*)d_in[19];
  const float* mixW1  = (const float*)d_in[20];
  const float* mixb1  = (const float*)d_in[21];
  const float* mixW2  = (const float*)d_in[22];
  const float* mixb2  = (const float*)d_in[23];
  const float* muMixW = (const float*)d_in[24];

  const int N = in_sizes[0];
  const int P = in_sizes[1] / 3;

  float* ws    = (float*)d_ws;
  float* eP    = ws;                         // P*24
  float* q     = eP    + (size_t)P*24;       // N*64
  float* mu    = q     + (size_t)N*64;       // N*384
  float* XCV   = mu    + (size_t)N*384;      // N*384
  float* dq    = XCV   + (size_t)N*384;      // N*64
  float* dmu   = dq    + (size_t)N*64;       // N*192
  float* rW2Sf = dmu   + (size_t)N*192;      // f16 512KB = 131072 floats
  float* rb2T  = rW2Sf + (size_t)131072;     // 8192
  float* TV    = rb2T  + (size_t)8192;       // N*192
  float* MUI   = TV    + (size_t)N*192;      // N*192
  int*   cnt    = (int*)(MUI + (size_t)N*192); // N
  int*   startA = cnt    + N;                  // N+1
  int*   cursor = startA + (N + 1);            // N
  int*   elist  = cursor + N;                  // P
  int*   eJ     = elist  + P;                  // P
  unsigned short* rW2S = (unsigned short*)rW2Sf;

  hipMemsetAsync(mu, 0, (size_t)N*384*sizeof(float), stream);
  hipMemsetAsync(cnt, 0, (size_t)N*sizeof(int), stream);
  k_init_q<<<(N*FD + 255)/256, 256, 0, stream>>>(Z, embed, q, N);
  k_transpose_w<<<(2*64*64*32 + 255)/256, 256, 0, stream>>>(recW2, recb2, rW2S, rb2T);

  // CSR build + CSR-ordered edge records (idx fixed across layers)
  k_count<<<(P + 255)/256, 256, 0, stream>>>(idx_i, cnt, P);
  k_scan<<<1, 1024, 0, stream>>>(cnt, startA, cursor, N);
  k_scatter<<<(P + 255)/256, 256, 0, stream>>>(idx_i, cursor, elist, P);
  k_edgeprep<<<(P + 255)/256, 256, 0, stream>>>(Rij, elist, idx_j, eP, eJ, P);

  const int ablk4  = (N + 3) / 4;
  const int ablk16 = (N + 15) / 16;
  for (int l = 0; l < 2; ++l){
    k_atom_pre<<<ablk16, 256, 0, stream>>>(q, mu,
        ctxW1 + (size_t)l*64*64,  ctxb1 + (size_t)l*64,
        ctxW2 + (size_t)l*64*192, ctxb2 + (size_t)l*192,
        compW1 + (size_t)l*128*32, compb1 + (size_t)l*32,
        compW2 + (size_t)l*32*64,  compb2 + (size_t)l*64,
        XCV, N);
    k_gather<<<ablk4, 256, 0, stream>>>(eP, eJ, startA, fW, fb, XCV,
        dq, dmu, l, N);
    k_tv<<<ablk16, 512, 0, stream>>>(dmu, XCV,
        recW1 + (size_t)l*64*32, recb1 + (size_t)l*32,
        rW2S + (size_t)l*131072, rb2T + (size_t)l*4096,
        MUI, TV, N);
    k_mix2<<<ablk16, 256, 0, stream>>>(q, mu, dq, MUI, TV,
        mixW1 + (size_t)l*128*64, mixb1 + (size_t)l*64,
        mixW2 + (size_t)l*64*192, mixb2 + (size_t)l*192,
        muMixW + (size_t)l*64*128, N);
  }

  hipMemcpyAsync(d_out, q, (size_t)N*64*sizeof(float), hipMemcpyDeviceToDevice, stream);
  hipMemcpyAsync((float*)d_out + (size_t)N*64, mu, (size_t)N*384*sizeof(float),
                 hipMemcpyDeviceToDevice, stream);
}

// Round 13
// 542.093 us; speedup vs baseline: 1.6424x; 1.0236x over previous
//
#include <hip/hip_runtime.h>
#include <math.h>

#define FD 64
#define NRBF 20
#define CUT 5.0f
#define EPSV 1e-8f
#define PI_F 3.14159265358979f

typedef _Float16 h2v __attribute__((ext_vector_type(2)));

__device__ __forceinline__ float wredsum(float v){
#pragma unroll
  for (int m = 32; m >= 1; m >>= 1) v += __shfl_xor(v, m, 64);
  return v;
}
__device__ __forceinline__ float wredmax(float v){
#pragma unroll
  for (int m = 32; m >= 1; m >>= 1) v = fmaxf(v, __shfl_xor(v, m, 64));
  return v;
}
__device__ __forceinline__ float silu_f(float x){ return x * (1.0f / (1.0f + __expf(-x))); }
__device__ __forceinline__ h2v as_h2(unsigned u){
  union { unsigned u; h2v h; } x; x.u = u; return x.h;
}
__device__ __forceinline__ unsigned pack_bf16(float a, float b){
  unsigned ua = __float_as_uint(a), ub = __float_as_uint(b);
  ua = (ua + 0x7fffu + ((ua >> 16) & 1u)) >> 16;
  ub = (ub + 0x7fffu + ((ub >> 16) & 1u)) >> 16;
  return ua | (ub << 16);
}
#define BF_LO(u) __uint_as_float((u) << 16)
#define BF_HI(u) __uint_as_float((u) & 0xffff0000u)

// ---- CSR build: histogram, scan, scatter ----
__global__ __launch_bounds__(256) void k_count(const int* __restrict__ idx_i,
                                               int* __restrict__ cnt, int P)
{
  int p = blockIdx.x * blockDim.x + threadIdx.x;
  if (p < P) atomicAdd(&cnt[idx_i[p]], 1);
}

__global__ __launch_bounds__(1024) void k_scan(const int* __restrict__ cnt,
                                               int* __restrict__ start,
                                               int* __restrict__ cursor, int N)
{
  __shared__ int part[1024];
  int t = threadIdx.x;
  int chunk = (N + 1023) / 1024;
  int lo = t * chunk, hi = lo + chunk; if (hi > N) hi = N;
  int s = 0;
  for (int i = lo; i < hi; ++i) s += cnt[i];
  part[t] = s;
  __syncthreads();
  for (int off = 1; off < 1024; off <<= 1){
    int v = 0;
    if (t >= off) v = part[t - off];
    __syncthreads();
    if (t >= off) part[t] += v;
    __syncthreads();
  }
  int run = (t == 0) ? 0 : part[t-1];
  for (int i = lo; i < hi; ++i){ start[i] = run; cursor[i] = run; run += cnt[i]; }
  if (t == 1023) start[N] = run;
}

__global__ __launch_bounds__(256) void k_scatter(const int* __restrict__ idx_i,
                                                 int* __restrict__ cursor,
                                                 int* __restrict__ elist, int P)
{
  int p = blockIdx.x * blockDim.x + threadIdx.x;
  if (p < P){
    int pos = atomicAdd(&cursor[idx_i[p]], 1);
    elist[pos] = p;
  }
}

// ---- edge records in CSR order: eP[e][24] = dir(3),fcut,phi*fcut(20); eJ[e]=idx_j ----
__global__ __launch_bounds__(256) void k_edgeprep(const float* __restrict__ Rij,
                                                  const int* __restrict__ elist,
                                                  const int* __restrict__ idx_j,
                                                  float* __restrict__ eP,
                                                  int* __restrict__ eJ, int P)
{
  int e = blockIdx.x * blockDim.x + threadIdx.x;
  if (e >= P) return;
  int p = elist[e];
  eJ[e] = idx_j[p];
  float rx = Rij[3*p+0], ry = Rij[3*p+1], rz = Rij[3*p+2];
  float d = sqrtf(rx*rx + ry*ry + rz*rz);
  float inv = 1.0f / d;
  float fc = (d < CUT) ? 0.5f * (__cosf(PI_F * d / CUT) + 1.0f) : 0.0f;
  float* pr = eP + (size_t)e * 24;
  pr[0] = rx*inv; pr[1] = ry*inv; pr[2] = rz*inv; pr[3] = fc;
  const float width = CUT / (float)(NRBF - 1);
#pragma unroll
  for (int r = 0; r < NRBF; ++r){
    float t = (d - width * (float)r) / width;
    pr[4+r] = __expf(-0.5f * t * t) * fc;
  }
}

// ---- transpose rec_W2 -> f16 rW2S in [l][c][kq][f][8] layout (conflict-free b128);
//      rb2 -> rb2T[l][c][f] (f32) ----
__global__ __launch_bounds__(256) void k_transpose_w(const float* __restrict__ rW2,
                                                     const float* __restrict__ rb2,
                                                     unsigned short* __restrict__ rW2S,
                                                     float* __restrict__ rb2T)
{
  int t = blockIdx.x * blockDim.x + threadIdx.x;
  if (t < 2*64*64*32){
    int km = t & 7;
    int f  = (t >> 3) & 63;
    int kq = (t >> 9) & 3;
    int c  = (t >> 11) & 63;
    int l  = t >> 17;
    int k  = kq*8 + km;
    float v = rW2[((size_t)(l*32 + k))*4096 + f*64 + c];
    _Float16 hv = (_Float16)v;            // RNE f32->f16
    unsigned short us;
    __builtin_memcpy(&us, &hv, 2);
    rW2S[t] = us;
  }
  if (t < 2*64*64){
    int f = t & 63, c = (t >> 6) & 63, l = t >> 12;
    rb2T[t] = rb2[(size_t)l*4096 + f*64 + c];
  }
}

// ---- K_init: q = embed[Z] ----
__global__ __launch_bounds__(256) void k_init_q(const int* __restrict__ Z,
                                                const float* __restrict__ embed,
                                                float* __restrict__ q, int Ntot)
{
  int t = blockIdx.x * blockDim.x + threadIdx.x;
  if (t >= Ntot * FD) return;
  int n = t >> 6, f = t & 63;
  q[t] = embed[Z[n]*FD + f];
}

// ---- K1: per-atom pre. 16 atoms/block, weights LDS-staged.
// Writes XCVh (packed bf16: k0=(X0,X1), k1=(X2,CV0), k2=(CV1,CV2)) and CVf (f32). ----
__global__ __launch_bounds__(256) void k_atom_pre(
    const float* __restrict__ q, const float* __restrict__ mu,
    const float* __restrict__ cW1, const float* __restrict__ cb1,
    const float* __restrict__ cW2, const float* __restrict__ cb2,
    const float* __restrict__ pW1, const float* __restrict__ pb1,
    const float* __restrict__ pW2, const float* __restrict__ pb2,
    unsigned* __restrict__ XCVh, float* __restrict__ CVf, int Ntot)
{
  __shared__ float wbuf[12288];     // 48 KB
  __shared__ float qs[16][64];      // 4 KB
  __shared__ float sbuf[16][128];   // 8 KB
  __shared__ float h1s[16][64];     // 4 KB
  __shared__ float hcs[16][32];     // 2 KB
  int t = threadIdx.x;
  int w = t >> 6, f = t & 63;
  int base = blockIdx.x * 16;
  const int aw = w * 4;
  float4* wt4 = (float4*)wbuf;

  float m0a[4], m1a[4], m2a[4], m0b[4], m1b[4], m2b[4];
#pragma unroll
  for (int s = 0; s < 4; ++s){
    int a = aw + s;
    int n = base + a; if (n >= Ntot) n = Ntot - 1;
    qs[a][f] = q[(size_t)n*64 + f];
    const float* mun = mu + (size_t)n * 384;
    m0a[s] = mun[0*128 + f];      m1a[s] = mun[1*128 + f];      m2a[s] = mun[2*128 + f];
    m0b[s] = mun[0*128 + 64 + f]; m1b[s] = mun[1*128 + 64 + f]; m2b[s] = mun[2*128 + 64 + f];
    sbuf[a][f]      = sqrtf(m0a[s]*m0a[s] + m1a[s]*m1a[s] + m2a[s]*m2a[s] + EPSV);
    sbuf[a][64 + f] = sqrtf(m0b[s]*m0b[s] + m1b[s]*m1b[s] + m2b[s]*m2b[s] + EPSV);
  }
#pragma unroll
  for (int i = 0; i < 4; ++i) wt4[t + i*256] = ((const float4*)cW1)[t + i*256];
  __syncthreads();

  float hacc[4];
#pragma unroll
  for (int s = 0; s < 4; ++s) hacc[s] = cb1[f];
  for (int k = 0; k < 64; ++k){
    float wv = wbuf[k*64 + f];
#pragma unroll
    for (int s = 0; s < 4; ++s) hacc[s] = fmaf(qs[aw + s][k], wv, hacc[s]);
  }
#pragma unroll
  for (int s = 0; s < 4; ++s) h1s[aw + s][f] = silu_f(hacc[s]);

  __syncthreads();
#pragma unroll
  for (int i = 0; i < 12; ++i) wt4[t + i*256] = ((const float4*)cW2)[t + i*256];
  __syncthreads();

  float x0[4], x1[4], x2[4];
#pragma unroll
  for (int s = 0; s < 4; ++s){ x0[s] = cb2[f]; x1[s] = cb2[64+f]; x2[s] = cb2[128+f]; }
  for (int k = 0; k < 64; ++k){
    float u0 = wbuf[k*192 + f];
    float u1 = wbuf[k*192 + 64 + f];
    float u2 = wbuf[k*192 + 128 + f];
#pragma unroll
    for (int s = 0; s < 4; ++s){
      float h = h1s[aw + s][k];
      x0[s] = fmaf(h, u0, x0[s]); x1[s] = fmaf(h, u1, x1[s]); x2[s] = fmaf(h, u2, x2[s]);
    }
  }
#pragma unroll
  for (int s = 0; s < 4; ++s){
    int n = base + aw + s;
    if (n < Ntot) XCVh[(size_t)n*192 + f] = pack_bf16(x0[s], x1[s]);
  }

  __syncthreads();
#pragma unroll
  for (int i = 0; i < 4; ++i) wt4[t + i*256] = ((const float4*)pW1)[t + i*256];
#pragma unroll
  for (int i = 0; i < 2; ++i) wt4[1024 + t + i*256] = ((const float4*)pW2)[t + i*256];
  __syncthreads();

  int ki = f & 31;
#pragma unroll
  for (int p = 0; p < 2; ++p){
    int a_h = aw + p*2 + (f >> 5);
    float ah = pb1[ki];
#pragma unroll 4
    for (int c = 0; c < 128; ++c) ah = fmaf(sbuf[a_h][c], wbuf[c*32 + ki], ah);
    hcs[a_h][ki] = fmaxf(ah, 0.0f);
  }

  float logit[4];
#pragma unroll
  for (int s = 0; s < 4; ++s) logit[s] = pb2[f];
  for (int k = 0; k < 32; ++k){
    float wv = wbuf[4096 + k*64 + f];
#pragma unroll
    for (int s = 0; s < 4; ++s) logit[s] = fmaf(hcs[aw + s][k], wv, logit[s]);
  }
#pragma unroll
  for (int s = 0; s < 4; ++s){
    float mx = wredmax(logit[s]);
    float e  = __expf(logit[s] - mx);
    float se = wredsum(e);
    float wt = e / se;
    float v0 = wredsum(m0a[s] + m0b[s]);
    float v1 = wredsum(m1a[s] + m1b[s]);
    float v2 = wredsum(m2a[s] + m2b[s]);
    int n = base + aw + s;
    if (n < Ntot){
      float cv0 = v0 * wt, cv1 = v1 * wt, cv2 = v2 * wt;
      XCVh[(size_t)n*192 + 64 + f]  = pack_bf16(x2[s], cv0);
      XCVh[(size_t)n*192 + 128 + f] = pack_bf16(cv1, cv2);
      float* cvn = CVf + (size_t)n*192;
      cvn[f] = cv0; cvn[64+f] = cv1; cvn[128+f] = cv2;
    }
  }
}

// ---- K2: gather, CSR-ordered eP/eJ, unroll-2, packed-bf16 XCV (half fetch bytes). ----
__global__ __launch_bounds__(256) void k_gather(
    const float* __restrict__ eP, const int* __restrict__ eJ,
    const int* __restrict__ start,
    const float* __restrict__ fW, const float* __restrict__ fb,
    const unsigned* __restrict__ XCVh,
    float* __restrict__ dq, float* __restrict__ dmu, int l, int Ntot)
{
  int w = threadIdx.x >> 6;
  int f = threadIdx.x & 63;
  int i = blockIdx.x * 4 + w;
  if (i >= Ntot) return;
  const int col = l * 192;

  float fw0[NRBF], fw1[NRBF], fw2[NRBF];
#pragma unroll
  for (int r = 0; r < NRBF; ++r){
    const float* fr = fW + r*384 + col;
    fw0[r] = fr[f]; fw1[r] = fr[64 + f]; fw2[r] = fr[128 + f];
  }
  float fb0 = fb[col + f], fb1 = fb[col + 64 + f], fb2 = fb[col + 128 + f];

  float dqa = 0.f, dm0 = 0.f, dm1 = 0.f, dm2 = 0.f;
  int e0 = start[i], e1 = start[i+1];
  int e = e0;
  for (; e + 2 <= e1; e += 2){
    int jA = eJ[e], jB = eJ[e+1];
    const float4* pr = (const float4*)(eP + (size_t)e * 24);
    float4 A0=pr[0],A1=pr[1],A2=pr[2],A3=pr[3],A4=pr[4],A5=pr[5];
    float4 B0=pr[6],B1=pr[7],B2=pr[8],B3=pr[9],B4=pr[10],B5=pr[11];
    const unsigned* xA = XCVh + (size_t)jA * 192;
    const unsigned* xB = XCVh + (size_t)jB * 192;
    unsigned uA0=xA[f], uA1=xA[64+f], uA2=xA[128+f];
    unsigned uB0=xB[f], uB1=xB[64+f], uB2=xB[128+f];
    float phA[NRBF] = {A1.x,A1.y,A1.z,A1.w, A2.x,A2.y,A2.z,A2.w,
                       A3.x,A3.y,A3.z,A3.w, A4.x,A4.y,A4.z,A4.w,
                       A5.x,A5.y,A5.z,A5.w};
    float phB[NRBF] = {B1.x,B1.y,B1.z,B1.w, B2.x,B2.y,B2.z,B2.w,
                       B3.x,B3.y,B3.z,B3.w, B4.x,B4.y,B4.z,B4.w,
                       B5.x,B5.y,B5.z,B5.w};
    float wA0=fb0*A0.w, wA1=fb1*A0.w, wA2=fb2*A0.w;
    float wB0=fb0*B0.w, wB1=fb1*B0.w, wB2=fb2*B0.w;
#pragma unroll
    for (int r = 0; r < NRBF; ++r){
      wA0 = fmaf(phA[r], fw0[r], wA0);
      wA1 = fmaf(phA[r], fw1[r], wA1);
      wA2 = fmaf(phA[r], fw2[r], wA2);
      wB0 = fmaf(phB[r], fw0[r], wB0);
      wB1 = fmaf(phB[r], fw1[r], wB1);
      wB2 = fmaf(phB[r], fw2[r], wB2);
    }
    dqa = fmaf(BF_LO(uA0), wA0, dqa);
    float dmRA = BF_HI(uA0) * wA1, dmmA = BF_LO(uA1) * wA2;
    dm0 = fmaf(dmRA, A0.x, fmaf(dmmA, BF_HI(uA1), dm0));
    dm1 = fmaf(dmRA, A0.y, fmaf(dmmA, BF_LO(uA2), dm1));
    dm2 = fmaf(dmRA, A0.z, fmaf(dmmA, BF_HI(uA2), dm2));
    dqa = fmaf(BF_LO(uB0), wB0, dqa);
    float dmRB = BF_HI(uB0) * wB1, dmmB = BF_LO(uB1) * wB2;
    dm0 = fmaf(dmRB, B0.x, fmaf(dmmB, BF_HI(uB1), dm0));
    dm1 = fmaf(dmRB, B0.y, fmaf(dmmB, BF_LO(uB2), dm1));
    dm2 = fmaf(dmRB, B0.z, fmaf(dmmB, BF_HI(uB2), dm2));
  }
  if (e < e1){
    int j = eJ[e];
    const float4* pr = (const float4*)(eP + (size_t)e * 24);
    float4 v0 = pr[0], v1 = pr[1], v2 = pr[2], v3 = pr[3], v4 = pr[4], v5 = pr[5];
    const unsigned* xj = XCVh + (size_t)j * 192;
    unsigned u0=xj[f], u1=xj[64+f], u2=xj[128+f];
    float ph[NRBF] = {v1.x,v1.y,v1.z,v1.w, v2.x,v2.y,v2.z,v2.w,
                      v3.x,v3.y,v3.z,v3.w, v4.x,v4.y,v4.z,v4.w,
                      v5.x,v5.y,v5.z,v5.w};
    float w0 = fb0 * v0.w, w1 = fb1 * v0.w, w2 = fb2 * v0.w;
#pragma unroll
    for (int r = 0; r < NRBF; ++r){
      w0 = fmaf(ph[r], fw0[r], w0);
      w1 = fmaf(ph[r], fw1[r], w1);
      w2 = fmaf(ph[r], fw2[r], w2);
    }
    dqa = fmaf(BF_LO(u0), w0, dqa);
    float dmR = BF_HI(u0) * w1, dmm = BF_LO(u1) * w2;
    dm0 = fmaf(dmR, v0.x, fmaf(dmm, BF_HI(u1), dm0));
    dm1 = fmaf(dmR, v0.y, fmaf(dmm, BF_LO(u2), dm1));
    dm2 = fmaf(dmR, v0.z, fmaf(dmm, BF_HI(u2), dm2));
  }
  dq[(size_t)i*64 + f] = dqa;
  float* dmn = dmu + (size_t)i*192;
  dmn[f] = dm0; dmn[64 + f] = dm1; dmn[128 + f] = dm2;
}

// ---- K3a: tv with f16 [c][kq][f][8] tiles (conflict-free) + fdot2. ----
__global__ __launch_bounds__(512) void k_tv(
    const float* __restrict__ dmuA, const float* __restrict__ CVf,
    const float* __restrict__ rW1, const float* __restrict__ rb1,
    const unsigned short* __restrict__ rW2S, const float* __restrict__ rb2Tl,
    float* __restrict__ MUI, float* __restrict__ TV, int Ntot)
{
  __shared__ float mus[16][3][64];  // 12 KB
  __shared__ float svs[16][64];     // 4 KB
  __shared__ float4 wt4[2048];      // 32 KB: 8 c x 4 kq x 64 f x 16B
  __shared__ float rbt[8][64];      // 2 KB
  int t = threadIdx.x;
  int w = t >> 6, f = t & 63;
  int base = blockIdx.x * 16;

#pragma unroll
  for (int s = 0; s < 2; ++s){
    int a = w*2 + s;
    int n = base + a; bool ok = (n < Ntot); if (!ok) n = Ntot - 1;
    const float* dmn = dmuA + (size_t)n*192;
    const float* cvn = CVf  + (size_t)n*192;
    float m0 = dmn[f]       + cvn[f];
    float m1 = dmn[64 + f]  + cvn[64 + f];
    float m2 = dmn[128 + f] + cvn[128 + f];
    mus[a][0][f] = m0; mus[a][1][f] = m1; mus[a][2][f] = m2;
    svs[a][f] = sqrtf(m0*m0 + m1*m1 + m2*m2 + EPSV);
    if (ok){
      float* mo = MUI + (size_t)n*192;
      mo[f] = m0; mo[64+f] = m1; mo[128+f] = m2;
    }
  }
  __syncthreads();

  int ki = f & 31;
  int a_h = w*2 + (f >> 5);
  float ah = rb1[ki];
#pragma unroll
  for (int c = 0; c < 64; ++c) ah = fmaf(svs[a_h][c], rW1[c*32 + ki], ah);
  ah = fmaxf(ah, 0.0f);
  // pack h pairs (f16) for both atoms: hpk[a][j] = (h[2j], h[2j+1])
  unsigned hpk0[16], hpk1[16];
#pragma unroll
  for (int k = 0; k < 16; ++k){
    float a0 = __shfl(ah, 2*k, 64),      b0 = __shfl(ah, 2*k + 1, 64);
    float a1 = __shfl(ah, 32 + 2*k, 64), b1 = __shfl(ah, 32 + 2*k + 1, 64);
    hpk0[k] = __builtin_bit_cast(unsigned, __builtin_amdgcn_cvt_pkrtz(a0, b0));
    hpk1[k] = __builtin_bit_cast(unsigned, __builtin_amdgcn_cvt_pkrtz(a1, b1));
  }

  const int a0i = w*2, a1i = a0i + 1;
  float mf00 = mus[a0i][0][f], mf01 = mus[a0i][1][f], mf02 = mus[a0i][2][f];
  float mf10 = mus[a1i][0][f], mf11 = mus[a1i][1][f], mf12 = mus[a1i][2][f];
  float tv00=0,tv01=0,tv02=0, tv10=0,tv11=0,tv12=0;
  const uint4* wtu = reinterpret_cast<const uint4*>(wt4);

  for (int ct = 0; ct < 8; ++ct){
    __syncthreads();
    const float4* src = (const float4*)rW2S + (size_t)ct*2048;
#pragma unroll
    for (int i = 0; i < 4; ++i) wt4[t + i*512] = src[t + i*512];
    if (t < 128) ((float4*)rbt)[t] = ((const float4*)(rb2Tl + ct*512))[t];
    __syncthreads();

#pragma unroll
    for (int cc = 0; cc < 8; ++cc){
      int c = ct*8 + cc;
      float u00 = mus[a0i][0][c], u01 = mus[a0i][1][c], u02 = mus[a0i][2][c];
      float u10 = mus[a1i][0][c], u11 = mus[a1i][1][c], u12 = mus[a1i][2][c];
      float g0 = u00*mf00 + u01*mf01 + u02*mf02;
      float g1 = u10*mf10 + u11*mf11 + u12*mf12;
      float acc0 = rbt[cc][f];
      float acc1 = acc0;
#pragma unroll
      for (int kq = 0; kq < 4; ++kq){
        uint4 u = wtu[(cc*4 + kq)*64 + f];   // lane-contiguous 16B: conflict-free
        int k0 = kq*4;
        acc0 = __builtin_amdgcn_fdot2(as_h2(u.x), as_h2(hpk0[k0+0]), acc0, false);
        acc0 = __builtin_amdgcn_fdot2(as_h2(u.y), as_h2(hpk0[k0+1]), acc0, false);
        acc0 = __builtin_amdgcn_fdot2(as_h2(u.z), as_h2(hpk0[k0+2]), acc0, false);
        acc0 = __builtin_amdgcn_fdot2(as_h2(u.w), as_h2(hpk0[k0+3]), acc0, false);
        acc1 = __builtin_amdgcn_fdot2(as_h2(u.x), as_h2(hpk1[k0+0]), acc1, false);
        acc1 = __builtin_amdgcn_fdot2(as_h2(u.y), as_h2(hpk1[k0+1]), acc1, false);
        acc1 = __builtin_amdgcn_fdot2(as_h2(u.z), as_h2(hpk1[k0+2]), acc1, false);
        acc1 = __builtin_amdgcn_fdot2(as_h2(u.w), as_h2(hpk1[k0+3]), acc1, false);
      }
      float mm0 = acc0 * g0, mm1 = acc1 * g1;
      tv00 = fmaf(u00, mm0, tv00); tv01 = fmaf(u01, mm0, tv01); tv02 = fmaf(u02, mm0, tv02);
      tv10 = fmaf(u10, mm1, tv10); tv11 = fmaf(u11, mm1, tv11); tv12 = fmaf(u12, mm1, tv12);
    }
  }

  int n0 = base + a0i, n1 = base + a1i;
  if (n0 < Ntot){
    float* tvp = TV + (size_t)n0*192;
    tvp[f] = tv00; tvp[64+f] = tv01; tvp[128+f] = tv02;
  }
  if (n1 < Ntot){
    float* tvp = TV + (size_t)n1*192;
    tvp[f] = tv10; tvp[64+f] = tv11; tvp[128+f] = tv12;
  }
}

// ---- K3b: mixing tail. 16 atoms/block (4 per wave), weights LDS-staged. ----
__global__ __launch_bounds__(256) void k_mix2(
    float* __restrict__ q, float* __restrict__ mu,
    const float* __restrict__ dq, const float* __restrict__ MUI, const float* __restrict__ TV,
    const float* __restrict__ mW1, const float* __restrict__ mb1,
    const float* __restrict__ mW2, const float* __restrict__ mb2,
    const float* __restrict__ Wm, int Ntot)
{
  __shared__ float wbuf[12288];     // 48 KB
  __shared__ float mua[16][3][64];  // 12 KB
  __shared__ float ava[16][128];    // 8 KB
  __shared__ float h2a[16][64];     // 4 KB
  int t = threadIdx.x;
  int w = t >> 6, f = t & 63;
  int base = blockIdx.x * 16;
  const int aw = w * 4;
  float4* wt4 = (float4*)wbuf;

  float qv[4], m0[4], m1[4], m2[4];
#pragma unroll
  for (int s = 0; s < 4; ++s){
    int a = aw + s;
    int n = base + a; if (n >= Ntot) n = Ntot - 1;
    qv[s] = q[(size_t)n*64 + f] + dq[(size_t)n*64 + f];
    const float* mi = MUI + (size_t)n*192;
    m0[s] = mi[f]; m1[s] = mi[64 + f]; m2[s] = mi[128 + f];
    mua[a][0][f] = m0[s]; mua[a][1][f] = m1[s]; mua[a][2][f] = m2[s];
  }

#pragma unroll
  for (int i = 0; i < 8; ++i) wt4[t + i*256] = ((const float4*)Wm)[t + i*256];
  __syncthreads();

  float V0[4]={0,0,0,0}, V1[4]={0,0,0,0}, V2[4]={0,0,0,0};
  float W0[4]={0,0,0,0}, W1[4]={0,0,0,0}, W2[4]={0,0,0,0};
  for (int k = 0; k < 64; ++k){
    float wv = wbuf[k*128 + f];
    float ww = wbuf[k*128 + 64 + f];
#pragma unroll
    for (int s = 0; s < 4; ++s){
      int a = aw + s;
      float b0 = mua[a][0][k], b1 = mua[a][1][k], b2 = mua[a][2][k];
      V0[s] = fmaf(b0, wv, V0[s]); V1[s] = fmaf(b1, wv, V1[s]); V2[s] = fmaf(b2, wv, V2[s]);
      W0[s] = fmaf(b0, ww, W0[s]); W1[s] = fmaf(b1, ww, W1[s]); W2[s] = fmaf(b2, ww, W2[s]);
    }
  }
  float dot[4];
#pragma unroll
  for (int s = 0; s < 4; ++s){
    int a = aw + s;
    ava[a][f] = qv[s];
    ava[a][64 + f] = sqrtf(V0[s]*V0[s] + V1[s]*V1[s] + V2[s]*V2[s] + EPSV);
    dot[s] = V0[s]*W0[s] + V1[s]*W1[s] + V2[s]*W2[s];
  }

  __syncthreads();
#pragma unroll
  for (int i = 0; i < 8; ++i) wt4[t + i*256] = ((const float4*)mW1)[t + i*256];
  __syncthreads();

  float acc[4];
#pragma unroll
  for (int s = 0; s < 4; ++s) acc[s] = mb1[f];
  for (int k = 0; k < 128; ++k){
    float wv = wbuf[k*64 + f];
#pragma unroll
    for (int s = 0; s < 4; ++s) acc[s] = fmaf(ava[aw + s][k], wv, acc[s]);
  }
#pragma unroll
  for (int s = 0; s < 4; ++s) h2a[aw + s][f] = silu_f(acc[s]);

  __syncthreads();
#pragma unroll
  for (int i = 0; i < 12; ++i) wt4[t + i*256] = ((const float4*)mW2)[t + i*256];
  __syncthreads();

  float y0[4], y1[4], y2[4];
#pragma unroll
  for (int s = 0; s < 4; ++s){ y0[s] = mb2[f]; y1[s] = mb2[64+f]; y2[s] = mb2[128+f]; }
  for (int k = 0; k < 64; ++k){
    float u0 = wbuf[k*192 + f];
    float u1 = wbuf[k*192 + 64 + f];
    float u2 = wbuf[k*192 + 128 + f];
#pragma unroll
    for (int s = 0; s < 4; ++s){
      float h = h2a[aw + s][k];
      y0[s] = fmaf(h, u0, y0[s]); y1[s] = fmaf(h, u1, y1[s]); y2[s] = fmaf(h, u2, y2[s]);
    }
  }

#pragma unroll
  for (int s = 0; s < 4; ++s){
    int n = base + aw + s;
    if (n < Ntot){
      q[(size_t)n*64 + f] = qv[s] + y0[s] + y2[s]*dot[s];
      const float* tvp = TV + (size_t)n*192;
      float* mun = mu + (size_t)n*384;
      mun[0*128 + f] = fmaf(y1[s], W0[s], m0[s]); mun[0*128 + 64 + f] = tvp[f];
      mun[1*128 + f] = fmaf(y1[s], W1[s], m1[s]); mun[1*128 + 64 + f] = tvp[64+f];
      mun[2*128 + f] = fmaf(y1[s], W2[s], m2[s]); mun[2*128 + 64 + f] = tvp[128+f];
    }
  }
}

extern "C" void kernel_launch(void* const* d_in, const int* in_sizes, int n_in,
                              void* d_out, int out_size, void* d_ws, size_t ws_size,
                              hipStream_t stream)
{
  const int*   Z      = (const int*)  d_in[0];
  const float* Rij    = (const float*)d_in[1];
  const int*   idx_i  = (const int*)  d_in[2];
  const int*   idx_j  = (const int*)  d_in[3];
  const float* embed  = (const float*)d_in[5];
  const float* fW     = (const float*)d_in[6];
  const float* fb     = (const float*)d_in[7];
  const float* ctxW1  = (const float*)d_in[8];
  const float* ctxb1  = (const float*)d_in[9];
  const float* ctxW2  = (const float*)d_in[10];
  const float* ctxb2  = (const float*)d_in[11];
  const float* compW1 = (const float*)d_in[12];
  const float* compb1 = (const float*)d_in[13];
  const float* compW2 = (const float*)d_in[14];
  const float* compb2 = (const float*)d_in[15];
  const float* recW1  = (const float*)d_in[16];
  const float* recb1  = (const float*)d_in[17];
  const float* recW2  = (const float*)d_in[18];
  const float* recb2  = (const float*)d_in[19];
  const float* mixW1  = (const float*)d_in[20];
  const float* mixb1  = (const float*)d_in[21];
  const float* mixW2  = (const float*)d_in[22];
  const float* mixb2  = (const float*)d_in[23];
  const float* muMixW = (const float*)d_in[24];

  const int N = in_sizes[0];
  const int P = in_sizes[1] / 3;

  float* ws    = (float*)d_ws;
  float* eP    = ws;                         // P*24
  float* q     = eP    + (size_t)P*24;       // N*64
  float* mu    = q     + (size_t)N*64;       // N*384
  float* XCVhf = mu    + (size_t)N*384;      // N*192 (uints)
  float* CVf   = XCVhf + (size_t)N*192;      // N*192
  float* dq    = CVf   + (size_t)N*192;      // N*64
  float* dmu   = dq    + (size_t)N*64;       // N*192
  float* rW2Sf = dmu   + (size_t)N*192;      // f16 512KB = 131072 floats
  float* rb2T  = rW2Sf + (size_t)131072;     // 8192
  float* TV    = rb2T  + (size_t)8192;       // N*192
  float* MUI   = TV    + (size_t)N*192;      // N*192
  int*   cnt    = (int*)(MUI + (size_t)N*192); // N
  int*   startA = cnt    + N;                  // N+1
  int*   cursor = startA + (N + 1);            // N
  int*   elist  = cursor + N;                  // P
  int*   eJ     = elist  + P;                  // P
  unsigned*       XCVh = (unsigned*)XCVhf;
  unsigned short* rW2S = (unsigned short*)rW2Sf;

  hipMemsetAsync(mu, 0, (size_t)N*384*sizeof(float), stream);
  hipMemsetAsync(cnt, 0, (size_t)N*sizeof(int), stream);
  k_init_q<<<(N*FD + 255)/256, 256, 0, stream>>>(Z, embed, q, N);
  k_transpose_w<<<(2*64*64*32 + 255)/256, 256, 0, stream>>>(recW2, recb2, rW2S, rb2T);

  // CSR build + CSR-ordered edge records (idx fixed across layers)
  k_count<<<(P + 255)/256, 256, 0, stream>>>(idx_i, cnt, P);
  k_scan<<<1, 1024, 0, stream>>>(cnt, startA, cursor, N);
  k_scatter<<<(P + 255)/256, 256, 0, stream>>>(idx_i, cursor, elist, P);
  k_edgeprep<<<(P + 255)/256, 256, 0, stream>>>(Rij, elist, idx_j, eP, eJ, P);

  const int ablk4  = (N + 3) / 4;
  const int ablk16 = (N + 15) / 16;
  for (int l = 0; l < 2; ++l){
    k_atom_pre<<<ablk16, 256, 0, stream>>>(q, mu,
        ctxW1 + (size_t)l*64*64,  ctxb1 + (size_t)l*64,
        ctxW2 + (size_t)l*64*192, ctxb2 + (size_t)l*192,
        compW1 + (size_t)l*128*32, compb1 + (size_t)l*32,
        compW2 + (size_t)l*32*64,  compb2 + (size_t)l*64,
        XCVh, CVf, N);
    k_gather<<<ablk4, 256, 0, stream>>>(eP, eJ, startA, fW, fb, XCVh,
        dq, dmu, l, N);
    k_tv<<<ablk16, 512, 0, stream>>>(dmu, CVf,
        recW1 + (size_t)l*64*32, recb1 + (size_t)l*32,
        rW2S + (size_t)l*131072, rb2T + (size_t)l*4096,
        MUI, TV, N);
    k_mix2<<<ablk16, 256, 0, stream>>>(q, mu, dq, MUI, TV,
        mixW1 + (size_t)l*128*64, mixb1 + (size_t)l*64,
        mixW2 + (size_t)l*64*192, mixb2 + (size_t)l*192,
        muMixW + (size_t)l*64*128, N);
  }

  hipMemcpyAsync(d_out, q, (size_t)N*64*sizeof(float), hipMemcpyDeviceToDevice, stream);
  hipMemcpyAsync((float*)d_out + (size_t)N*64, mu, (size_t)N*384*sizeof(float),
                 hipMemcpyDeviceToDevice, stream);
}

// Round 14
// 539.015 us; speedup vs baseline: 1.6517x; 1.0057x over previous
//
#include <hip/hip_runtime.h>
#include <math.h>

#define FD 64
#define NRBF 20
#define CUT 5.0f
#define EPSV 1e-8f
#define PI_F 3.14159265358979f

typedef _Float16 h2v __attribute__((ext_vector_type(2)));

__device__ __forceinline__ float wredsum(float v){
#pragma unroll
  for (int m = 32; m >= 1; m >>= 1) v += __shfl_xor(v, m, 64);
  return v;
}
__device__ __forceinline__ float wredmax(float v){
#pragma unroll
  for (int m = 32; m >= 1; m >>= 1) v = fmaxf(v, __shfl_xor(v, m, 64));
  return v;
}
__device__ __forceinline__ float silu_f(float x){ return x * (1.0f / (1.0f + __expf(-x))); }
__device__ __forceinline__ h2v as_h2(unsigned u){
  union { unsigned u; h2v h; } x; x.u = u; return x.h;
}
__device__ __forceinline__ unsigned pack_bf16(float a, float b){
  unsigned ua = __float_as_uint(a), ub = __float_as_uint(b);
  ua = (ua + 0x7fffu + ((ua >> 16) & 1u)) >> 16;
  ub = (ub + 0x7fffu + ((ub >> 16) & 1u)) >> 16;
  return ua | (ub << 16);
}
__device__ __forceinline__ unsigned pack_f16(float a, float b){
  return __builtin_bit_cast(unsigned, __builtin_amdgcn_cvt_pkrtz(a, b));
}
#define BF_LO(u) __uint_as_float((u) << 16)
#define BF_HI(u) __uint_as_float((u) & 0xffff0000u)

// ---- CSR build: histogram, scan, scatter ----
__global__ __launch_bounds__(256) void k_count(const int* __restrict__ idx_i,
                                               int* __restrict__ cnt, int P)
{
  int p = blockIdx.x * blockDim.x + threadIdx.x;
  if (p < P) atomicAdd(&cnt[idx_i[p]], 1);
}

__global__ __launch_bounds__(1024) void k_scan(const int* __restrict__ cnt,
                                               int* __restrict__ start,
                                               int* __restrict__ cursor, int N)
{
  __shared__ int part[1024];
  int t = threadIdx.x;
  int chunk = (N + 1023) / 1024;
  int lo = t * chunk, hi = lo + chunk; if (hi > N) hi = N;
  int s = 0;
  for (int i = lo; i < hi; ++i) s += cnt[i];
  part[t] = s;
  __syncthreads();
  for (int off = 1; off < 1024; off <<= 1){
    int v = 0;
    if (t >= off) v = part[t - off];
    __syncthreads();
    if (t >= off) part[t] += v;
    __syncthreads();
  }
  int run = (t == 0) ? 0 : part[t-1];
  for (int i = lo; i < hi; ++i){ start[i] = run; cursor[i] = run; run += cnt[i]; }
  if (t == 1023) start[N] = run;
}

__global__ __launch_bounds__(256) void k_scatter(const int* __restrict__ idx_i,
                                                 int* __restrict__ cursor,
                                                 int* __restrict__ elist, int P)
{
  int p = blockIdx.x * blockDim.x + threadIdx.x;
  if (p < P){
    int pos = atomicAdd(&cursor[idx_i[p]], 1);
    elist[pos] = p;
  }
}

// ---- edge records in CSR order, 64B each:
// [0..3]=dir(3)+fcut (f32); [4..13]=phi*fcut packed f16 pairs (10 uints); [14..15]=pad ----
__global__ __launch_bounds__(256) void k_edgeprep(const float* __restrict__ Rij,
                                                  const int* __restrict__ elist,
                                                  const int* __restrict__ idx_j,
                                                  float* __restrict__ eP,
                                                  int* __restrict__ eJ, int P)
{
  int e = blockIdx.x * blockDim.x + threadIdx.x;
  if (e >= P) return;
  int p = elist[e];
  eJ[e] = idx_j[p];
  float rx = Rij[3*p+0], ry = Rij[3*p+1], rz = Rij[3*p+2];
  float d = sqrtf(rx*rx + ry*ry + rz*rz);
  float inv = 1.0f / d;
  float fc = (d < CUT) ? 0.5f * (__cosf(PI_F * d / CUT) + 1.0f) : 0.0f;
  float* pr = eP + (size_t)e * 16;
  pr[0] = rx*inv; pr[1] = ry*inv; pr[2] = rz*inv; pr[3] = fc;
  const float width = CUT / (float)(NRBF - 1);
  float ph[NRBF];
#pragma unroll
  for (int r = 0; r < NRBF; ++r){
    float t = (d - width * (float)r) / width;
    ph[r] = __expf(-0.5f * t * t) * fc;
  }
  unsigned* pu = (unsigned*)(pr + 4);
#pragma unroll
  for (int r = 0; r < 10; ++r) pu[r] = pack_f16(ph[2*r], ph[2*r+1]);
  pr[14] = 0.f; pr[15] = 0.f;
}

// ---- transpose rec_W2 -> f16 rW2S in [l][c][kq][f][8] layout (conflict-free b128);
//      rb2 -> rb2T[l][c][f] (f32) ----
__global__ __launch_bounds__(256) void k_transpose_w(const float* __restrict__ rW2,
                                                     const float* __restrict__ rb2,
                                                     unsigned short* __restrict__ rW2S,
                                                     float* __restrict__ rb2T)
{
  int t = blockIdx.x * blockDim.x + threadIdx.x;
  if (t < 2*64*64*32){
    int km = t & 7;
    int f  = (t >> 3) & 63;
    int kq = (t >> 9) & 3;
    int c  = (t >> 11) & 63;
    int l  = t >> 17;
    int k  = kq*8 + km;
    float v = rW2[((size_t)(l*32 + k))*4096 + f*64 + c];
    _Float16 hv = (_Float16)v;
    unsigned short us;
    __builtin_memcpy(&us, &hv, 2);
    rW2S[t] = us;
  }
  if (t < 2*64*64){
    int f = t & 63, c = (t >> 6) & 63, l = t >> 12;
    rb2T[t] = rb2[(size_t)l*4096 + f*64 + c];
  }
}

// ---- K_init: q = embed[Z] ----
__global__ __launch_bounds__(256) void k_init_q(const int* __restrict__ Z,
                                                const float* __restrict__ embed,
                                                float* __restrict__ q, int Ntot)
{
  int t = blockIdx.x * blockDim.x + threadIdx.x;
  if (t >= Ntot * FD) return;
  int n = t >> 6, f = t & 63;
  q[t] = embed[Z[n]*FD + f];
}

// ---- K1: per-atom pre. 16 atoms/block, weights LDS-staged.
// Writes XCVh (packed bf16) and CVf (f32). ----
__global__ __launch_bounds__(256) void k_atom_pre(
    const float* __restrict__ q, const float* __restrict__ mu,
    const float* __restrict__ cW1, const float* __restrict__ cb1,
    const float* __restrict__ cW2, const float* __restrict__ cb2,
    const float* __restrict__ pW1, const float* __restrict__ pb1,
    const float* __restrict__ pW2, const float* __restrict__ pb2,
    unsigned* __restrict__ XCVh, float* __restrict__ CVf, int Ntot)
{
  __shared__ float wbuf[12288];     // 48 KB
  __shared__ float qs[16][64];      // 4 KB
  __shared__ float sbuf[16][128];   // 8 KB
  __shared__ float h1s[16][64];     // 4 KB
  __shared__ float hcs[16][32];     // 2 KB
  int t = threadIdx.x;
  int w = t >> 6, f = t & 63;
  int base = blockIdx.x * 16;
  const int aw = w * 4;
  float4* wt4 = (float4*)wbuf;

  float m0a[4], m1a[4], m2a[4], m0b[4], m1b[4], m2b[4];
#pragma unroll
  for (int s = 0; s < 4; ++s){
    int a = aw + s;
    int n = base + a; if (n >= Ntot) n = Ntot - 1;
    qs[a][f] = q[(size_t)n*64 + f];
    const float* mun = mu + (size_t)n * 384;
    m0a[s] = mun[0*128 + f];      m1a[s] = mun[1*128 + f];      m2a[s] = mun[2*128 + f];
    m0b[s] = mun[0*128 + 64 + f]; m1b[s] = mun[1*128 + 64 + f]; m2b[s] = mun[2*128 + 64 + f];
    sbuf[a][f]      = sqrtf(m0a[s]*m0a[s] + m1a[s]*m1a[s] + m2a[s]*m2a[s] + EPSV);
    sbuf[a][64 + f] = sqrtf(m0b[s]*m0b[s] + m1b[s]*m1b[s] + m2b[s]*m2b[s] + EPSV);
  }
#pragma unroll
  for (int i = 0; i < 4; ++i) wt4[t + i*256] = ((const float4*)cW1)[t + i*256];
  __syncthreads();

  float hacc[4];
#pragma unroll
  for (int s = 0; s < 4; ++s) hacc[s] = cb1[f];
  for (int k = 0; k < 64; ++k){
    float wv = wbuf[k*64 + f];
#pragma unroll
    for (int s = 0; s < 4; ++s) hacc[s] = fmaf(qs[aw + s][k], wv, hacc[s]);
  }
#pragma unroll
  for (int s = 0; s < 4; ++s) h1s[aw + s][f] = silu_f(hacc[s]);

  __syncthreads();
#pragma unroll
  for (int i = 0; i < 12; ++i) wt4[t + i*256] = ((const float4*)cW2)[t + i*256];
  __syncthreads();

  float x0[4], x1[4], x2[4];
#pragma unroll
  for (int s = 0; s < 4; ++s){ x0[s] = cb2[f]; x1[s] = cb2[64+f]; x2[s] = cb2[128+f]; }
  for (int k = 0; k < 64; ++k){
    float u0 = wbuf[k*192 + f];
    float u1 = wbuf[k*192 + 64 + f];
    float u2 = wbuf[k*192 + 128 + f];
#pragma unroll
    for (int s = 0; s < 4; ++s){
      float h = h1s[aw + s][k];
      x0[s] = fmaf(h, u0, x0[s]); x1[s] = fmaf(h, u1, x1[s]); x2[s] = fmaf(h, u2, x2[s]);
    }
  }
#pragma unroll
  for (int s = 0; s < 4; ++s){
    int n = base + aw + s;
    if (n < Ntot) XCVh[(size_t)n*192 + f] = pack_bf16(x0[s], x1[s]);
  }

  __syncthreads();
#pragma unroll
  for (int i = 0; i < 4; ++i) wt4[t + i*256] = ((const float4*)pW1)[t + i*256];
#pragma unroll
  for (int i = 0; i < 2; ++i) wt4[1024 + t + i*256] = ((const float4*)pW2)[t + i*256];
  __syncthreads();

  int ki = f & 31;
#pragma unroll
  for (int p = 0; p < 2; ++p){
    int a_h = aw + p*2 + (f >> 5);
    float ah = pb1[ki];
#pragma unroll 4
    for (int c = 0; c < 128; ++c) ah = fmaf(sbuf[a_h][c], wbuf[c*32 + ki], ah);
    hcs[a_h][ki] = fmaxf(ah, 0.0f);
  }

  float logit[4];
#pragma unroll
  for (int s = 0; s < 4; ++s) logit[s] = pb2[f];
  for (int k = 0; k < 32; ++k){
    float wv = wbuf[4096 + k*64 + f];
#pragma unroll
    for (int s = 0; s < 4; ++s) logit[s] = fmaf(hcs[aw + s][k], wv, logit[s]);
  }
#pragma unroll
  for (int s = 0; s < 4; ++s){
    float mx = wredmax(logit[s]);
    float e  = __expf(logit[s] - mx);
    float se = wredsum(e);
    float wt = e / se;
    float v0 = wredsum(m0a[s] + m0b[s]);
    float v1 = wredsum(m1a[s] + m1b[s]);
    float v2 = wredsum(m2a[s] + m2b[s]);
    int n = base + aw + s;
    if (n < Ntot){
      float cv0 = v0 * wt, cv1 = v1 * wt, cv2 = v2 * wt;
      XCVh[(size_t)n*192 + 64 + f]  = pack_bf16(x2[s], cv0);
      XCVh[(size_t)n*192 + 128 + f] = pack_bf16(cv1, cv2);
      float* cvn = CVf + (size_t)n*192;
      cvn[f] = cv0; cvn[64+f] = cv1; cvn[128+f] = cv2;
    }
  }
}

// ---- K2: gather, 64B eP records, fdot2 filter MLP, packed-bf16 XCV. ----
__global__ __launch_bounds__(256) void k_gather(
    const float* __restrict__ eP, const int* __restrict__ eJ,
    const int* __restrict__ start,
    const float* __restrict__ fW, const float* __restrict__ fb,
    const unsigned* __restrict__ XCVh,
    float* __restrict__ dq, float* __restrict__ dmu, int l, int Ntot)
{
  int w = threadIdx.x >> 6;
  int f = threadIdx.x & 63;
  int i = blockIdx.x * 4 + w;
  if (i >= Ntot) return;
  const int col = l * 192;

  // hoist lane-f filter weights as packed f16 pairs (30 uints)
  unsigned fwp0[10], fwp1[10], fwp2[10];
#pragma unroll
  for (int r = 0; r < 10; ++r){
    const float* fa = fW + (2*r)*384 + col;
    const float* fbp = fW + (2*r+1)*384 + col;
    fwp0[r] = pack_f16(fa[f],       fbp[f]);
    fwp1[r] = pack_f16(fa[64 + f],  fbp[64 + f]);
    fwp2[r] = pack_f16(fa[128 + f], fbp[128 + f]);
  }
  float fb0 = fb[col + f], fb1 = fb[col + 64 + f], fb2 = fb[col + 128 + f];

  float dqa = 0.f, dm0 = 0.f, dm1 = 0.f, dm2 = 0.f;
  int e0 = start[i], e1 = start[i+1];
  int e = e0;
  for (; e + 2 <= e1; e += 2){
    int jA = eJ[e], jB = eJ[e+1];
    const float4* pr = (const float4*)(eP + (size_t)e * 16);
    const uint4*  pu = (const uint4*)pr;
    float4 A0 = pr[0];
    uint4  Ap0 = pu[1], Ap1 = pu[2], Ap2 = pu[3];
    float4 B0 = pr[4];
    uint4  Bp0 = pu[5], Bp1 = pu[6], Bp2 = pu[7];
    const unsigned* xA = XCVh + (size_t)jA * 192;
    const unsigned* xB = XCVh + (size_t)jB * 192;
    unsigned uA0=xA[f], uA1=xA[64+f], uA2=xA[128+f];
    unsigned uB0=xB[f], uB1=xB[64+f], uB2=xB[128+f];
    unsigned phA[10] = {Ap0.x,Ap0.y,Ap0.z,Ap0.w, Ap1.x,Ap1.y,Ap1.z,Ap1.w, Ap2.x,Ap2.y};
    unsigned phB[10] = {Bp0.x,Bp0.y,Bp0.z,Bp0.w, Bp1.x,Bp1.y,Bp1.z,Bp1.w, Bp2.x,Bp2.y};
    float wA0=fb0*A0.w, wA1=fb1*A0.w, wA2=fb2*A0.w;
    float wB0=fb0*B0.w, wB1=fb1*B0.w, wB2=fb2*B0.w;
#pragma unroll
    for (int r = 0; r < 10; ++r){
      wA0 = __builtin_amdgcn_fdot2(as_h2(phA[r]), as_h2(fwp0[r]), wA0, false);
      wA1 = __builtin_amdgcn_fdot2(as_h2(phA[r]), as_h2(fwp1[r]), wA1, false);
      wA2 = __builtin_amdgcn_fdot2(as_h2(phA[r]), as_h2(fwp2[r]), wA2, false);
      wB0 = __builtin_amdgcn_fdot2(as_h2(phB[r]), as_h2(fwp0[r]), wB0, false);
      wB1 = __builtin_amdgcn_fdot2(as_h2(phB[r]), as_h2(fwp1[r]), wB1, false);
      wB2 = __builtin_amdgcn_fdot2(as_h2(phB[r]), as_h2(fwp2[r]), wB2, false);
    }
    dqa = fmaf(BF_LO(uA0), wA0, dqa);
    float dmRA = BF_HI(uA0) * wA1, dmmA = BF_LO(uA1) * wA2;
    dm0 = fmaf(dmRA, A0.x, fmaf(dmmA, BF_HI(uA1), dm0));
    dm1 = fmaf(dmRA, A0.y, fmaf(dmmA, BF_LO(uA2), dm1));
    dm2 = fmaf(dmRA, A0.z, fmaf(dmmA, BF_HI(uA2), dm2));
    dqa = fmaf(BF_LO(uB0), wB0, dqa);
    float dmRB = BF_HI(uB0) * wB1, dmmB = BF_LO(uB1) * wB2;
    dm0 = fmaf(dmRB, B0.x, fmaf(dmmB, BF_HI(uB1), dm0));
    dm1 = fmaf(dmRB, B0.y, fmaf(dmmB, BF_LO(uB2), dm1));
    dm2 = fmaf(dmRB, B0.z, fmaf(dmmB, BF_HI(uB2), dm2));
  }
  if (e < e1){
    int j = eJ[e];
    const float4* pr = (const float4*)(eP + (size_t)e * 16);
    const uint4*  pu = (const uint4*)pr;
    float4 A0 = pr[0];
    uint4  Ap0 = pu[1], Ap1 = pu[2], Ap2 = pu[3];
    const unsigned* xj = XCVh + (size_t)j * 192;
    unsigned u0=xj[f], u1=xj[64+f], u2=xj[128+f];
    unsigned ph[10] = {Ap0.x,Ap0.y,Ap0.z,Ap0.w, Ap1.x,Ap1.y,Ap1.z,Ap1.w, Ap2.x,Ap2.y};
    float w0 = fb0 * A0.w, w1 = fb1 * A0.w, w2 = fb2 * A0.w;
#pragma unroll
    for (int r = 0; r < 10; ++r){
      w0 = __builtin_amdgcn_fdot2(as_h2(ph[r]), as_h2(fwp0[r]), w0, false);
      w1 = __builtin_amdgcn_fdot2(as_h2(ph[r]), as_h2(fwp1[r]), w1, false);
      w2 = __builtin_amdgcn_fdot2(as_h2(ph[r]), as_h2(fwp2[r]), w2, false);
    }
    dqa = fmaf(BF_LO(u0), w0, dqa);
    float dmR = BF_HI(u0) * w1, dmm = BF_LO(u1) * w2;
    dm0 = fmaf(dmR, A0.x, fmaf(dmm, BF_HI(u1), dm0));
    dm1 = fmaf(dmR, A0.y, fmaf(dmm, BF_LO(u2), dm1));
    dm2 = fmaf(dmR, A0.z, fmaf(dmm, BF_HI(u2), dm2));
  }
  dq[(size_t)i*64 + f] = dqa;
  float* dmn = dmu + (size_t)i*192;
  dmn[f] = dm0; dmn[64 + f] = dm1; dmn[128 + f] = dm2;
}

// ---- K3a: tv with f16 [c][kq][f][8] tiles (conflict-free) + fdot2. ----
__global__ __launch_bounds__(512) void k_tv(
    const float* __restrict__ dmuA, const float* __restrict__ CVf,
    const float* __restrict__ rW1, const float* __restrict__ rb1,
    const unsigned short* __restrict__ rW2S, const float* __restrict__ rb2Tl,
    float* __restrict__ MUI, float* __restrict__ TV, int Ntot)
{
  __shared__ float mus[16][3][64];  // 12 KB
  __shared__ float svs[16][64];     // 4 KB
  __shared__ float4 wt4[2048];      // 32 KB
  __shared__ float rbt[8][64];      // 2 KB
  int t = threadIdx.x;
  int w = t >> 6, f = t & 63;
  int base = blockIdx.x * 16;

#pragma unroll
  for (int s = 0; s < 2; ++s){
    int a = w*2 + s;
    int n = base + a; bool ok = (n < Ntot); if (!ok) n = Ntot - 1;
    const float* dmn = dmuA + (size_t)n*192;
    const float* cvn = CVf  + (size_t)n*192;
    float m0 = dmn[f]       + cvn[f];
    float m1 = dmn[64 + f]  + cvn[64 + f];
    float m2 = dmn[128 + f] + cvn[128 + f];
    mus[a][0][f] = m0; mus[a][1][f] = m1; mus[a][2][f] = m2;
    svs[a][f] = sqrtf(m0*m0 + m1*m1 + m2*m2 + EPSV);
    if (ok){
      float* mo = MUI + (size_t)n*192;
      mo[f] = m0; mo[64+f] = m1; mo[128+f] = m2;
    }
  }
  __syncthreads();

  int ki = f & 31;
  int a_h = w*2 + (f >> 5);
  float ah = rb1[ki];
#pragma unroll
  for (int c = 0; c < 64; ++c) ah = fmaf(svs[a_h][c], rW1[c*32 + ki], ah);
  ah = fmaxf(ah, 0.0f);
  unsigned hpk0[16], hpk1[16];
#pragma unroll
  for (int k = 0; k < 16; ++k){
    float a0 = __shfl(ah, 2*k, 64),      b0 = __shfl(ah, 2*k + 1, 64);
    float a1 = __shfl(ah, 32 + 2*k, 64), b1 = __shfl(ah, 32 + 2*k + 1, 64);
    hpk0[k] = pack_f16(a0, b0);
    hpk1[k] = pack_f16(a1, b1);
  }

  const int a0i = w*2, a1i = a0i + 1;
  float mf00 = mus[a0i][0][f], mf01 = mus[a0i][1][f], mf02 = mus[a0i][2][f];
  float mf10 = mus[a1i][0][f], mf11 = mus[a1i][1][f], mf12 = mus[a1i][2][f];
  float tv00=0,tv01=0,tv02=0, tv10=0,tv11=0,tv12=0;
  const uint4* wtu = reinterpret_cast<const uint4*>(wt4);

  for (int ct = 0; ct < 8; ++ct){
    __syncthreads();
    const float4* src = (const float4*)rW2S + (size_t)ct*2048;
#pragma unroll
    for (int i = 0; i < 4; ++i) wt4[t + i*512] = src[t + i*512];
    if (t < 128) ((float4*)rbt)[t] = ((const float4*)(rb2Tl + ct*512))[t];
    __syncthreads();

#pragma unroll
    for (int cc = 0; cc < 8; ++cc){
      int c = ct*8 + cc;
      float u00 = mus[a0i][0][c], u01 = mus[a0i][1][c], u02 = mus[a0i][2][c];
      float u10 = mus[a1i][0][c], u11 = mus[a1i][1][c], u12 = mus[a1i][2][c];
      float g0 = u00*mf00 + u01*mf01 + u02*mf02;
      float g1 = u10*mf10 + u11*mf11 + u12*mf12;
      float acc0 = rbt[cc][f];
      float acc1 = acc0;
#pragma unroll
      for (int kq = 0; kq < 4; ++kq){
        uint4 u = wtu[(cc*4 + kq)*64 + f];
        int k0 = kq*4;
        acc0 = __builtin_amdgcn_fdot2(as_h2(u.x), as_h2(hpk0[k0+0]), acc0, false);
        acc0 = __builtin_amdgcn_fdot2(as_h2(u.y), as_h2(hpk0[k0+1]), acc0, false);
        acc0 = __builtin_amdgcn_fdot2(as_h2(u.z), as_h2(hpk0[k0+2]), acc0, false);
        acc0 = __builtin_amdgcn_fdot2(as_h2(u.w), as_h2(hpk0[k0+3]), acc0, false);
        acc1 = __builtin_amdgcn_fdot2(as_h2(u.x), as_h2(hpk1[k0+0]), acc1, false);
        acc1 = __builtin_amdgcn_fdot2(as_h2(u.y), as_h2(hpk1[k0+1]), acc1, false);
        acc1 = __builtin_amdgcn_fdot2(as_h2(u.z), as_h2(hpk1[k0+2]), acc1, false);
        acc1 = __builtin_amdgcn_fdot2(as_h2(u.w), as_h2(hpk1[k0+3]), acc1, false);
      }
      float mm0 = acc0 * g0, mm1 = acc1 * g1;
      tv00 = fmaf(u00, mm0, tv00); tv01 = fmaf(u01, mm0, tv01); tv02 = fmaf(u02, mm0, tv02);
      tv10 = fmaf(u10, mm1, tv10); tv11 = fmaf(u11, mm1, tv11); tv12 = fmaf(u12, mm1, tv12);
    }
  }

  int n0 = base + a0i, n1 = base + a1i;
  if (n0 < Ntot){
    float* tvp = TV + (size_t)n0*192;
    tvp[f] = tv00; tvp[64+f] = tv01; tvp[128+f] = tv02;
  }
  if (n1 < Ntot){
    float* tvp = TV + (size_t)n1*192;
    tvp[f] = tv10; tvp[64+f] = tv11; tvp[128+f] = tv12;
  }
}

// ---- K3b: mixing tail. 16 atoms/block (4 per wave), weights LDS-staged. ----
__global__ __launch_bounds__(256) void k_mix2(
    float* __restrict__ q, float* __restrict__ mu,
    const float* __restrict__ dq, const float* __restrict__ MUI, const float* __restrict__ TV,
    const float* __restrict__ mW1, const float* __restrict__ mb1,
    const float* __restrict__ mW2, const float* __restrict__ mb2,
    const float* __restrict__ Wm, int Ntot)
{
  __shared__ float wbuf[12288];     // 48 KB
  __shared__ float mua[16][3][64];  // 12 KB
  __shared__ float ava[16][128];    // 8 KB
  __shared__ float h2a[16][64];     // 4 KB
  int t = threadIdx.x;
  int w = t >> 6, f = t & 63;
  int base = blockIdx.x * 16;
  const int aw = w * 4;
  float4* wt4 = (float4*)wbuf;

  float qv[4], m0[4], m1[4], m2[4];
#pragma unroll
  for (int s = 0; s < 4; ++s){
    int a = aw + s;
    int n = base + a; if (n >= Ntot) n = Ntot - 1;
    qv[s] = q[(size_t)n*64 + f] + dq[(size_t)n*64 + f];
    const float* mi = MUI + (size_t)n*192;
    m0[s] = mi[f]; m1[s] = mi[64 + f]; m2[s] = mi[128 + f];
    mua[a][0][f] = m0[s]; mua[a][1][f] = m1[s]; mua[a][2][f] = m2[s];
  }

#pragma unroll
  for (int i = 0; i < 8; ++i) wt4[t + i*256] = ((const float4*)Wm)[t + i*256];
  __syncthreads();

  float V0[4]={0,0,0,0}, V1[4]={0,0,0,0}, V2[4]={0,0,0,0};
  float W0[4]={0,0,0,0}, W1[4]={0,0,0,0}, W2[4]={0,0,0,0};
  for (int k = 0; k < 64; ++k){
    float wv = wbuf[k*128 + f];
    float ww = wbuf[k*128 + 64 + f];
#pragma unroll
    for (int s = 0; s < 4; ++s){
      int a = aw + s;
      float b0 = mua[a][0][k], b1 = mua[a][1][k], b2 = mua[a][2][k];
      V0[s] = fmaf(b0, wv, V0[s]); V1[s] = fmaf(b1, wv, V1[s]); V2[s] = fmaf(b2, wv, V2[s]);
      W0[s] = fmaf(b0, ww, W0[s]); W1[s] = fmaf(b1, ww, W1[s]); W2[s] = fmaf(b2, ww, W2[s]);
    }
  }
  float dot[4];
#pragma unroll
  for (int s = 0; s < 4; ++s){
    int a = aw + s;
    ava[a][f] = qv[s];
    ava[a][64 + f] = sqrtf(V0[s]*V0[s] + V1[s]*V1[s] + V2[s]*V2[s] + EPSV);
    dot[s] = V0[s]*W0[s] + V1[s]*W1[s] + V2[s]*W2[s];
  }

  __syncthreads();
#pragma unroll
  for (int i = 0; i < 8; ++i) wt4[t + i*256] = ((const float4*)mW1)[t + i*256];
  __syncthreads();

  float acc[4];
#pragma unroll
  for (int s = 0; s < 4; ++s) acc[s] = mb1[f];
  for (int k = 0; k < 128; ++k){
    float wv = wbuf[k*64 + f];
#pragma unroll
    for (int s = 0; s < 4; ++s) acc[s] = fmaf(ava[aw + s][k], wv, acc[s]);
  }
#pragma unroll
  for (int s = 0; s < 4; ++s) h2a[aw + s][f] = silu_f(acc[s]);

  __syncthreads();
#pragma unroll
  for (int i = 0; i < 12; ++i) wt4[t + i*256] = ((const float4*)mW2)[t + i*256];
  __syncthreads();

  float y0[4], y1[4], y2[4];
#pragma unroll
  for (int s = 0; s < 4; ++s){ y0[s] = mb2[f]; y1[s] = mb2[64+f]; y2[s] = mb2[128+f]; }
  for (int k = 0; k < 64; ++k){
    float u0 = wbuf[k*192 + f];
    float u1 = wbuf[k*192 + 64 + f];
    float u2 = wbuf[k*192 + 128 + f];
#pragma unroll
    for (int s = 0; s < 4; ++s){
      float h = h2a[aw + s][k];
      y0[s] = fmaf(h, u0, y0[s]); y1[s] = fmaf(h, u1, y1[s]); y2[s] = fmaf(h, u2, y2[s]);
    }
  }

#pragma unroll
  for (int s = 0; s < 4; ++s){
    int n = base + aw + s;
    if (n < Ntot){
      q[(size_t)n*64 + f] = qv[s] + y0[s] + y2[s]*dot[s];
      const float* tvp = TV + (size_t)n*192;
      float* mun = mu + (size_t)n*384;
      mun[0*128 + f] = fmaf(y1[s], W0[s], m0[s]); mun[0*128 + 64 + f] = tvp[f];
      mun[1*128 + f] = fmaf(y1[s], W1[s], m1[s]); mun[1*128 + 64 + f] = tvp[64+f];
      mun[2*128 + f] = fmaf(y1[s], W2[s], m2[s]); mun[2*128 + 64 + f] = tvp[128+f];
    }
  }
}

extern "C" void kernel_launch(void* const* d_in, const int* in_sizes, int n_in,
                              void* d_out, int out_size, void* d_ws, size_t ws_size,
                              hipStream_t stream)
{
  const int*   Z      = (const int*)  d_in[0];
  const float* Rij    = (const float*)d_in[1];
  const int*   idx_i  = (const int*)  d_in[2];
  const int*   idx_j  = (const int*)  d_in[3];
  const float* embed  = (const float*)d_in[5];
  const float* fW     = (const float*)d_in[6];
  const float* fb     = (const float*)d_in[7];
  const float* ctxW1  = (const float*)d_in[8];
  const float* ctxb1  = (const float*)d_in[9];
  const float* ctxW2  = (const float*)d_in[10];
  const float* ctxb2  = (const float*)d_in[11];
  const float* compW1 = (const float*)d_in[12];
  const float* compb1 = (const float*)d_in[13];
  const float* compW2 = (const float*)d_in[14];
  const float* compb2 = (const float*)d_in[15];
  const float* recW1  = (const float*)d_in[16];
  const float* recb1  = (const float*)d_in[17];
  const float* recW2  = (const float*)d_in[18];
  const float* recb2  = (const float*)d_in[19];
  const float* mixW1  = (const float*)d_in[20];
  const float* mixb1  = (const float*)d_in[21];
  const float* mixW2  = (const float*)d_in[22];
  const float* mixb2  = (const float*)d_in[23];
  const float* muMixW = (const float*)d_in[24];

  const int N = in_sizes[0];
  const int P = in_sizes[1] / 3;

  float* ws    = (float*)d_ws;
  float* eP    = ws;                         // P*16 (64B records)
  float* q     = eP    + (size_t)P*16;       // N*64
  float* mu    = q     + (size_t)N*64;       // N*384
  float* XCVhf = mu    + (size_t)N*384;      // N*192 (uints)
  float* CVf   = XCVhf + (size_t)N*192;      // N*192
  float* dq    = CVf   + (size_t)N*192;      // N*64
  float* dmu   = dq    + (size_t)N*64;       // N*192
  float* rW2Sf = dmu   + (size_t)N*192;      // f16 512KB = 131072 floats
  float* rb2T  = rW2Sf + (size_t)131072;     // 8192
  float* TV    = rb2T  + (size_t)8192;       // N*192
  float* MUI   = TV    + (size_t)N*192;      // N*192
  int*   cnt    = (int*)(MUI + (size_t)N*192); // N
  int*   startA = cnt    + N;                  // N+1
  int*   cursor = startA + (N + 1);            // N
  int*   elist  = cursor + N;                  // P
  int*   eJ     = elist  + P;                  // P
  unsigned*       XCVh = (unsigned*)XCVhf;
  unsigned short* rW2S = (unsigned short*)rW2Sf;

  hipMemsetAsync(mu, 0, (size_t)N*384*sizeof(float), stream);
  hipMemsetAsync(cnt, 0, (size_t)N*sizeof(int), stream);
  k_init_q<<<(N*FD + 255)/256, 256, 0, stream>>>(Z, embed, q, N);
  k_transpose_w<<<(2*64*64*32 + 255)/256, 256, 0, stream>>>(recW2, recb2, rW2S, rb2T);

  // CSR build + CSR-ordered edge records (idx fixed across layers)
  k_count<<<(P + 255)/256, 256, 0, stream>>>(idx_i, cnt, P);
  k_scan<<<1, 1024, 0, stream>>>(cnt, startA, cursor, N);
  k_scatter<<<(P + 255)/256, 256, 0, stream>>>(idx_i, cursor, elist, P);
  k_edgeprep<<<(P + 255)/256, 256, 0, stream>>>(Rij, elist, idx_j, eP, eJ, P);

  const int ablk4  = (N + 3) / 4;
  const int ablk16 = (N + 15) / 16;
  for (int l = 0; l < 2; ++l){
    k_atom_pre<<<ablk16, 256, 0, stream>>>(q, mu,
        ctxW1 + (size_t)l*64*64,  ctxb1 + (size_t)l*64,
        ctxW2 + (size_t)l*64*192, ctxb2 + (size_t)l*192,
        compW1 + (size_t)l*128*32, compb1 + (size_t)l*32,
        compW2 + (size_t)l*32*64,  compb2 + (size_t)l*64,
        XCVh, CVf, N);
    k_gather<<<ablk4, 256, 0, stream>>>(eP, eJ, startA, fW, fb, XCVh,
        dq, dmu, l, N);
    k_tv<<<ablk16, 512, 0, stream>>>(dmu, CVf,
        recW1 + (size_t)l*64*32, recb1 + (size_t)l*32,
        rW2S + (size_t)l*131072, rb2T + (size_t)l*4096,
        MUI, TV, N);
    k_mix2<<<ablk16, 256, 0, stream>>>(q, mu, dq, MUI, TV,
        mixW1 + (size_t)l*128*64, mixb1 + (size_t)l*64,
        mixW2 + (size_t)l*64*192, mixb2 + (size_t)l*192,
        muMixW + (size_t)l*64*128, N);
  }

  hipMemcpyAsync(d_out, q, (size_t)N*64*sizeof(float), hipMemcpyDeviceToDevice, stream);
  hipMemcpyAsync((float*)d_out + (size_t)N*64, mu, (size_t)N*384*sizeof(float),
                 hipMemcpyDeviceToDevice, stream);
}

// Round 15
// 530.478 us; speedup vs baseline: 1.6783x; 1.0161x over previous
//
#include <hip/hip_runtime.h>
#include <math.h>

#define FD 64
#define NRBF 20
#define CUT 5.0f
#define EPSV 1e-8f
#define PI_F 3.14159265358979f

typedef _Float16 h2v __attribute__((ext_vector_type(2)));

__device__ __forceinline__ float wredsum(float v){
#pragma unroll
  for (int m = 32; m >= 1; m >>= 1) v += __shfl_xor(v, m, 64);
  return v;
}
__device__ __forceinline__ float wredmax(float v){
#pragma unroll
  for (int m = 32; m >= 1; m >>= 1) v = fmaxf(v, __shfl_xor(v, m, 64));
  return v;
}
__device__ __forceinline__ float silu_f(float x){ return x * (1.0f / (1.0f + __expf(-x))); }
__device__ __forceinline__ h2v as_h2(unsigned u){
  union { unsigned u; h2v h; } x; x.u = u; return x.h;
}
__device__ __forceinline__ unsigned pack_bf16(float a, float b){
  unsigned ua = __float_as_uint(a), ub = __float_as_uint(b);
  ua = (ua + 0x7fffu + ((ua >> 16) & 1u)) >> 16;
  ub = (ub + 0x7fffu + ((ub >> 16) & 1u)) >> 16;
  return ua | (ub << 16);
}
__device__ __forceinline__ unsigned pack_f16(float a, float b){
  return __builtin_bit_cast(unsigned, __builtin_amdgcn_cvt_pkrtz(a, b));
}
#define BF_LO(u) __uint_as_float((u) << 16)
#define BF_HI(u) __uint_as_float((u) & 0xffff0000u)

// ---- CSR build: histogram, scan, scatter ----
__global__ __launch_bounds__(256) void k_count(const int* __restrict__ idx_i,
                                               int* __restrict__ cnt, int P)
{
  int p = blockIdx.x * blockDim.x + threadIdx.x;
  if (p < P) atomicAdd(&cnt[idx_i[p]], 1);
}

__global__ __launch_bounds__(1024) void k_scan(const int* __restrict__ cnt,
                                               int* __restrict__ start,
                                               int* __restrict__ cursor, int N)
{
  __shared__ int part[1024];
  int t = threadIdx.x;
  int chunk = (N + 1023) / 1024;
  int lo = t * chunk, hi = lo + chunk; if (hi > N) hi = N;
  int s = 0;
  for (int i = lo; i < hi; ++i) s += cnt[i];
  part[t] = s;
  __syncthreads();
  for (int off = 1; off < 1024; off <<= 1){
    int v = 0;
    if (t >= off) v = part[t - off];
    __syncthreads();
    if (t >= off) part[t] += v;
    __syncthreads();
  }
  int run = (t == 0) ? 0 : part[t-1];
  for (int i = lo; i < hi; ++i){ start[i] = run; cursor[i] = run; run += cnt[i]; }
  if (t == 1023) start[N] = run;
}

__global__ __launch_bounds__(256) void k_scatter(const int* __restrict__ idx_i,
                                                 int* __restrict__ cursor,
                                                 int* __restrict__ elist, int P)
{
  int p = blockIdx.x * blockDim.x + threadIdx.x;
  if (p < P){
    int pos = atomicAdd(&cursor[idx_i[p]], 1);
    elist[pos] = p;
  }
}

// ---- edge records in CSR order, 64B each:
// [0..3]=dir(3)+fcut (f32); [4..13]=phi*fcut packed f16 pairs; [14..15]=pad ----
__global__ __launch_bounds__(256) void k_edgeprep(const float* __restrict__ Rij,
                                                  const int* __restrict__ elist,
                                                  const int* __restrict__ idx_j,
                                                  float* __restrict__ eP,
                                                  int* __restrict__ eJ, int P)
{
  int e = blockIdx.x * blockDim.x + threadIdx.x;
  if (e >= P) return;
  int p = elist[e];
  eJ[e] = idx_j[p];
  float rx = Rij[3*p+0], ry = Rij[3*p+1], rz = Rij[3*p+2];
  float d = sqrtf(rx*rx + ry*ry + rz*rz);
  float inv = 1.0f / d;
  float fc = (d < CUT) ? 0.5f * (__cosf(PI_F * d / CUT) + 1.0f) : 0.0f;
  float* pr = eP + (size_t)e * 16;
  pr[0] = rx*inv; pr[1] = ry*inv; pr[2] = rz*inv; pr[3] = fc;
  const float width = CUT / (float)(NRBF - 1);
  float ph[NRBF];
#pragma unroll
  for (int r = 0; r < NRBF; ++r){
    float t = (d - width * (float)r) / width;
    ph[r] = __expf(-0.5f * t * t) * fc;
  }
  unsigned* pu = (unsigned*)(pr + 4);
#pragma unroll
  for (int r = 0; r < 10; ++r) pu[r] = pack_f16(ph[2*r], ph[2*r+1]);
  pr[14] = 0.f; pr[15] = 0.f;
}

// ---- transpose rec_W2 -> f16 rW2S in [l][c][kq][f][8] layout; rb2 -> rb2T ----
__global__ __launch_bounds__(256) void k_transpose_w(const float* __restrict__ rW2,
                                                     const float* __restrict__ rb2,
                                                     unsigned short* __restrict__ rW2S,
                                                     float* __restrict__ rb2T)
{
  int t = blockIdx.x * blockDim.x + threadIdx.x;
  if (t < 2*64*64*32){
    int km = t & 7;
    int f  = (t >> 3) & 63;
    int kq = (t >> 9) & 3;
    int c  = (t >> 11) & 63;
    int l  = t >> 17;
    int k  = kq*8 + km;
    float v = rW2[((size_t)(l*32 + k))*4096 + f*64 + c];
    _Float16 hv = (_Float16)v;
    unsigned short us;
    __builtin_memcpy(&us, &hv, 2);
    rW2S[t] = us;
  }
  if (t < 2*64*64){
    int f = t & 63, c = (t >> 6) & 63, l = t >> 12;
    rb2T[t] = rb2[(size_t)l*4096 + f*64 + c];
  }
}

// ---- K_init: q = embed[Z] ----
__global__ __launch_bounds__(256) void k_init_q(const int* __restrict__ Z,
                                                const float* __restrict__ embed,
                                                float* __restrict__ q, int Ntot)
{
  int t = blockIdx.x * blockDim.x + threadIdx.x;
  if (t >= Ntot * FD) return;
  int n = t >> 6, f = t & 63;
  q[t] = embed[Z[n]*FD + f];
}

// ---- K1: per-atom pre. 16 atoms/block, weights LDS-staged. ----
__global__ __launch_bounds__(256) void k_atom_pre(
    const float* __restrict__ q, const float* __restrict__ mu,
    const float* __restrict__ cW1, const float* __restrict__ cb1,
    const float* __restrict__ cW2, const float* __restrict__ cb2,
    const float* __restrict__ pW1, const float* __restrict__ pb1,
    const float* __restrict__ pW2, const float* __restrict__ pb2,
    unsigned* __restrict__ XCVh, float* __restrict__ CVf, int Ntot)
{
  __shared__ float wbuf[12288];     // 48 KB
  __shared__ float qs[16][64];      // 4 KB
  __shared__ float sbuf[16][128];   // 8 KB
  __shared__ float h1s[16][64];     // 4 KB
  __shared__ float hcs[16][32];     // 2 KB
  int t = threadIdx.x;
  int w = t >> 6, f = t & 63;
  int base = blockIdx.x * 16;
  const int aw = w * 4;
  float4* wt4 = (float4*)wbuf;

  float m0a[4], m1a[4], m2a[4], m0b[4], m1b[4], m2b[4];
#pragma unroll
  for (int s = 0; s < 4; ++s){
    int a = aw + s;
    int n = base + a; if (n >= Ntot) n = Ntot - 1;
    qs[a][f] = q[(size_t)n*64 + f];
    const float* mun = mu + (size_t)n * 384;
    m0a[s] = mun[0*128 + f];      m1a[s] = mun[1*128 + f];      m2a[s] = mun[2*128 + f];
    m0b[s] = mun[0*128 + 64 + f]; m1b[s] = mun[1*128 + 64 + f]; m2b[s] = mun[2*128 + 64 + f];
    sbuf[a][f]      = sqrtf(m0a[s]*m0a[s] + m1a[s]*m1a[s] + m2a[s]*m2a[s] + EPSV);
    sbuf[a][64 + f] = sqrtf(m0b[s]*m0b[s] + m1b[s]*m1b[s] + m2b[s]*m2b[s] + EPSV);
  }
#pragma unroll
  for (int i = 0; i < 4; ++i) wt4[t + i*256] = ((const float4*)cW1)[t + i*256];
  __syncthreads();

  float hacc[4];
#pragma unroll
  for (int s = 0; s < 4; ++s) hacc[s] = cb1[f];
  for (int k = 0; k < 64; ++k){
    float wv = wbuf[k*64 + f];
#pragma unroll
    for (int s = 0; s < 4; ++s) hacc[s] = fmaf(qs[aw + s][k], wv, hacc[s]);
  }
#pragma unroll
  for (int s = 0; s < 4; ++s) h1s[aw + s][f] = silu_f(hacc[s]);

  __syncthreads();
#pragma unroll
  for (int i = 0; i < 12; ++i) wt4[t + i*256] = ((const float4*)cW2)[t + i*256];
  __syncthreads();

  float x0[4], x1[4], x2[4];
#pragma unroll
  for (int s = 0; s < 4; ++s){ x0[s] = cb2[f]; x1[s] = cb2[64+f]; x2[s] = cb2[128+f]; }
  for (int k = 0; k < 64; ++k){
    float u0 = wbuf[k*192 + f];
    float u1 = wbuf[k*192 + 64 + f];
    float u2 = wbuf[k*192 + 128 + f];
#pragma unroll
    for (int s = 0; s < 4; ++s){
      float h = h1s[aw + s][k];
      x0[s] = fmaf(h, u0, x0[s]); x1[s] = fmaf(h, u1, x1[s]); x2[s] = fmaf(h, u2, x2[s]);
    }
  }
#pragma unroll
  for (int s = 0; s < 4; ++s){
    int n = base + aw + s;
    if (n < Ntot) XCVh[(size_t)n*192 + f] = pack_bf16(x0[s], x1[s]);
  }

  __syncthreads();
#pragma unroll
  for (int i = 0; i < 4; ++i) wt4[t + i*256] = ((const float4*)pW1)[t + i*256];
#pragma unroll
  for (int i = 0; i < 2; ++i) wt4[1024 + t + i*256] = ((const float4*)pW2)[t + i*256];
  __syncthreads();

  int ki = f & 31;
#pragma unroll
  for (int p = 0; p < 2; ++p){
    int a_h = aw + p*2 + (f >> 5);
    float ah = pb1[ki];
#pragma unroll 4
    for (int c = 0; c < 128; ++c) ah = fmaf(sbuf[a_h][c], wbuf[c*32 + ki], ah);
    hcs[a_h][ki] = fmaxf(ah, 0.0f);
  }

  float logit[4];
#pragma unroll
  for (int s = 0; s < 4; ++s) logit[s] = pb2[f];
  for (int k = 0; k < 32; ++k){
    float wv = wbuf[4096 + k*64 + f];
#pragma unroll
    for (int s = 0; s < 4; ++s) logit[s] = fmaf(hcs[aw + s][k], wv, logit[s]);
  }
#pragma unroll
  for (int s = 0; s < 4; ++s){
    float mx = wredmax(logit[s]);
    float e  = __expf(logit[s] - mx);
    float se = wredsum(e);
    float wt = e / se;
    float v0 = wredsum(m0a[s] + m0b[s]);
    float v1 = wredsum(m1a[s] + m1b[s]);
    float v2 = wredsum(m2a[s] + m2b[s]);
    int n = base + aw + s;
    if (n < Ntot){
      float cv0 = v0 * wt, cv1 = v1 * wt, cv2 = v2 * wt;
      XCVh[(size_t)n*192 + 64 + f]  = pack_bf16(x2[s], cv0);
      XCVh[(size_t)n*192 + 128 + f] = pack_bf16(cv1, cv2);
      float* cvn = CVf + (size_t)n*192;
      cvn[f] = cv0; cvn[64+f] = cv1; cvn[128+f] = cv2;
    }
  }
}

// ---- K2: gather, unroll-4 edge pipeline (latency hiding), fdot2 MLP, bf16 XCV. ----
__global__ __launch_bounds__(256) void k_gather(
    const float* __restrict__ eP, const int* __restrict__ eJ,
    const int* __restrict__ start,
    const float* __restrict__ fW, const float* __restrict__ fb,
    const unsigned* __restrict__ XCVh,
    float* __restrict__ dq, float* __restrict__ dmu, int l, int Ntot)
{
  int w = threadIdx.x >> 6;
  int f = threadIdx.x & 63;
  int i = blockIdx.x * 4 + w;
  if (i >= Ntot) return;
  const int col = l * 192;

  unsigned fwp0[10], fwp1[10], fwp2[10];
#pragma unroll
  for (int r = 0; r < 10; ++r){
    const float* fa = fW + (2*r)*384 + col;
    const float* fbp = fW + (2*r+1)*384 + col;
    fwp0[r] = pack_f16(fa[f],       fbp[f]);
    fwp1[r] = pack_f16(fa[64 + f],  fbp[64 + f]);
    fwp2[r] = pack_f16(fa[128 + f], fbp[128 + f]);
  }
  float fb0 = fb[col + f], fb1 = fb[col + 64 + f], fb2 = fb[col + 128 + f];

  float dqa = 0.f, dm0 = 0.f, dm1 = 0.f, dm2 = 0.f;
  int e0 = start[i], e1 = start[i+1];
  int e = e0;
  for (; e + 4 <= e1; e += 4){
    int jj[4];
    float4 d4[4];
    uint4  p0[4], p1[4], p2[4];
    unsigned xv0[4], xv1[4], xv2[4];
#pragma unroll
    for (int u = 0; u < 4; ++u) jj[u] = eJ[e + u];
#pragma unroll
    for (int u = 0; u < 4; ++u){
      const float4* pr = (const float4*)(eP + (size_t)(e + u) * 16);
      const uint4*  pui = (const uint4*)pr;
      d4[u] = pr[0]; p0[u] = pui[1]; p1[u] = pui[2]; p2[u] = pui[3];
    }
#pragma unroll
    for (int u = 0; u < 4; ++u){
      const unsigned* xj = XCVh + (size_t)jj[u] * 192;
      xv0[u] = xj[f]; xv1[u] = xj[64 + f]; xv2[u] = xj[128 + f];
    }
#pragma unroll
    for (int u = 0; u < 4; ++u){
      unsigned ph[10] = {p0[u].x,p0[u].y,p0[u].z,p0[u].w,
                         p1[u].x,p1[u].y,p1[u].z,p1[u].w,
                         p2[u].x,p2[u].y};
      float fc = d4[u].w;
      float w0 = fb0 * fc, w1 = fb1 * fc, w2 = fb2 * fc;
#pragma unroll
      for (int r = 0; r < 10; ++r){
        w0 = __builtin_amdgcn_fdot2(as_h2(ph[r]), as_h2(fwp0[r]), w0, false);
        w1 = __builtin_amdgcn_fdot2(as_h2(ph[r]), as_h2(fwp1[r]), w1, false);
        w2 = __builtin_amdgcn_fdot2(as_h2(ph[r]), as_h2(fwp2[r]), w2, false);
      }
      dqa = fmaf(BF_LO(xv0[u]), w0, dqa);
      float dmR = BF_HI(xv0[u]) * w1, dmm = BF_LO(xv1[u]) * w2;
      dm0 = fmaf(dmR, d4[u].x, fmaf(dmm, BF_HI(xv1[u]), dm0));
      dm1 = fmaf(dmR, d4[u].y, fmaf(dmm, BF_LO(xv2[u]), dm1));
      dm2 = fmaf(dmR, d4[u].z, fmaf(dmm, BF_HI(xv2[u]), dm2));
    }
  }
  for (; e < e1; ++e){
    int j = eJ[e];
    const float4* pr = (const float4*)(eP + (size_t)e * 16);
    const uint4*  pu = (const uint4*)pr;
    float4 A0 = pr[0];
    uint4  Ap0 = pu[1], Ap1 = pu[2], Ap2 = pu[3];
    const unsigned* xj = XCVh + (size_t)j * 192;
    unsigned u0=xj[f], u1=xj[64+f], u2=xj[128+f];
    unsigned ph[10] = {Ap0.x,Ap0.y,Ap0.z,Ap0.w, Ap1.x,Ap1.y,Ap1.z,Ap1.w, Ap2.x,Ap2.y};
    float w0 = fb0 * A0.w, w1 = fb1 * A0.w, w2 = fb2 * A0.w;
#pragma unroll
    for (int r = 0; r < 10; ++r){
      w0 = __builtin_amdgcn_fdot2(as_h2(ph[r]), as_h2(fwp0[r]), w0, false);
      w1 = __builtin_amdgcn_fdot2(as_h2(ph[r]), as_h2(fwp1[r]), w1, false);
      w2 = __builtin_amdgcn_fdot2(as_h2(ph[r]), as_h2(fwp2[r]), w2, false);
    }
    dqa = fmaf(BF_LO(u0), w0, dqa);
    float dmR = BF_HI(u0) * w1, dmm = BF_LO(u1) * w2;
    dm0 = fmaf(dmR, A0.x, fmaf(dmm, BF_HI(u1), dm0));
    dm1 = fmaf(dmR, A0.y, fmaf(dmm, BF_LO(u2), dm1));
    dm2 = fmaf(dmR, A0.z, fmaf(dmm, BF_HI(u2), dm2));
  }
  dq[(size_t)i*64 + f] = dqa;
  float* dmn = dmu + (size_t)i*192;
  dmn[f] = dm0; dmn[64 + f] = dm1; dmn[128 + f] = dm2;
}

// ---- K3a: tv with f16 [c][kq][f][8] tiles (conflict-free) + fdot2. ----
__global__ __launch_bounds__(512) void k_tv(
    const float* __restrict__ dmuA, const float* __restrict__ CVf,
    const float* __restrict__ rW1, const float* __restrict__ rb1,
    const unsigned short* __restrict__ rW2S, const float* __restrict__ rb2Tl,
    float* __restrict__ MUI, float* __restrict__ TV, int Ntot)
{
  __shared__ float mus[16][3][64];  // 12 KB
  __shared__ float svs[16][64];     // 4 KB
  __shared__ float4 wt4[2048];      // 32 KB
  __shared__ float rbt[8][64];      // 2 KB
  int t = threadIdx.x;
  int w = t >> 6, f = t & 63;
  int base = blockIdx.x * 16;

#pragma unroll
  for (int s = 0; s < 2; ++s){
    int a = w*2 + s;
    int n = base + a; bool ok = (n < Ntot); if (!ok) n = Ntot - 1;
    const float* dmn = dmuA + (size_t)n*192;
    const float* cvn = CVf  + (size_t)n*192;
    float m0 = dmn[f]       + cvn[f];
    float m1 = dmn[64 + f]  + cvn[64 + f];
    float m2 = dmn[128 + f] + cvn[128 + f];
    mus[a][0][f] = m0; mus[a][1][f] = m1; mus[a][2][f] = m2;
    svs[a][f] = sqrtf(m0*m0 + m1*m1 + m2*m2 + EPSV);
    if (ok){
      float* mo = MUI + (size_t)n*192;
      mo[f] = m0; mo[64+f] = m1; mo[128+f] = m2;
    }
  }
  __syncthreads();

  int ki = f & 31;
  int a_h = w*2 + (f >> 5);
  float ah = rb1[ki];
#pragma unroll
  for (int c = 0; c < 64; ++c) ah = fmaf(svs[a_h][c], rW1[c*32 + ki], ah);
  ah = fmaxf(ah, 0.0f);
  unsigned hpk0[16], hpk1[16];
#pragma unroll
  for (int k = 0; k < 16; ++k){
    float a0 = __shfl(ah, 2*k, 64),      b0 = __shfl(ah, 2*k + 1, 64);
    float a1 = __shfl(ah, 32 + 2*k, 64), b1 = __shfl(ah, 32 + 2*k + 1, 64);
    hpk0[k] = pack_f16(a0, b0);
    hpk1[k] = pack_f16(a1, b1);
  }

  const int a0i = w*2, a1i = a0i + 1;
  float mf00 = mus[a0i][0][f], mf01 = mus[a0i][1][f], mf02 = mus[a0i][2][f];
  float mf10 = mus[a1i][0][f], mf11 = mus[a1i][1][f], mf12 = mus[a1i][2][f];
  float tv00=0,tv01=0,tv02=0, tv10=0,tv11=0,tv12=0;
  const uint4* wtu = reinterpret_cast<const uint4*>(wt4);

  for (int ct = 0; ct < 8; ++ct){
    __syncthreads();
    const float4* src = (const float4*)rW2S + (size_t)ct*2048;
#pragma unroll
    for (int i = 0; i < 4; ++i) wt4[t + i*512] = src[t + i*512];
    if (t < 128) ((float4*)rbt)[t] = ((const float4*)(rb2Tl + ct*512))[t];
    __syncthreads();

#pragma unroll
    for (int cc = 0; cc < 8; ++cc){
      int c = ct*8 + cc;
      float u00 = mus[a0i][0][c], u01 = mus[a0i][1][c], u02 = mus[a0i][2][c];
      float u10 = mus[a1i][0][c], u11 = mus[a1i][1][c], u12 = mus[a1i][2][c];
      float g0 = u00*mf00 + u01*mf01 + u02*mf02;
      float g1 = u10*mf10 + u11*mf11 + u12*mf12;
      float acc0 = rbt[cc][f];
      float acc1 = acc0;
#pragma unroll
      for (int kq = 0; kq < 4; ++kq){
        uint4 u = wtu[(cc*4 + kq)*64 + f];
        int k0 = kq*4;
        acc0 = __builtin_amdgcn_fdot2(as_h2(u.x), as_h2(hpk0[k0+0]), acc0, false);
        acc0 = __builtin_amdgcn_fdot2(as_h2(u.y), as_h2(hpk0[k0+1]), acc0, false);
        acc0 = __builtin_amdgcn_fdot2(as_h2(u.z), as_h2(hpk0[k0+2]), acc0, false);
        acc0 = __builtin_amdgcn_fdot2(as_h2(u.w), as_h2(hpk0[k0+3]), acc0, false);
        acc1 = __builtin_amdgcn_fdot2(as_h2(u.x), as_h2(hpk1[k0+0]), acc1, false);
        acc1 = __builtin_amdgcn_fdot2(as_h2(u.y), as_h2(hpk1[k0+1]), acc1, false);
        acc1 = __builtin_amdgcn_fdot2(as_h2(u.z), as_h2(hpk1[k0+2]), acc1, false);
        acc1 = __builtin_amdgcn_fdot2(as_h2(u.w), as_h2(hpk1[k0+3]), acc1, false);
      }
      float mm0 = acc0 * g0, mm1 = acc1 * g1;
      tv00 = fmaf(u00, mm0, tv00); tv01 = fmaf(u01, mm0, tv01); tv02 = fmaf(u02, mm0, tv02);
      tv10 = fmaf(u10, mm1, tv10); tv11 = fmaf(u11, mm1, tv11); tv12 = fmaf(u12, mm1, tv12);
    }
  }

  int n0 = base + a0i, n1 = base + a1i;
  if (n0 < Ntot){
    float* tvp = TV + (size_t)n0*192;
    tvp[f] = tv00; tvp[64+f] = tv01; tvp[128+f] = tv02;
  }
  if (n1 < Ntot){
    float* tvp = TV + (size_t)n1*192;
    tvp[f] = tv10; tvp[64+f] = tv11; tvp[128+f] = tv12;
  }
}

// ---- K3b: mixing tail. 16 atoms/block (4 per wave), weights LDS-staged. ----
__global__ __launch_bounds__(256) void k_mix2(
    float* __restrict__ q, float* __restrict__ mu,
    const float* __restrict__ dq, const float* __restrict__ MUI, const float* __restrict__ TV,
    const float* __restrict__ mW1, const float* __restrict__ mb1,
    const float* __restrict__ mW2, const float* __restrict__ mb2,
    const float* __restrict__ Wm, int Ntot)
{
  __shared__ float wbuf[12288];     // 48 KB
  __shared__ float mua[16][3][64];  // 12 KB
  __shared__ float ava[16][128];    // 8 KB
  __shared__ float h2a[16][64];     // 4 KB
  int t = threadIdx.x;
  int w = t >> 6, f = t & 63;
  int base = blockIdx.x * 16;
  const int aw = w * 4;
  float4* wt4 = (float4*)wbuf;

  float qv[4], m0[4], m1[4], m2[4];
#pragma unroll
  for (int s = 0; s < 4; ++s){
    int a = aw + s;
    int n = base + a; if (n >= Ntot) n = Ntot - 1;
    qv[s] = q[(size_t)n*64 + f] + dq[(size_t)n*64 + f];
    const float* mi = MUI + (size_t)n*192;
    m0[s] = mi[f]; m1[s] = mi[64 + f]; m2[s] = mi[128 + f];
    mua[a][0][f] = m0[s]; mua[a][1][f] = m1[s]; mua[a][2][f] = m2[s];
  }

#pragma unroll
  for (int i = 0; i < 8; ++i) wt4[t + i*256] = ((const float4*)Wm)[t + i*256];
  __syncthreads();

  float V0[4]={0,0,0,0}, V1[4]={0,0,0,0}, V2[4]={0,0,0,0};
  float W0[4]={0,0,0,0}, W1[4]={0,0,0,0}, W2[4]={0,0,0,0};
  for (int k = 0; k < 64; ++k){
    float wv = wbuf[k*128 + f];
    float ww = wbuf[k*128 + 64 + f];
#pragma unroll
    for (int s = 0; s < 4; ++s){
      int a = aw + s;
      float b0 = mua[a][0][k], b1 = mua[a][1][k], b2 = mua[a][2][k];
      V0[s] = fmaf(b0, wv, V0[s]); V1[s] = fmaf(b1, wv, V1[s]); V2[s] = fmaf(b2, wv, V2[s]);
      W0[s] = fmaf(b0, ww, W0[s]); W1[s] = fmaf(b1, ww, W1[s]); W2[s] = fmaf(b2, ww, W2[s]);
    }
  }
  float dot[4];
#pragma unroll
  for (int s = 0; s < 4; ++s){
    int a = aw + s;
    ava[a][f] = qv[s];
    ava[a][64 + f] = sqrtf(V0[s]*V0[s] + V1[s]*V1[s] + V2[s]*V2[s] + EPSV);
    dot[s] = V0[s]*W0[s] + V1[s]*W1[s] + V2[s]*W2[s];
  }

  __syncthreads();
#pragma unroll
  for (int i = 0; i < 8; ++i) wt4[t + i*256] = ((const float4*)mW1)[t + i*256];
  __syncthreads();

  float acc[4];
#pragma unroll
  for (int s = 0; s < 4; ++s) acc[s] = mb1[f];
  for (int k = 0; k < 128; ++k){
    float wv = wbuf[k*64 + f];
#pragma unroll
    for (int s = 0; s < 4; ++s) acc[s] = fmaf(ava[aw + s][k], wv, acc[s]);
  }
#pragma unroll
  for (int s = 0; s < 4; ++s) h2a[aw + s][f] = silu_f(acc[s]);

  __syncthreads();
#pragma unroll
  for (int i = 0; i < 12; ++i) wt4[t + i*256] = ((const float4*)mW2)[t + i*256];
  __syncthreads();

  float y0[4], y1[4], y2[4];
#pragma unroll
  for (int s = 0; s < 4; ++s){ y0[s] = mb2[f]; y1[s] = mb2[64+f]; y2[s] = mb2[128+f]; }
  for (int k = 0; k < 64; ++k){
    float u0 = wbuf[k*192 + f];
    float u1 = wbuf[k*192 + 64 + f];
    float u2 = wbuf[k*192 + 128 + f];
#pragma unroll
    for (int s = 0; s < 4; ++s){
      float h = h2a[aw + s][k];
      y0[s] = fmaf(h, u0, y0[s]); y1[s] = fmaf(h, u1, y1[s]); y2[s] = fmaf(h, u2, y2[s]);
    }
  }

#pragma unroll
  for (int s = 0; s < 4; ++s){
    int n = base + aw + s;
    if (n < Ntot){
      q[(size_t)n*64 + f] = qv[s] + y0[s] + y2[s]*dot[s];
      const float* tvp = TV + (size_t)n*192;
      float* mun = mu + (size_t)n*384;
      mun[0*128 + f] = fmaf(y1[s], W0[s], m0[s]); mun[0*128 + 64 + f] = tvp[f];
      mun[1*128 + f] = fmaf(y1[s], W1[s], m1[s]); mun[1*128 + 64 + f] = tvp[64+f];
      mun[2*128 + f] = fmaf(y1[s], W2[s], m2[s]); mun[2*128 + 64 + f] = tvp[128+f];
    }
  }
}

extern "C" void kernel_launch(void* const* d_in, const int* in_sizes, int n_in,
                              void* d_out, int out_size, void* d_ws, size_t ws_size,
                              hipStream_t stream)
{
  const int*   Z      = (const int*)  d_in[0];
  const float* Rij    = (const float*)d_in[1];
  const int*   idx_i  = (const int*)  d_in[2];
  const int*   idx_j  = (const int*)  d_in[3];
  const float* embed  = (const float*)d_in[5];
  const float* fW     = (const float*)d_in[6];
  const float* fb     = (const float*)d_in[7];
  const float* ctxW1  = (const float*)d_in[8];
  const float* ctxb1  = (const float*)d_in[9];
  const float* ctxW2  = (const float*)d_in[10];
  const float* ctxb2  = (const float*)d_in[11];
  const float* compW1 = (const float*)d_in[12];
  const float* compb1 = (const float*)d_in[13];
  const float* compW2 = (const float*)d_in[14];
  const float* compb2 = (const float*)d_in[15];
  const float* recW1  = (const float*)d_in[16];
  const float* recb1  = (const float*)d_in[17];
  const float* recW2  = (const float*)d_in[18];
  const float* recb2  = (const float*)d_in[19];
  const float* mixW1  = (const float*)d_in[20];
  const float* mixb1  = (const float*)d_in[21];
  const float* mixW2  = (const float*)d_in[22];
  const float* mixb2  = (const float*)d_in[23];
  const float* muMixW = (const float*)d_in[24];

  const int N = in_sizes[0];
  const int P = in_sizes[1] / 3;

  float* ws    = (float*)d_ws;
  float* eP    = ws;                         // P*16 (64B records)
  float* q     = eP    + (size_t)P*16;       // N*64
  float* mu    = q     + (size_t)N*64;       // N*384
  float* XCVhf = mu    + (size_t)N*384;      // N*192 (uints)
  float* CVf   = XCVhf + (size_t)N*192;      // N*192
  float* dq    = CVf   + (size_t)N*192;      // N*64
  float* dmu   = dq    + (size_t)N*64;       // N*192
  float* rW2Sf = dmu   + (size_t)N*192;      // f16 512KB = 131072 floats
  float* rb2T  = rW2Sf + (size_t)131072;     // 8192
  float* TV    = rb2T  + (size_t)8192;       // N*192
  float* MUI   = TV    + (size_t)N*192;      // N*192
  int*   cnt    = (int*)(MUI + (size_t)N*192); // N
  int*   startA = cnt    + N;                  // N+1
  int*   cursor = startA + (N + 1);            // N
  int*   elist  = cursor + N;                  // P
  int*   eJ     = elist  + P;                  // P
  unsigned*       XCVh = (unsigned*)XCVhf;
  unsigned short* rW2S = (unsigned short*)rW2Sf;

  hipMemsetAsync(mu, 0, (size_t)N*384*sizeof(float), stream);
  hipMemsetAsync(cnt, 0, (size_t)N*sizeof(int), stream);
  k_init_q<<<(N*FD + 255)/256, 256, 0, stream>>>(Z, embed, q, N);
  k_transpose_w<<<(2*64*64*32 + 255)/256, 256, 0, stream>>>(recW2, recb2, rW2S, rb2T);

  // CSR build + CSR-ordered edge records (idx fixed across layers)
  k_count<<<(P + 255)/256, 256, 0, stream>>>(idx_i, cnt, P);
  k_scan<<<1, 1024, 0, stream>>>(cnt, startA, cursor, N);
  k_scatter<<<(P + 255)/256, 256, 0, stream>>>(idx_i, cursor, elist, P);
  k_edgeprep<<<(P + 255)/256, 256, 0, stream>>>(Rij, elist, idx_j, eP, eJ, P);

  const int ablk4  = (N + 3) / 4;
  const int ablk16 = (N + 15) / 16;
  for (int l = 0; l < 2; ++l){
    k_atom_pre<<<ablk16, 256, 0, stream>>>(q, mu,
        ctxW1 + (size_t)l*64*64,  ctxb1 + (size_t)l*64,
        ctxW2 + (size_t)l*64*192, ctxb2 + (size_t)l*192,
        compW1 + (size_t)l*128*32, compb1 + (size_t)l*32,
        compW2 + (size_t)l*32*64,  compb2 + (size_t)l*64,
        XCVh, CVf, N);
    k_gather<<<ablk4, 256, 0, stream>>>(eP, eJ, startA, fW, fb, XCVh,
        dq, dmu, l, N);
    k_tv<<<ablk16, 512, 0, stream>>>(dmu, CVf,
        recW1 + (size_t)l*64*32, recb1 + (size_t)l*32,
        rW2S + (size_t)l*131072, rb2T + (size_t)l*4096,
        MUI, TV, N);
    k_mix2<<<ablk16, 256, 0, stream>>>(q, mu, dq, MUI, TV,
        mixW1 + (size_t)l*128*64, mixb1 + (size_t)l*64,
        mixW2 + (size_t)l*64*192, mixb2 + (size_t)l*192,
        muMixW + (size_t)l*64*128, N);
  }

  hipMemcpyAsync(d_out, q, (size_t)N*64*sizeof(float), hipMemcpyDeviceToDevice, stream);
  hipMemcpyAsync((float*)d_out + (size_t)N*64, mu, (size_t)N*384*sizeof(float),
                 hipMemcpyDeviceToDevice, stream);
}